// Round 11
// baseline (3448.149 us; speedup 1.0000x reference)
//
#include <hip/hip_runtime.h>

#define NN 1000000
#define NE 4000000
#define NG 25000
#define BN_EPS 1e-5f

typedef unsigned short u16t;
typedef unsigned int u32t;
typedef __attribute__((ext_vector_type(8))) short bf16x8;
typedef __attribute__((ext_vector_type(4))) float f32x4;

__device__ inline u16t f2bf(float f) {
  u32t u = __float_as_uint(f);
  u32t r = (u + 0x7FFFu + ((u >> 16) & 1u)) >> 16;
  return (u16t)r;
}
__device__ inline float bf2f(u16t h) { return __uint_as_float((u32t)h << 16); }
__device__ inline u16t f2h(float f) {
  _Float16 h = (_Float16)f;
  return *(u16t*)&h;
}
__device__ inline float h2f(u16t v) {
  _Float16 h = *(_Float16*)&v;
  return (float)h;
}
__device__ inline void add8h(float* a, uint4 v) {
  union { uint4 u; _Float16 h[8]; } cv;
  cv.u = v;
#pragma unroll
  for (int j = 0; j < 8; ++j) a[j] += (float)cv.h[j];
}

// ---- workspace layout (bytes) ----
static const size_t OFF_U    = 0;           // fp16 64MB; also YB
static const size_t OFF_YA   = 130000000;
static const size_t OFF_NDE  = 202000000;   // uint2[NN] (8MB); dead in head phase (H1 ends 201.2e6, H2 @210e6)
static const size_t OFF_ST   = 258000000;
static const size_t OFF_RS   = 259000000;
static const size_t OFF_CUR  = 263200000;   // CSR cursor; PERM overlays after k_scatter
static const size_t OFF_BSUM = 267300000;
static const size_t OFF_SSRC = 268000000;   // 16MB
static const size_t OFF_WK   = 285000000;
static const size_t OFF_XC   = 287000000;
static const size_t OFF_SSRC2= 300000000;   // 16MB permuted edge ids
static const size_t OFF_T3   = 0;
static const size_t OFF_H1   = 150000000;
static const size_t OFF_H2   = 210000000;

// ---------------- CSR build ----------------
__global__ __launch_bounds__(256) void k_hist(const int* __restrict__ ei, u32t* __restrict__ cnt) {
  const int i = blockIdx.x * 256 + threadIdx.x;
  if (i < NE) atomicAdd(&cnt[ei[NE + i]], 1u);
}

__global__ __launch_bounds__(256) void k_scan1(const u32t* __restrict__ deg, u32t* __restrict__ bsum) {
  __shared__ u32t red[4];
  const int b = blockIdx.x, t = threadIdx.x;
  u32t s = 0;
#pragma unroll
  for (int j = 0; j < 4; ++j) {
    const int i = b * 1024 + j * 256 + t;
    if (i < NN) s += deg[i];
  }
#pragma unroll
  for (int off = 32; off > 0; off >>= 1) s += __shfl_down(s, off);
  if ((t & 63) == 0) red[t >> 6] = s;
  __syncthreads();
  if (t == 0) bsum[b] = red[0] + red[1] + red[2] + red[3];
}

__global__ __launch_bounds__(256) void k_scan2(u32t* __restrict__ bsum, u32t* __restrict__ rs, int nblk) {
  __shared__ u32t sh[256];
  const int t = threadIdx.x;
  u32t v[4];
#pragma unroll
  for (int j = 0; j < 4; ++j) {
    const int i = t * 4 + j;
    v[j] = (i < nblk) ? bsum[i] : 0u;
  }
  const u32t tot = v[0] + v[1] + v[2] + v[3];
  sh[t] = tot;
  __syncthreads();
  for (int off = 1; off < 256; off <<= 1) {
    u32t add = (t >= off) ? sh[t - off] : 0u;
    __syncthreads();
    sh[t] += add;
    __syncthreads();
  }
  const u32t tb = (t == 0) ? 0u : sh[t - 1];
  u32t run = tb;
#pragma unroll
  for (int j = 0; j < 4; ++j) {
    const int i = t * 4 + j;
    if (i < nblk) bsum[i] = run;
    run += v[j];
  }
  if (t == 0) rs[NN] = NE;
}

__global__ __launch_bounds__(256) void k_scan3(u32t* __restrict__ cur, u32t* __restrict__ rs,
                                               const u32t* __restrict__ bsum) {
  __shared__ u32t sh[256];
  const int b = blockIdx.x, t = threadIdx.x;
  const int i0 = b * 1024 + t * 4;
  u32t v[4];
#pragma unroll
  for (int j = 0; j < 4; ++j) v[j] = (i0 + j < NN) ? cur[i0 + j] : 0u;
  sh[t] = v[0] + v[1] + v[2] + v[3];
  __syncthreads();
  for (int off = 1; off < 256; off <<= 1) {
    u32t add = (t >= off) ? sh[t - off] : 0u;
    __syncthreads();
    sh[t] += add;
    __syncthreads();
  }
  u32t run = bsum[b] + ((t == 0) ? 0u : sh[t - 1]);
#pragma unroll
  for (int j = 0; j < 4; ++j) {
    const int i = i0 + j;
    if (i < NN) { rs[i] = run; cur[i] = run; }
    run += v[j];
  }
}

__global__ __launch_bounds__(256) void k_scatter(const int* __restrict__ ei,
                                                 u32t* __restrict__ cur, int* __restrict__ ssrc) {
  const int i = blockIdx.x * 256 + threadIdx.x;
  if (i < NE) {
    const int src = ei[i], dst = ei[NE + i];
    const u32t pos = atomicAdd(&cur[dst], 1u);
    ssrc[pos] = src;
  }
}

// ---------------- degree-sort permutation + permuted CSR ----------------
__global__ __launch_bounds__(256) void k_dhist(const u32t* __restrict__ rs, u32t* __restrict__ dh) {
  __shared__ u32t h[64];
  const int t = threadIdx.x;
  if (t < 64) h[t] = 0;
  __syncthreads();
#pragma unroll
  for (int j = 0; j < 4; ++j) {
    const int n = blockIdx.x * 1024 + j * 256 + t;
    if (n < NN) {
      u32t d = rs[n + 1] - rs[n];
      d = d > 63u ? 63u : d;
      atomicAdd(&h[d], 1u);
    }
  }
  __syncthreads();
  if (t < 64 && h[t]) atomicAdd(&dh[t], h[t]);
}

// scans both node counts (dc) and edge bases (ec); preserves dc0; inits bin-63 edge cursor
__global__ __launch_bounds__(64) void k_dscan(const u32t* __restrict__ dh, u32t* __restrict__ dc,
                                              u32t* __restrict__ dc0, u32t* __restrict__ ec,
                                              u32t* __restrict__ cur63) {
  __shared__ u32t sn[64], se[64];
  const int t = threadIdx.x;
  const u32t cnt = dh[t];
  sn[t] = cnt;
  se[t] = (t < 63) ? cnt * (u32t)t : 0u;
  __syncthreads();
  for (int off = 1; off < 64; off <<= 1) {
    u32t a = (t >= off) ? sn[t - off] : 0u;
    u32t b = (t >= off) ? se[t - off] : 0u;
    __syncthreads();
    sn[t] += a;
    se[t] += b;
    __syncthreads();
  }
  const u32t nb = (t == 0) ? 0u : sn[t - 1];
  const u32t eb = (t == 0) ? 0u : se[t - 1];
  dc[t] = nb;
  dc0[t] = nb;
  ec[t] = eb;                   // for t==63: sum over d<63 of dh[d]*d = bin-63 edge base
  if (t == 63) *cur63 = eb;
}

// places nodes; emits PERM[pos]=n and NDE[pos]={edge_offset, true_degree}
__global__ __launch_bounds__(256) void k_dscatter(const u32t* __restrict__ rs, u32t* __restrict__ dc,
                                                  const u32t* __restrict__ dc0, const u32t* __restrict__ ec,
                                                  u32t* __restrict__ cur63,
                                                  u32t* __restrict__ perm, uint2* __restrict__ nde) {
  __shared__ u32t h[64], base[64];
  const int t = threadIdx.x;
  u32t d[4], loc[4], dt[4];
  if (t < 64) h[t] = 0;
  __syncthreads();
#pragma unroll
  for (int j = 0; j < 4; ++j) {
    const int n = blockIdx.x * 1024 + j * 256 + t;
    if (n < NN) {
      const u32t dtrue = rs[n + 1] - rs[n];
      u32t dd = dtrue > 63u ? 63u : dtrue;
      d[j] = dd;
      dt[j] = dtrue;
      loc[j] = atomicAdd(&h[dd], 1u);
    } else d[j] = 64u;
  }
  __syncthreads();
  if (t < 64) base[t] = h[t] ? atomicAdd(&dc[t], h[t]) : 0u;
  __syncthreads();
#pragma unroll
  for (int j = 0; j < 4; ++j) {
    const int n = blockIdx.x * 1024 + j * 256 + t;
    if (d[j] < 64u) {
      const u32t pos = base[d[j]] + loc[j];
      perm[pos] = (u32t)n;
      u32t eoff;
      if (d[j] < 63u) eoff = ec[d[j]] + (pos - dc0[d[j]]) * d[j];
      else eoff = atomicAdd(cur63, dt[j]);
      nde[pos] = make_uint2(eoff, dt[j]);
    }
  }
}

// copy edge ids into permuted-contiguous layout (order within node preserved -> bit-identical sums)
__global__ __launch_bounds__(256) void k_eperm(const uint2* __restrict__ nde, const u32t* __restrict__ perm,
                                               const u32t* __restrict__ rs, const int* __restrict__ ssrc,
                                               int* __restrict__ ssrc2) {
  const int p = blockIdx.x * 256 + threadIdx.x;
  if (p < NN) {
    const uint2 nd = nde[p];
    const u32t e0 = rs[perm[p]];
    for (u32t j = 0; j < nd.y; ++j) ssrc2[nd.x + j] = ssrc[e0 + j];
  }
}

// ---------------- GNN kernels ----------------

__global__ __launch_bounds__(256) void k_mlp1_first(
    const float* __restrict__ x, const float* __restrict__ W1, u16t* __restrict__ u)
{
  __shared__ float Wt[78 * 33];
  __shared__ float xt_[8 * 79];
  const int t = threadIdx.x;
  for (int id = t; id < 78 * 32; id += 256) {
    int k = id >> 5, c = id & 31;
    Wt[k * 33 + c] = W1[id];
  }
  const int c = t & 31, nl = t >> 5;
  const int ntiles = NN / 8;
  for (int tile = blockIdx.x; tile < ntiles; tile += gridDim.x) {
    const int n0 = tile * 8;
    __syncthreads();
    for (int id = t; id < 8 * 78; id += 256) {
      int r = id / 78, k = id - r * 78;
      xt_[r * 79 + k] = x[(size_t)n0 * 78 + id];
    }
    __syncthreads();
    float acc = 0.f;
    const float* xr = xt_ + nl * 79;
#pragma unroll
    for (int k = 0; k < 78; ++k) acc = fmaf(xr[k], Wt[k * 33 + c], acc);
    u[(size_t)(n0 + nl) * 32 + c] = f2h(acc);
  }
}

// layer0 part B: 64 (degree-sorted) nodes/block; permuted-CSR gather
__global__ __launch_bounds__(256) void k_agg0(
    const u16t* __restrict__ u, const uint2* __restrict__ nde, const int* __restrict__ ssrc2,
    const u32t* __restrict__ perm,
    const float* __restrict__ b1, const float* __restrict__ W2, const float* __restrict__ b2,
    u16t* __restrict__ yout, float* __restrict__ stats_out)
{
  __shared__ float W2s[32 * 33];
  __shared__ float A1[64 * 33];
  __shared__ float red[256];
  __shared__ u32t pm[64];
  __shared__ uint2 nds[64];
  const int t = threadIdx.x;
  for (int id = t; id < 1024; id += 256) {
    int k = id >> 5, c = id & 31;
    W2s[k * 33 + c] = W2[id];
  }
  if (t < 64) {
    pm[t] = perm[blockIdx.x * 64 + t];
    nds[t] = nde[blockIdx.x * 64 + t];
  }
  __syncthreads();
  const int nl = t >> 2, c0 = (t & 3) * 8;
  const int pn = (int)pm[nl];
  float a[8] = {};
  add8h(a, *(const uint4*)(u + (size_t)pn * 32 + c0));
  const u32t e0 = nds[nl].x, e1 = e0 + nds[nl].y;
  u32t e = e0;
  for (; e + 4 <= e1; e += 4) {
    const int s0v = ssrc2[e], s1v = ssrc2[e + 1], s2v = ssrc2[e + 2], s3v = ssrc2[e + 3];
    const uint4 v0 = *(const uint4*)(u + (size_t)s0v * 32 + c0);
    const uint4 v1 = *(const uint4*)(u + (size_t)s1v * 32 + c0);
    const uint4 v2 = *(const uint4*)(u + (size_t)s2v * 32 + c0);
    const uint4 v3 = *(const uint4*)(u + (size_t)s3v * 32 + c0);
    add8h(a, v0); add8h(a, v1); add8h(a, v2); add8h(a, v3);
  }
  for (; e < e1; ++e)
    add8h(a, *(const uint4*)(u + (size_t)ssrc2[e] * 32 + c0));
  float* hp = A1 + nl * 33 + c0;
#pragma unroll
  for (int j = 0; j < 8; ++j) hp[j] = fmaxf(a[j] + b1[c0 + j], 0.f);
  __syncthreads();
  const int c = t & 31;
  const float b2v = b2[c];
  float rsum = 0.f, rq = 0.f;
#pragma unroll
  for (int rep = 0; rep < 8; ++rep) {
    const int row = (t >> 5) + rep * 8;
    const float* hr = A1 + row * 33;
    float acc = b2v;
#pragma unroll
    for (int k = 0; k < 32; ++k) acc = fmaf(hr[k], W2s[k * 33 + c], acc);
    acc = fmaxf(acc, 0.f);
    yout[(size_t)pm[row] * 32 + c] = f2h(acc);
    rsum += acc;
    rq += acc * acc;
  }
  rsum += __shfl_down(rsum, 32);
  rq += __shfl_down(rq, 32);
  __syncthreads();
  const int wv_ = t >> 6, lane = t & 63;
  if (lane < 32) {
    red[wv_ * 32 + lane] = rsum;
    red[128 + wv_ * 32 + lane] = rq;
  }
  __syncthreads();
  if (t < 32) {
    float aa = red[t] + red[32 + t] + red[64 + t] + red[96 + t];
    float bb = red[128 + t] + red[160 + t] + red[192 + t] + red[224 + t];
    unsafeAtomicAdd(&stats_out[t], aa);
    unsafeAtomicAdd(&stats_out[32 + t], bb);
  }
}

// layers 1..4: permuted-CSR gather
__global__ __launch_bounds__(256) void k_layer(
    const u16t* __restrict__ yin, const uint2* __restrict__ nde, const int* __restrict__ ssrc2,
    const u32t* __restrict__ perm,
    const float* __restrict__ stats, const float* __restrict__ gamma, const float* __restrict__ beta,
    const float* __restrict__ W1, const float* __restrict__ b1,
    const float* __restrict__ W2, const float* __restrict__ b2,
    u16t* __restrict__ yout, float* __restrict__ stats_out)
{
  __shared__ float W1s[32 * 33];
  __shared__ float W2s[32 * 33];
  __shared__ float A1[64 * 33];
  __shared__ float A2[64 * 33];
  __shared__ float red[256];
  __shared__ u32t pm[64];
  __shared__ uint2 nds[64];
  const int t = threadIdx.x;
  for (int id = t; id < 1024; id += 256) {
    int k = id >> 5, c = id & 31;
    W1s[k * 33 + c] = W1[id];
    W2s[k * 33 + c] = W2[id];
  }
  if (t < 64) {
    pm[t] = perm[blockIdx.x * 64 + t];
    nds[t] = nde[blockIdx.x * 64 + t];
  }
  __syncthreads();
  const int nl = t >> 2, c0 = (t & 3) * 8;
  const int pn = (int)pm[nl];
  float sc[8], sh[8];
#pragma unroll
  for (int j = 0; j < 8; ++j) {
    const int c = c0 + j;
    const float mu = stats[c] * (1.f / NN);
    float var = fmaxf(stats[32 + c] * (1.f / NN) - mu * mu, 0.f);
    sc[j] = gamma[c] * rsqrtf(var + BN_EPS);
    sh[j] = beta[c] - mu * sc[j];
  }
  float a[8] = {};
  add8h(a, *(const uint4*)(yin + (size_t)pn * 32 + c0));
  const u32t e0 = nds[nl].x, e1 = e0 + nds[nl].y;
  u32t e = e0;
  for (; e + 4 <= e1; e += 4) {
    const int s0v = ssrc2[e], s1v = ssrc2[e + 1], s2v = ssrc2[e + 2], s3v = ssrc2[e + 3];
    const uint4 v0 = *(const uint4*)(yin + (size_t)s0v * 32 + c0);
    const uint4 v1 = *(const uint4*)(yin + (size_t)s1v * 32 + c0);
    const uint4 v2 = *(const uint4*)(yin + (size_t)s2v * 32 + c0);
    const uint4 v3 = *(const uint4*)(yin + (size_t)s3v * 32 + c0);
    add8h(a, v0); add8h(a, v1); add8h(a, v2); add8h(a, v3);
  }
  for (; e < e1; ++e)
    add8h(a, *(const uint4*)(yin + (size_t)ssrc2[e] * 32 + c0));
  const float cnt = (float)(e1 - e0 + 1u);
  float* hp = A1 + nl * 33 + c0;
#pragma unroll
  for (int j = 0; j < 8; ++j) hp[j] = sc[j] * a[j] + cnt * sh[j];
  __syncthreads();
  const int c = t & 31;
  const float b1v = b1[c];
#pragma unroll
  for (int rep = 0; rep < 8; ++rep) {
    const int row = (t >> 5) + rep * 8;
    const float* hr = A1 + row * 33;
    float acc = b1v;
#pragma unroll
    for (int k = 0; k < 32; ++k) acc = fmaf(hr[k], W1s[k * 33 + c], acc);
    A2[row * 33 + c] = fmaxf(acc, 0.f);
  }
  __syncthreads();
  const float b2v = b2[c];
  float rsum = 0.f, rq = 0.f;
#pragma unroll
  for (int rep = 0; rep < 8; ++rep) {
    const int row = (t >> 5) + rep * 8;
    const float* hr = A2 + row * 33;
    float acc = b2v;
#pragma unroll
    for (int k = 0; k < 32; ++k) acc = fmaf(hr[k], W2s[k * 33 + c], acc);
    acc = fmaxf(acc, 0.f);
    yout[(size_t)pm[row] * 32 + c] = f2h(acc);
    rsum += acc;
    rq += acc * acc;
  }
  rsum += __shfl_down(rsum, 32);
  rq += __shfl_down(rq, 32);
  __syncthreads();
  const int wv_ = t >> 6, lane = t & 63;
  if (lane < 32) {
    red[wv_ * 32 + lane] = rsum;
    red[128 + wv_ * 32 + lane] = rq;
  }
  __syncthreads();
  if (t < 32) {
    float aa = red[t] + red[32 + t] + red[64 + t] + red[96 + t];
    float bb = red[128 + t] + red[160 + t] + red[192 + t] + red[224 + t];
    unsafeAtomicAdd(&stats_out[t], aa);
    unsafeAtomicAdd(&stats_out[32 + t], bb);
  }
}

__global__ __launch_bounds__(64) void k_pool_xd(
    const u16t* __restrict__ y, const int* __restrict__ batch,
    const float* __restrict__ stats, const float* __restrict__ gamma,
    const float* __restrict__ beta, const float* __restrict__ Wxd,
    const float* __restrict__ bxd, u16t* __restrict__ xc)
{
  const int g = blockIdx.x, t = threadIdx.x;
  int lo = 0, n = NN;
  while (n > 0) {
    int h = n >> 1, m = lo + h;
    if (batch[m] < g) { lo = m + 1; n -= h + 1; } else n = h;
  }
  int hi = lo;
  n = NN - lo;
  while (n > 0) {
    int h = n >> 1, m = hi + h;
    if (batch[m] < g + 1) { hi = m + 1; n -= h + 1; } else n = h;
  }
  const int c = t & 31;
  const float mu = stats[4 * 64 + c] * (1.f / NN);
  float var = fmaxf(stats[4 * 64 + 32 + c] * (1.f / NN) - mu * mu, 0.f);
  const float sc = gamma[4 * 32 + c] * rsqrtf(var + BN_EPS);
  const float sh = beta[4 * 32 + c] - mu * sc;
  float acc = 0.f;
  for (int i = lo + (t >> 5); i < hi; i += 2) acc += h2f(y[(size_t)i * 32 + c]);
  acc += __shfl_down(acc, 32);
  __shared__ float pl[32];
  if (t < 32) pl[t] = acc * sc + (float)(hi - lo) * sh;
  __syncthreads();
#pragma unroll
  for (int rep = 0; rep < 2; ++rep) {
    const int o = t + rep * 64;
    float a = bxd[o];
#pragma unroll
    for (int cc = 0; cc < 32; ++cc) a = fmaf(pl[cc], Wxd[cc * 128 + o], a);
    xc[(size_t)g * 256 + o] = f2bf(fmaxf(a, 0.f));
  }
}

// ---------------- weight prep ----------------
__global__ __launch_bounds__(256) void k_prep(
    const float* __restrict__ w2, const float* __restrict__ w3,
    const float* __restrict__ wxt, const float* __restrict__ wf1, const float* __restrict__ wf2,
    u16t* __restrict__ W2k, u16t* __restrict__ W3k,
    u16t* __restrict__ WXT, u16t* __restrict__ WF1, u16t* __restrict__ WF2)
{
  const int i = blockIdx.x * 256 + threadIdx.x;
  if (i < 64 * 256) {
    int c2 = i >> 8, kk = i & 255, tt = kk >> 5, ci = kk & 31;
    W2k[i] = f2bf(w2[c2 * 256 + ci * 8 + tt]);
  }
  if (i < 128 * 512) {
    int c3 = i >> 9, kk = i & 511, tt = kk >> 6, ci = kk & 63;
    W3k[i] = f2bf(w3[c3 * 512 + ci * 8 + tt]);
  }
  if (i < 128 * 2944) {
    int nn = i / 2944, kk = i - nn * 2944;
    WXT[i] = f2bf(wxt[kk * 128 + nn]);
  }
  if (i < 1024 * 256) {
    int nn = i >> 8, kk = i & 255;
    WF1[i] = f2bf(wf1[kk * 1024 + nn]);
  }
  if (i < 128 * 1024) {
    int nn = i >> 10, kk = i & 1023;
    WF2[i] = f2bf(wf2[kk * 128 + nn]);
  }
}

// ---------------- fused per-graph CNN (unchanged) ----------------
__global__ __launch_bounds__(256, 4) void k_cnn(
    const float* __restrict__ xo,
    const float* __restrict__ w1, const float* __restrict__ b1,
    const u16t* __restrict__ W2k, const float* __restrict__ b2,
    const u16t* __restrict__ W3k, const float* __restrict__ b3,
    u16t* __restrict__ t3)
{
  __shared__ __align__(16) char smem[30720];
  float* xot = (float*)(smem);
  float* w1s = (float*)(smem + 3072);
  float* b2s = (float*)(smem + 4096);
  float* b3s = (float*)(smem + 4352);
  short* T1T = (short*)(smem + 4864);
  char*  T2B = smem + 20736;
  u16t*  stg = (u16t*)(smem + 4864);

  const int g = blockIdx.x, t = threadIdx.x;
  const int w = t >> 6, l = t & 63, col = l & 15, kg = l >> 4;

  for (int i = t; i < 768; i += 256) xot[i] = (i < 735) ? xo[(size_t)g * 735 + i] : 0.f;
  w1s[t] = w1[t];
  if (t < 64) b2s[t] = b2[t];
  if (t < 128) b3s[t] = b3[t];
  if (t < 192) {
    int r = 242 + (t >> 5), c = t & 31;
    T1T[r * 32 + c] = 0;
  }
  __syncthreads();

  {
    const int c = t >> 3, qg = t & 7;
    float wv[8];
#pragma unroll
    for (int j = 0; j < 8; ++j) wv[j] = w1s[c * 8 + j];
    const float bias = b1[c];
    const int q0 = qg * 31, qe = (q0 + 31 < 242) ? q0 + 31 : 242;
#pragma unroll 1
    for (int qc = q0; qc < qe; qc += 10) {
      const int cnt = (qe - qc < 10) ? qe - qc : 10;
      float xv[37];
#pragma unroll
      for (int j = 0; j < 37; ++j) xv[j] = xot[3 * qc + j];
#pragma unroll
      for (int j0 = 0; j0 < 10; ++j0) {
        if (j0 < cnt) {
          float a0 = bias, a1 = bias, a2 = bias;
#pragma unroll
          for (int tt = 0; tt < 8; ++tt) {
            a0 = fmaf(wv[tt], xv[3 * j0 + tt], a0);
            a1 = fmaf(wv[tt], xv[3 * j0 + 1 + tt], a1);
            a2 = fmaf(wv[tt], xv[3 * j0 + 2 + tt], a2);
          }
          float m = fmaxf(fmaxf(a0, a1), fmaxf(a2, 0.f));
          const int pos = qc + j0;
          T1T[pos * 32 + (c ^ ((pos & 3) << 3))] = (short)f2bf(m);
        }
      }
    }
  }
  __syncthreads();

  {
    bf16x8 am[8];
#pragma unroll
    for (int kk = 0; kk < 8; ++kk)
      am[kk] = *(const bf16x8*)(W2k + (w * 16 + col) * 256 + kk * 32 + kg * 8);
#pragma unroll 1
    for (int qt = 0; qt < 5; ++qt) {
      const int rbase = qt * 48 + col * 3;
      bf16x8 rv[10];
#pragma unroll
      for (int s = 0; s < 10; ++s) {
        const int row = rbase + s;
        rv[s] = *(const bf16x8*)(T1T + row * 32 + ((kg ^ (row & 3)) << 3));
      }
      f32x4 a0 = {0.f, 0.f, 0.f, 0.f}, a1 = a0, a2 = a0;
#pragma unroll
      for (int kk = 0; kk < 8; ++kk) {
        a0 = __builtin_amdgcn_mfma_f32_16x16x32_bf16(am[kk], rv[kk], a0, 0, 0, 0);
        a1 = __builtin_amdgcn_mfma_f32_16x16x32_bf16(am[kk], rv[kk + 1], a1, 0, 0, 0);
        a2 = __builtin_amdgcn_mfma_f32_16x16x32_bf16(am[kk], rv[kk + 2], a2, 0, 0, 0);
      }
      const int q = qt * 16 + col;
      if (q < 78) {
        union { u16t u[4]; uint2 v; } pk;
#pragma unroll
        for (int r = 0; r < 4; ++r) {
          const float bb = b2s[w * 16 + kg * 4 + r];
          float m = fmaxf(fmaxf(a0[r], a1[r]), a2[r]);
          pk.u[r] = f2bf(fmaxf(m + bb, 0.f));
        }
        const int boff = (q * 128 + (w * 16 + kg * 4) * 2) ^ ((q & 7) << 4);
        *(uint2*)(T2B + boff) = pk.v;
      }
    }
  }
  __syncthreads();

  {
#pragma unroll 1
    for (int mi = 0; mi < 2; ++mi) {
      const int m3 = w * 2 + mi;
      f32x4 acc[2][3];
#pragma unroll
      for (int qt = 0; qt < 2; ++qt)
#pragma unroll
        for (int r = 0; r < 3; ++r) acc[qt][r] = (f32x4){0.f, 0.f, 0.f, 0.f};
#pragma unroll 1
      for (int kh = 0; kh < 2; ++kh) {
        bf16x8 amh[8];
#pragma unroll
        for (int tt = 0; tt < 8; ++tt)
          amh[tt] = *(const bf16x8*)(W3k + (m3 * 16 + col) * 512 + (tt * 2 + kh) * 32 + kg * 8);
#pragma unroll
        for (int qt = 0; qt < 2; ++qt) {
          const int rbase = qt * 48 + col * 3;
          bf16x8 rv[10];
#pragma unroll
          for (int s = 0; s < 10; ++s) {
            int row = rbase + s;
            row = (row < 78) ? row : 77;
            const int boff = (row * 128 + kh * 64 + kg * 16) ^ ((row & 7) << 4);
            rv[s] = *(const bf16x8*)(T2B + boff);
          }
#pragma unroll
          for (int tt = 0; tt < 8; ++tt) {
            acc[qt][0] = __builtin_amdgcn_mfma_f32_16x16x32_bf16(amh[tt], rv[tt], acc[qt][0], 0, 0, 0);
            acc[qt][1] = __builtin_amdgcn_mfma_f32_16x16x32_bf16(amh[tt], rv[tt + 1], acc[qt][1], 0, 0, 0);
            acc[qt][2] = __builtin_amdgcn_mfma_f32_16x16x32_bf16(amh[tt], rv[tt + 2], acc[qt][2], 0, 0, 0);
          }
        }
      }
#pragma unroll
      for (int qt = 0; qt < 2; ++qt) {
        const int q = qt * 16 + col;
        if (q < 23) {
#pragma unroll
          for (int r = 0; r < 4; ++r) {
            const int c = m3 * 16 + kg * 4 + r;
            float m = fmaxf(fmaxf(acc[qt][0][r], acc[qt][1][r]), acc[qt][2][r]);
            stg[c * 23 + q] = f2bf(fmaxf(m + b3s[c], 0.f));
          }
        }
      }
    }
  }
  __syncthreads();

  {
    const uint4* s4 = (const uint4*)stg;
    uint4* d4 = (uint4*)(t3 + (size_t)g * 2944);
    for (int id = t; id < 368; id += 256) d4[id] = s4[id];
  }
}

// ---------------- bf16 MFMA GEMM ----------------
__global__ __launch_bounds__(256) void k_mgemm(
    const u16t* __restrict__ A, int lda,
    const u16t* __restrict__ WT, const float* __restrict__ bias,
    void* __restrict__ Cv, int ldc, int c_off, int M, int Kd,
    int relu_f, int out32)
{
  __shared__ __align__(16) u16t As[128 * 4 * 8];
  __shared__ __align__(16) u16t Ws2[64 * 4 * 8];
  const int t = threadIdx.x;
  const int w = t >> 6, l = t & 63, col = l & 15, kg = l >> 4;
  const int wm = w & 1, wn = w >> 1;
  const int m0 = blockIdx.x * 128, n0 = blockIdx.y * 64;
  f32x4 acc[4][2];
#pragma unroll
  for (int i = 0; i < 4; ++i)
#pragma unroll
    for (int j = 0; j < 2; ++j) acc[i][j] = (f32x4){0.f, 0.f, 0.f, 0.f};
  const int ar = t >> 1, ac = (t & 1) * 2;
  const int wr = t >> 2, wc = t & 3;
  const bool aok = (m0 + ar) < M;
  const u16t* Ap = A + (size_t)(m0 + ar) * lda;
  const u16t* Wp = WT + (size_t)(n0 + wr) * Kd;
  for (int k0 = 0; k0 < Kd; k0 += 32) {
    bf16x8 av0 = {0, 0, 0, 0, 0, 0, 0, 0}, av1 = {0, 0, 0, 0, 0, 0, 0, 0};
    if (aok) {
      av0 = *(const bf16x8*)(Ap + k0 + ac * 8);
      av1 = *(const bf16x8*)(Ap + k0 + (ac + 1) * 8);
    }
    const bf16x8 wv = *(const bf16x8*)(Wp + k0 + wc * 8);
    __syncthreads();
    *(bf16x8*)(As + (ar * 4 + (ac ^ (ar & 3))) * 8) = av0;
    *(bf16x8*)(As + (ar * 4 + ((ac + 1) ^ (ar & 3))) * 8) = av1;
    *(bf16x8*)(Ws2 + (wr * 4 + (wc ^ (wr & 3))) * 8) = wv;
    __syncthreads();
    bf16x8 af[4], bf[2];
#pragma unroll
    for (int i = 0; i < 4; ++i) {
      const int R = wm * 64 + i * 16 + col;
      af[i] = *(const bf16x8*)(As + (R * 4 + (kg ^ (R & 3))) * 8);
    }
#pragma unroll
    for (int j = 0; j < 2; ++j) {
      const int R = wn * 32 + j * 16 + col;
      bf[j] = *(const bf16x8*)(Ws2 + (R * 4 + (kg ^ (R & 3))) * 8);
    }
#pragma unroll
    for (int i = 0; i < 4; ++i)
#pragma unroll
      for (int j = 0; j < 2; ++j)
        acc[i][j] = __builtin_amdgcn_mfma_f32_16x16x32_bf16(af[i], bf[j], acc[i][j], 0, 0, 0);
  }
#pragma unroll
  for (int j = 0; j < 2; ++j) {
    const int gn = n0 + wn * 32 + j * 16 + col;
    const float bb = bias[gn];
#pragma unroll
    for (int i = 0; i < 4; ++i) {
      const int gmb = m0 + wm * 64 + i * 16 + kg * 4;
#pragma unroll
      for (int r = 0; r < 4; ++r) {
        const int gm = gmb + r;
        if (gm < M) {
          float v = acc[i][j][r] + bb;
          if (relu_f) v = fmaxf(v, 0.f);
          if (out32) ((float*)Cv)[(size_t)gm * ldc + c_off + gn] = v;
          else ((u16t*)Cv)[(size_t)gm * ldc + c_off + gn] = f2bf(v);
        }
      }
    }
  }
}

__global__ __launch_bounds__(256) void k_out(
    const float* __restrict__ h2, const float* __restrict__ Wo,
    const float* __restrict__ bo, float* __restrict__ out)
{
  __shared__ float Ws_[128];
  const int t = threadIdx.x;
  if (t < 128) Ws_[t] = Wo[t];
  __syncthreads();
  const int g = blockIdx.x * 32 + (t >> 3), l = t & 7;
  float acc = 0.f;
  if (g < NG) {
    const float* hr = h2 + (size_t)g * 128 + l * 16;
    const float* wr = Ws_ + l * 16;
#pragma unroll
    for (int j = 0; j < 16; ++j) acc = fmaf(hr[j], wr[j], acc);
  }
  acc += __shfl_down(acc, 4, 8);
  acc += __shfl_down(acc, 2, 8);
  acc += __shfl_down(acc, 1, 8);
  if (l == 0 && g < NG) out[g] = acc + bo[0];
}

extern "C" void kernel_launch(void* const* d_in, const int* in_sizes, int n_in,
                              void* d_out, int out_size, void* d_ws, size_t ws_size,
                              hipStream_t stream) {
  const float* x    = (const float*)d_in[0];
  const int*   ei   = (const int*)d_in[1];
  const int*   batch= (const int*)d_in[2];
  const float* xo   = (const float*)d_in[3];
  const float* g1W1 = (const float*)d_in[4];
  const float* g1b1 = (const float*)d_in[5];
  const float* g1W2 = (const float*)d_in[6];
  const float* g1b2 = (const float*)d_in[7];
  const float* gsW1 = (const float*)d_in[8];
  const float* gsb1 = (const float*)d_in[9];
  const float* gsW2 = (const float*)d_in[10];
  const float* gsb2 = (const float*)d_in[11];
  const float* bng  = (const float*)d_in[12];
  const float* bnb  = (const float*)d_in[13];
  const float* Wxd  = (const float*)d_in[14];
  const float* bxd  = (const float*)d_in[15];
  const float* c1W  = (const float*)d_in[16];
  const float* c1b  = (const float*)d_in[17];
  const float* c2W  = (const float*)d_in[18];
  const float* c2b  = (const float*)d_in[19];
  const float* c3W  = (const float*)d_in[20];
  const float* c3b  = (const float*)d_in[21];
  const float* Wxt  = (const float*)d_in[22];
  const float* bxt  = (const float*)d_in[23];
  const float* W1f  = (const float*)d_in[24];
  const float* b1f  = (const float*)d_in[25];
  const float* W2f  = (const float*)d_in[26];
  const float* b2f  = (const float*)d_in[27];
  const float* Wo   = (const float*)d_in[28];
  const float* bo   = (const float*)d_in[29];

  char* ws = (char*)d_ws;
  u16t*  U    = (u16t*)(ws + OFF_U);
  u16t*  YA   = (u16t*)(ws + OFF_YA);
  u16t*  YB   = (u16t*)(ws + OFF_U);
  uint2* NDE  = (uint2*)(ws + OFF_NDE);
  float* ST   = (float*)(ws + OFF_ST);
  u32t*  RS   = (u32t*)(ws + OFF_RS);
  u32t*  CUR  = (u32t*)(ws + OFF_CUR);
  u32t*  BS   = (u32t*)(ws + OFF_BSUM);
  u32t*  DH   = (u32t*)(ws + OFF_BSUM + 4096);
  u32t*  DC   = (u32t*)(ws + OFF_BSUM + 4352);
  u32t*  DC0  = (u32t*)(ws + OFF_BSUM + 4608);
  u32t*  EC   = (u32t*)(ws + OFF_BSUM + 4864);
  u32t*  C63  = (u32t*)(ws + OFF_BSUM + 5120);
  u32t*  PERM = (u32t*)(ws + OFF_CUR);        // overlays CUR after k_scatter
  int*   SSRC = (int*)(ws + OFF_SSRC);
  int*   SSRC2= (int*)(ws + OFF_SSRC2);
  u16t*  WK   = (u16t*)(ws + OFF_WK);
  u16t*  W2K  = WK;
  u16t*  W3K  = WK + 16384;
  u16t*  WXT  = WK + 16384 + 65536;
  u16t*  WF1  = WK + 16384 + 65536 + 376832;
  u16t*  WF2  = WK + 16384 + 65536 + 376832 + 262144;
  u16t*  XC   = (u16t*)(ws + OFF_XC);
  u16t*  T3   = (u16t*)(ws + OFF_T3);
  u16t*  H1   = (u16t*)(ws + OFF_H1);
  float* H2   = (float*)(ws + OFF_H2);
  float* OUT  = (float*)d_out;

  const int NBLK = (NN + 1023) / 1024;

  hipMemsetAsync(ST, 0, 5 * 64 * sizeof(float), stream);
  hipMemsetAsync(CUR, 0, NN * sizeof(u32t), stream);
  hipMemsetAsync(DH, 0, 64 * sizeof(u32t), stream);

  k_prep<<<(128 * 2944 + 255) / 256, 256, 0, stream>>>(c2W, c3W, Wxt, W1f, W2f,
                                                        W2K, W3K, WXT, WF1, WF2);

  k_hist<<<(NE + 255) / 256, 256, 0, stream>>>(ei, CUR);
  k_scan1<<<NBLK, 256, 0, stream>>>(CUR, BS);
  k_scan2<<<1, 256, 0, stream>>>(BS, RS, NBLK);
  k_scan3<<<NBLK, 256, 0, stream>>>(CUR, RS, BS);
  k_scatter<<<(NE + 255) / 256, 256, 0, stream>>>(ei, CUR, SSRC);

  // degree-sorted permutation + permuted CSR (collapses the per-node pointer chase)
  k_dhist<<<NBLK, 256, 0, stream>>>(RS, DH);
  k_dscan<<<1, 64, 0, stream>>>(DH, DC, DC0, EC, C63);
  k_dscatter<<<NBLK, 256, 0, stream>>>(RS, DC, DC0, EC, C63, PERM, NDE);
  k_eperm<<<(NN + 255) / 256, 256, 0, stream>>>(NDE, PERM, RS, SSRC, SSRC2);

  k_mlp1_first<<<2048, 256, 0, stream>>>(x, g1W1, U);
  k_agg0<<<NN / 64, 256, 0, stream>>>(U, NDE, SSRC2, PERM, g1b1, g1W2, g1b2, YA, ST + 0);
  const u16t* yin = YA;
  u16t* yout = YB;
  for (int lyr = 1; lyr <= 4; ++lyr) {
    k_layer<<<NN / 64, 256, 0, stream>>>(yin, NDE, SSRC2, PERM, ST + (lyr - 1) * 64,
                                         bng + (lyr - 1) * 32, bnb + (lyr - 1) * 32,
                                         gsW1 + (lyr - 1) * 1024, gsb1 + (lyr - 1) * 32,
                                         gsW2 + (lyr - 1) * 1024, gsb2 + (lyr - 1) * 32,
                                         yout, ST + lyr * 64);
    const u16t* tmp = yin;
    yin = yout;
    yout = (u16t*)tmp;
  }
  k_pool_xd<<<NG, 64, 0, stream>>>(yin, batch, ST, bng, bnb, Wxd, bxd, XC);

  k_cnn<<<NG, 256, 0, stream>>>(xo, c1W, c1b, W2K, c2b, W3K, c3b, T3);

  {
    dim3 grid((NG + 127) / 128, 2);
    k_mgemm<<<grid, 256, 0, stream>>>(T3, 2944, WXT, bxt, XC, 256, 128, NG, 2944, 0, 0);
  }
  {
    dim3 grid((NG + 127) / 128, 16);
    k_mgemm<<<grid, 256, 0, stream>>>(XC, 256, WF1, b1f, H1, 1024, 0, NG, 256, 1, 0);
  }
  {
    dim3 grid((NG + 127) / 128, 2);
    k_mgemm<<<grid, 256, 0, stream>>>(H1, 1024, WF2, b2f, H2, 128, 0, NG, 1024, 1, 1);
  }
  k_out<<<(NG + 31) / 32, 256, 0, stream>>>(H2, Wo, bo, OUT);
}

// Round 12
// 2799.125 us; speedup vs baseline: 1.2319x; 1.2319x over previous
//
#include <hip/hip_runtime.h>

#define NN 1000000
#define NE 4000000
#define NG 25000
#define BN_EPS 1e-5f

typedef unsigned short u16t;
typedef unsigned int u32t;
typedef __attribute__((ext_vector_type(8))) short bf16x8;
typedef __attribute__((ext_vector_type(8))) _Float16 f16x8;
typedef __attribute__((ext_vector_type(4))) float f32x4;

__device__ inline u16t f2bf(float f) {
  u32t u = __float_as_uint(f);
  u32t r = (u + 0x7FFFu + ((u >> 16) & 1u)) >> 16;
  return (u16t)r;
}
__device__ inline float bf2f(u16t h) { return __uint_as_float((u32t)h << 16); }
__device__ inline u16t f2h(float f) {
  _Float16 h = (_Float16)f;
  return *(u16t*)&h;
}
__device__ inline float h2f(u16t v) {
  _Float16 h = *(_Float16*)&v;
  return (float)h;
}
__device__ inline void add8h(float* a, uint4 v) {
  union { uint4 u; _Float16 h[8]; } cv;
  cv.u = v;
#pragma unroll
  for (int j = 0; j < 8; ++j) a[j] += (float)cv.h[j];
}

// ---- workspace layout (bytes) ----
static const size_t OFF_U    = 0;           // fp16 64MB; also YB
static const size_t OFF_YA   = 130000000;
static const size_t OFF_NDE  = 202000000;   // uint2[NN] (8MB)
static const size_t OFF_ST   = 258000000;
static const size_t OFF_RS   = 259000000;
static const size_t OFF_CUR  = 263200000;   // CSR cursor; PERM overlays after k_scatter
static const size_t OFF_BSUM = 267300000;
static const size_t OFF_SSRC = 268000000;   // 16MB
static const size_t OFF_WK   = 285000000;
static const size_t OFF_XC   = 287000000;
static const size_t OFF_SSRC2= 300000000;   // 16MB permuted edge ids
static const size_t OFF_T3   = 0;
static const size_t OFF_H1   = 150000000;
static const size_t OFF_H2   = 210000000;

// ---------------- CSR build ----------------
__global__ __launch_bounds__(256) void k_hist(const int* __restrict__ ei, u32t* __restrict__ cnt) {
  const int i = blockIdx.x * 256 + threadIdx.x;
  if (i < NE) atomicAdd(&cnt[ei[NE + i]], 1u);
}

__global__ __launch_bounds__(256) void k_scan1(const u32t* __restrict__ deg, u32t* __restrict__ bsum) {
  __shared__ u32t red[4];
  const int b = blockIdx.x, t = threadIdx.x;
  u32t s = 0;
#pragma unroll
  for (int j = 0; j < 4; ++j) {
    const int i = b * 1024 + j * 256 + t;
    if (i < NN) s += deg[i];
  }
#pragma unroll
  for (int off = 32; off > 0; off >>= 1) s += __shfl_down(s, off);
  if ((t & 63) == 0) red[t >> 6] = s;
  __syncthreads();
  if (t == 0) bsum[b] = red[0] + red[1] + red[2] + red[3];
}

__global__ __launch_bounds__(256) void k_scan2(u32t* __restrict__ bsum, u32t* __restrict__ rs, int nblk) {
  __shared__ u32t sh[256];
  const int t = threadIdx.x;
  u32t v[4];
#pragma unroll
  for (int j = 0; j < 4; ++j) {
    const int i = t * 4 + j;
    v[j] = (i < nblk) ? bsum[i] : 0u;
  }
  const u32t tot = v[0] + v[1] + v[2] + v[3];
  sh[t] = tot;
  __syncthreads();
  for (int off = 1; off < 256; off <<= 1) {
    u32t add = (t >= off) ? sh[t - off] : 0u;
    __syncthreads();
    sh[t] += add;
    __syncthreads();
  }
  const u32t tb = (t == 0) ? 0u : sh[t - 1];
  u32t run = tb;
#pragma unroll
  for (int j = 0; j < 4; ++j) {
    const int i = t * 4 + j;
    if (i < nblk) bsum[i] = run;
    run += v[j];
  }
  if (t == 0) rs[NN] = NE;
}

__global__ __launch_bounds__(256) void k_scan3(u32t* __restrict__ cur, u32t* __restrict__ rs,
                                               const u32t* __restrict__ bsum) {
  __shared__ u32t sh[256];
  const int b = blockIdx.x, t = threadIdx.x;
  const int i0 = b * 1024 + t * 4;
  u32t v[4];
#pragma unroll
  for (int j = 0; j < 4; ++j) v[j] = (i0 + j < NN) ? cur[i0 + j] : 0u;
  sh[t] = v[0] + v[1] + v[2] + v[3];
  __syncthreads();
  for (int off = 1; off < 256; off <<= 1) {
    u32t add = (t >= off) ? sh[t - off] : 0u;
    __syncthreads();
    sh[t] += add;
    __syncthreads();
  }
  u32t run = bsum[b] + ((t == 0) ? 0u : sh[t - 1]);
#pragma unroll
  for (int j = 0; j < 4; ++j) {
    const int i = i0 + j;
    if (i < NN) { rs[i] = run; cur[i] = run; }
    run += v[j];
  }
}

__global__ __launch_bounds__(256) void k_scatter(const int* __restrict__ ei,
                                                 u32t* __restrict__ cur, int* __restrict__ ssrc) {
  const int i = blockIdx.x * 256 + threadIdx.x;
  if (i < NE) {
    const int src = ei[i], dst = ei[NE + i];
    const u32t pos = atomicAdd(&cur[dst], 1u);
    ssrc[pos] = src;
  }
}

// ---------------- degree-sort permutation + permuted CSR ----------------
__global__ __launch_bounds__(256) void k_dhist(const u32t* __restrict__ rs, u32t* __restrict__ dh) {
  __shared__ u32t h[64];
  const int t = threadIdx.x;
  if (t < 64) h[t] = 0;
  __syncthreads();
#pragma unroll
  for (int j = 0; j < 4; ++j) {
    const int n = blockIdx.x * 1024 + j * 256 + t;
    if (n < NN) {
      u32t d = rs[n + 1] - rs[n];
      d = d > 63u ? 63u : d;
      atomicAdd(&h[d], 1u);
    }
  }
  __syncthreads();
  if (t < 64 && h[t]) atomicAdd(&dh[t], h[t]);
}

__global__ __launch_bounds__(64) void k_dscan(const u32t* __restrict__ dh, u32t* __restrict__ dc,
                                              u32t* __restrict__ dc0, u32t* __restrict__ ec,
                                              u32t* __restrict__ cur63) {
  __shared__ u32t sn[64], se[64];
  const int t = threadIdx.x;
  const u32t cnt = dh[t];
  sn[t] = cnt;
  se[t] = (t < 63) ? cnt * (u32t)t : 0u;
  __syncthreads();
  for (int off = 1; off < 64; off <<= 1) {
    u32t a = (t >= off) ? sn[t - off] : 0u;
    u32t b = (t >= off) ? se[t - off] : 0u;
    __syncthreads();
    sn[t] += a;
    se[t] += b;
    __syncthreads();
  }
  const u32t nb = (t == 0) ? 0u : sn[t - 1];
  const u32t eb = (t == 0) ? 0u : se[t - 1];
  dc[t] = nb;
  dc0[t] = nb;
  ec[t] = eb;
  if (t == 63) *cur63 = eb;
}

__global__ __launch_bounds__(256) void k_dscatter(const u32t* __restrict__ rs, u32t* __restrict__ dc,
                                                  const u32t* __restrict__ dc0, const u32t* __restrict__ ec,
                                                  u32t* __restrict__ cur63,
                                                  u32t* __restrict__ perm, uint2* __restrict__ nde) {
  __shared__ u32t h[64], base[64];
  const int t = threadIdx.x;
  u32t d[4], loc[4], dt[4];
  if (t < 64) h[t] = 0;
  __syncthreads();
#pragma unroll
  for (int j = 0; j < 4; ++j) {
    const int n = blockIdx.x * 1024 + j * 256 + t;
    if (n < NN) {
      const u32t dtrue = rs[n + 1] - rs[n];
      u32t dd = dtrue > 63u ? 63u : dtrue;
      d[j] = dd;
      dt[j] = dtrue;
      loc[j] = atomicAdd(&h[dd], 1u);
    } else d[j] = 64u;
  }
  __syncthreads();
  if (t < 64) base[t] = h[t] ? atomicAdd(&dc[t], h[t]) : 0u;
  __syncthreads();
#pragma unroll
  for (int j = 0; j < 4; ++j) {
    const int n = blockIdx.x * 1024 + j * 256 + t;
    if (d[j] < 64u) {
      const u32t pos = base[d[j]] + loc[j];
      perm[pos] = (u32t)n;
      u32t eoff;
      if (d[j] < 63u) eoff = ec[d[j]] + (pos - dc0[d[j]]) * d[j];
      else eoff = atomicAdd(cur63, dt[j]);
      nde[pos] = make_uint2(eoff, dt[j]);
    }
  }
}

__global__ __launch_bounds__(256) void k_eperm(const uint2* __restrict__ nde, const u32t* __restrict__ perm,
                                               const u32t* __restrict__ rs, const int* __restrict__ ssrc,
                                               int* __restrict__ ssrc2) {
  const int p = blockIdx.x * 256 + threadIdx.x;
  if (p < NN) {
    const uint2 nd = nde[p];
    const u32t e0 = rs[perm[p]];
    for (u32t j = 0; j < nd.y; ++j) ssrc2[nd.x + j] = ssrc[e0 + j];
  }
}

// ---------------- GNN kernels ----------------

__global__ __launch_bounds__(256) void k_mlp1_first(
    const float* __restrict__ x, const float* __restrict__ W1, u16t* __restrict__ u)
{
  __shared__ float Wt[78 * 33];
  __shared__ float xt_[8 * 79];
  const int t = threadIdx.x;
  for (int id = t; id < 78 * 32; id += 256) {
    int k = id >> 5, c = id & 31;
    Wt[k * 33 + c] = W1[id];
  }
  const int c = t & 31, nl = t >> 5;
  const int ntiles = NN / 8;
  for (int tile = blockIdx.x; tile < ntiles; tile += gridDim.x) {
    const int n0 = tile * 8;
    __syncthreads();
    for (int id = t; id < 8 * 78; id += 256) {
      int r = id / 78, k = id - r * 78;
      xt_[r * 79 + k] = x[(size_t)n0 * 78 + id];
    }
    __syncthreads();
    float acc = 0.f;
    const float* xr = xt_ + nl * 79;
#pragma unroll
    for (int k = 0; k < 78; ++k) acc = fmaf(xr[k], Wt[k * 33 + c], acc);
    u[(size_t)(n0 + nl) * 32 + c] = f2h(acc);
  }
}

// layer0 part B: gather + fp16-MFMA MLP (y = relu(relu(gather+b1) @ W2 + b2))
__global__ __launch_bounds__(256) void k_agg0(
    const u16t* __restrict__ u, const uint2* __restrict__ nde, const int* __restrict__ ssrc2,
    const u32t* __restrict__ perm,
    const float* __restrict__ b1, const float* __restrict__ W2, const float* __restrict__ b2,
    u16t* __restrict__ yout, float* __restrict__ stats_out)
{
  __shared__ __align__(16) u16t W2t[32 * 40];
  __shared__ __align__(16) u16t A1h[64 * 40];
  __shared__ __align__(16) u16t A2h[64 * 40];
  __shared__ float red[256];
  __shared__ u32t pm[64];
  __shared__ uint2 nds[64];
  const int t = threadIdx.x;
  for (int id = t; id < 1024; id += 256) {
    int k = id >> 5, c = id & 31;
    W2t[c * 40 + k] = f2h(W2[id]);
  }
  if (t < 64) {
    pm[t] = perm[blockIdx.x * 64 + t];
    nds[t] = nde[blockIdx.x * 64 + t];
  }
  __syncthreads();
  const int nl = t >> 2, c0 = (t & 3) * 8;
  {
    const int pn = (int)pm[nl];
    float a[8] = {};
    add8h(a, *(const uint4*)(u + (size_t)pn * 32 + c0));
    const u32t e0 = nds[nl].x, e1 = e0 + nds[nl].y;
    u32t e = e0;
    for (; e + 4 <= e1; e += 4) {
      const int s0v = ssrc2[e], s1v = ssrc2[e + 1], s2v = ssrc2[e + 2], s3v = ssrc2[e + 3];
      const uint4 v0 = *(const uint4*)(u + (size_t)s0v * 32 + c0);
      const uint4 v1 = *(const uint4*)(u + (size_t)s1v * 32 + c0);
      const uint4 v2 = *(const uint4*)(u + (size_t)s2v * 32 + c0);
      const uint4 v3 = *(const uint4*)(u + (size_t)s3v * 32 + c0);
      add8h(a, v0); add8h(a, v1); add8h(a, v2); add8h(a, v3);
    }
    for (; e < e1; ++e)
      add8h(a, *(const uint4*)(u + (size_t)ssrc2[e] * 32 + c0));
    union { u16t h[8]; uint4 v; } pk;
#pragma unroll
    for (int j = 0; j < 8; ++j) pk.h[j] = f2h(fmaxf(a[j] + b1[c0 + j], 0.f));
    *(uint4*)(A1h + nl * 40 + c0) = pk.v;
  }
  __syncthreads();
  // MFMA: C[64x32] = A1 @ W2 ; M=node(4x16 tiles,1/wave), N=chout(2x16), K=32
  {
    const int w = t >> 6, l = t & 63, col = l & 15, kg = l >> 4;
    const int m0 = w * 16;
    const f16x8 af = *(const f16x8*)(A1h + (m0 + col) * 40 + kg * 8);
    const f16x8 bf0 = *(const f16x8*)(W2t + col * 40 + kg * 8);
    const f16x8 bf1 = *(const f16x8*)(W2t + (16 + col) * 40 + kg * 8);
    f32x4 ac0 = {0.f, 0.f, 0.f, 0.f}, ac1 = {0.f, 0.f, 0.f, 0.f};
    ac0 = __builtin_amdgcn_mfma_f32_16x16x32_f16(af, bf0, ac0, 0, 0, 0);
    ac1 = __builtin_amdgcn_mfma_f32_16x16x32_f16(af, bf1, ac1, 0, 0, 0);
    const float bb0 = b2[col], bb1 = b2[16 + col];
#pragma unroll
    for (int r = 0; r < 4; ++r) {
      const int m = m0 + kg * 4 + r;
      A2h[m * 40 + col] = f2h(fmaxf(ac0[r] + bb0, 0.f));
      A2h[m * 40 + 16 + col] = f2h(fmaxf(ac1[r] + bb1, 0.f));
    }
  }
  __syncthreads();
  // stats + coalesced writeout
  const int c = t & 31;
  float rsum = 0.f, rq = 0.f;
#pragma unroll
  for (int rep = 0; rep < 8; ++rep) {
    const int row = (t >> 5) + rep * 8;
    const float v = h2f(A2h[row * 40 + c]);
    rsum += v;
    rq += v * v;
  }
  {
    const int row = t >> 2;
    const uint4 v = *(const uint4*)(A2h + row * 40 + (t & 3) * 8);
    *(uint4*)(yout + (size_t)pm[row] * 32 + (t & 3) * 8) = v;
  }
  rsum += __shfl_down(rsum, 32);
  rq += __shfl_down(rq, 32);
  __syncthreads();
  const int wv_ = t >> 6, lane = t & 63;
  if (lane < 32) {
    red[wv_ * 32 + lane] = rsum;
    red[128 + wv_ * 32 + lane] = rq;
  }
  __syncthreads();
  if (t < 32) {
    float aa = red[t] + red[32 + t] + red[64 + t] + red[96 + t];
    float bb = red[128 + t] + red[160 + t] + red[192 + t] + red[224 + t];
    unsafeAtomicAdd(&stats_out[t], aa);
    unsafeAtomicAdd(&stats_out[32 + t], bb);
  }
}

// layers 1..4: gather + BN-affine + two fp16-MFMA MLPs
__global__ __launch_bounds__(256) void k_layer(
    const u16t* __restrict__ yin, const uint2* __restrict__ nde, const int* __restrict__ ssrc2,
    const u32t* __restrict__ perm,
    const float* __restrict__ stats, const float* __restrict__ gamma, const float* __restrict__ beta,
    const float* __restrict__ W1, const float* __restrict__ b1,
    const float* __restrict__ W2, const float* __restrict__ b2,
    u16t* __restrict__ yout, float* __restrict__ stats_out)
{
  __shared__ __align__(16) u16t W1t[32 * 40];
  __shared__ __align__(16) u16t W2t[32 * 40];
  __shared__ __align__(16) u16t A1h[64 * 40];
  __shared__ __align__(16) u16t A2h[64 * 40];
  __shared__ float red[256];
  __shared__ u32t pm[64];
  __shared__ uint2 nds[64];
  const int t = threadIdx.x;
  for (int id = t; id < 1024; id += 256) {
    int k = id >> 5, c = id & 31;
    W1t[c * 40 + k] = f2h(W1[id]);
    W2t[c * 40 + k] = f2h(W2[id]);
  }
  if (t < 64) {
    pm[t] = perm[blockIdx.x * 64 + t];
    nds[t] = nde[blockIdx.x * 64 + t];
  }
  __syncthreads();
  const int nl = t >> 2, c0 = (t & 3) * 8;
  {
    const int pn = (int)pm[nl];
    float sc[8], sh[8];
#pragma unroll
    for (int j = 0; j < 8; ++j) {
      const int c = c0 + j;
      const float mu = stats[c] * (1.f / NN);
      float var = fmaxf(stats[32 + c] * (1.f / NN) - mu * mu, 0.f);
      sc[j] = gamma[c] * rsqrtf(var + BN_EPS);
      sh[j] = beta[c] - mu * sc[j];
    }
    float a[8] = {};
    add8h(a, *(const uint4*)(yin + (size_t)pn * 32 + c0));
    const u32t e0 = nds[nl].x, e1 = e0 + nds[nl].y;
    u32t e = e0;
    for (; e + 4 <= e1; e += 4) {
      const int s0v = ssrc2[e], s1v = ssrc2[e + 1], s2v = ssrc2[e + 2], s3v = ssrc2[e + 3];
      const uint4 v0 = *(const uint4*)(yin + (size_t)s0v * 32 + c0);
      const uint4 v1 = *(const uint4*)(yin + (size_t)s1v * 32 + c0);
      const uint4 v2 = *(const uint4*)(yin + (size_t)s2v * 32 + c0);
      const uint4 v3 = *(const uint4*)(yin + (size_t)s3v * 32 + c0);
      add8h(a, v0); add8h(a, v1); add8h(a, v2); add8h(a, v3);
    }
    for (; e < e1; ++e)
      add8h(a, *(const uint4*)(yin + (size_t)ssrc2[e] * 32 + c0));
    const float cnt = (float)(e1 - e0 + 1u);
    union { u16t h[8]; uint4 v; } pk;
#pragma unroll
    for (int j = 0; j < 8; ++j) pk.h[j] = f2h(sc[j] * a[j] + cnt * sh[j]);
    *(uint4*)(A1h + nl * 40 + c0) = pk.v;
  }
  __syncthreads();
  const int w = t >> 6, l = t & 63, col = l & 15, kg = l >> 4;
  const int m0 = w * 16;
  // matmul1: A2 = relu(A1 @ W1 + b1)
  {
    const f16x8 af = *(const f16x8*)(A1h + (m0 + col) * 40 + kg * 8);
    const f16x8 bf0 = *(const f16x8*)(W1t + col * 40 + kg * 8);
    const f16x8 bf1 = *(const f16x8*)(W1t + (16 + col) * 40 + kg * 8);
    f32x4 ac0 = {0.f, 0.f, 0.f, 0.f}, ac1 = {0.f, 0.f, 0.f, 0.f};
    ac0 = __builtin_amdgcn_mfma_f32_16x16x32_f16(af, bf0, ac0, 0, 0, 0);
    ac1 = __builtin_amdgcn_mfma_f32_16x16x32_f16(af, bf1, ac1, 0, 0, 0);
    const float bb0 = b1[col], bb1 = b1[16 + col];
#pragma unroll
    for (int r = 0; r < 4; ++r) {
      const int m = m0 + kg * 4 + r;
      A2h[m * 40 + col] = f2h(fmaxf(ac0[r] + bb0, 0.f));
      A2h[m * 40 + 16 + col] = f2h(fmaxf(ac1[r] + bb1, 0.f));
    }
  }
  __syncthreads();
  // matmul2: y = relu(A2 @ W2 + b2) -> A1h (reuse)
  {
    const f16x8 af = *(const f16x8*)(A2h + (m0 + col) * 40 + kg * 8);
    const f16x8 bf0 = *(const f16x8*)(W2t + col * 40 + kg * 8);
    const f16x8 bf1 = *(const f16x8*)(W2t + (16 + col) * 40 + kg * 8);
    f32x4 ac0 = {0.f, 0.f, 0.f, 0.f}, ac1 = {0.f, 0.f, 0.f, 0.f};
    ac0 = __builtin_amdgcn_mfma_f32_16x16x32_f16(af, bf0, ac0, 0, 0, 0);
    ac1 = __builtin_amdgcn_mfma_f32_16x16x32_f16(af, bf1, ac1, 0, 0, 0);
    const float bb0 = b2[col], bb1 = b2[16 + col];
#pragma unroll
    for (int r = 0; r < 4; ++r) {
      const int m = m0 + kg * 4 + r;
      A1h[m * 40 + col] = f2h(fmaxf(ac0[r] + bb0, 0.f));
      A1h[m * 40 + 16 + col] = f2h(fmaxf(ac1[r] + bb1, 0.f));
    }
  }
  __syncthreads();
  // stats + coalesced writeout from A1h
  const int c = t & 31;
  float rsum = 0.f, rq = 0.f;
#pragma unroll
  for (int rep = 0; rep < 8; ++rep) {
    const int row = (t >> 5) + rep * 8;
    const float v = h2f(A1h[row * 40 + c]);
    rsum += v;
    rq += v * v;
  }
  {
    const int row = t >> 2;
    const uint4 v = *(const uint4*)(A1h + row * 40 + (t & 3) * 8);
    *(uint4*)(yout + (size_t)pm[row] * 32 + (t & 3) * 8) = v;
  }
  rsum += __shfl_down(rsum, 32);
  rq += __shfl_down(rq, 32);
  __syncthreads();
  const int wv_ = t >> 6, lane = t & 63;
  if (lane < 32) {
    red[wv_ * 32 + lane] = rsum;
    red[128 + wv_ * 32 + lane] = rq;
  }
  __syncthreads();
  if (t < 32) {
    float aa = red[t] + red[32 + t] + red[64 + t] + red[96 + t];
    float bb = red[128 + t] + red[160 + t] + red[192 + t] + red[224 + t];
    unsafeAtomicAdd(&stats_out[t], aa);
    unsafeAtomicAdd(&stats_out[32 + t], bb);
  }
}

__global__ __launch_bounds__(64) void k_pool_xd(
    const u16t* __restrict__ y, const int* __restrict__ batch,
    const float* __restrict__ stats, const float* __restrict__ gamma,
    const float* __restrict__ beta, const float* __restrict__ Wxd,
    const float* __restrict__ bxd, u16t* __restrict__ xc)
{
  const int g = blockIdx.x, t = threadIdx.x;
  int lo = 0, n = NN;
  while (n > 0) {
    int h = n >> 1, m = lo + h;
    if (batch[m] < g) { lo = m + 1; n -= h + 1; } else n = h;
  }
  int hi = lo;
  n = NN - lo;
  while (n > 0) {
    int h = n >> 1, m = hi + h;
    if (batch[m] < g + 1) { hi = m + 1; n -= h + 1; } else n = h;
  }
  const int c = t & 31;
  const float mu = stats[4 * 64 + c] * (1.f / NN);
  float var = fmaxf(stats[4 * 64 + 32 + c] * (1.f / NN) - mu * mu, 0.f);
  const float sc = gamma[4 * 32 + c] * rsqrtf(var + BN_EPS);
  const float sh = beta[4 * 32 + c] - mu * sc;
  float acc = 0.f;
  for (int i = lo + (t >> 5); i < hi; i += 2) acc += h2f(y[(size_t)i * 32 + c]);
  acc += __shfl_down(acc, 32);
  __shared__ float pl[32];
  if (t < 32) pl[t] = acc * sc + (float)(hi - lo) * sh;
  __syncthreads();
#pragma unroll
  for (int rep = 0; rep < 2; ++rep) {
    const int o = t + rep * 64;
    float a = bxd[o];
#pragma unroll
    for (int cc = 0; cc < 32; ++cc) a = fmaf(pl[cc], Wxd[cc * 128 + o], a);
    xc[(size_t)g * 256 + o] = f2bf(fmaxf(a, 0.f));
  }
}

// ---------------- weight prep ----------------
__global__ __launch_bounds__(256) void k_prep(
    const float* __restrict__ w2, const float* __restrict__ w3,
    const float* __restrict__ wxt, const float* __restrict__ wf1, const float* __restrict__ wf2,
    u16t* __restrict__ W2k, u16t* __restrict__ W3k,
    u16t* __restrict__ WXT, u16t* __restrict__ WF1, u16t* __restrict__ WF2)
{
  const int i = blockIdx.x * 256 + threadIdx.x;
  if (i < 64 * 256) {
    int c2 = i >> 8, kk = i & 255, tt = kk >> 5, ci = kk & 31;
    W2k[i] = f2bf(w2[c2 * 256 + ci * 8 + tt]);
  }
  if (i < 128 * 512) {
    int c3 = i >> 9, kk = i & 511, tt = kk >> 6, ci = kk & 63;
    W3k[i] = f2bf(w3[c3 * 512 + ci * 8 + tt]);
  }
  if (i < 128 * 2944) {
    int nn = i / 2944, kk = i - nn * 2944;
    WXT[i] = f2bf(wxt[kk * 128 + nn]);
  }
  if (i < 1024 * 256) {
    int nn = i >> 8, kk = i & 255;
    WF1[i] = f2bf(wf1[kk * 1024 + nn]);
  }
  if (i < 128 * 1024) {
    int nn = i >> 10, kk = i & 1023;
    WF2[i] = f2bf(wf2[kk * 128 + nn]);
  }
}

// ---------------- fused per-graph CNN (unchanged) ----------------
__global__ __launch_bounds__(256, 4) void k_cnn(
    const float* __restrict__ xo,
    const float* __restrict__ w1, const float* __restrict__ b1,
    const u16t* __restrict__ W2k, const float* __restrict__ b2,
    const u16t* __restrict__ W3k, const float* __restrict__ b3,
    u16t* __restrict__ t3)
{
  __shared__ __align__(16) char smem[30720];
  float* xot = (float*)(smem);
  float* w1s = (float*)(smem + 3072);
  float* b2s = (float*)(smem + 4096);
  float* b3s = (float*)(smem + 4352);
  short* T1T = (short*)(smem + 4864);
  char*  T2B = smem + 20736;
  u16t*  stg = (u16t*)(smem + 4864);

  const int g = blockIdx.x, t = threadIdx.x;
  const int w = t >> 6, l = t & 63, col = l & 15, kg = l >> 4;

  for (int i = t; i < 768; i += 256) xot[i] = (i < 735) ? xo[(size_t)g * 735 + i] : 0.f;
  w1s[t] = w1[t];
  if (t < 64) b2s[t] = b2[t];
  if (t < 128) b3s[t] = b3[t];
  if (t < 192) {
    int r = 242 + (t >> 5), c = t & 31;
    T1T[r * 32 + c] = 0;
  }
  __syncthreads();

  {
    const int c = t >> 3, qg = t & 7;
    float wv[8];
#pragma unroll
    for (int j = 0; j < 8; ++j) wv[j] = w1s[c * 8 + j];
    const float bias = b1[c];
    const int q0 = qg * 31, qe = (q0 + 31 < 242) ? q0 + 31 : 242;
#pragma unroll 1
    for (int qc = q0; qc < qe; qc += 10) {
      const int cnt = (qe - qc < 10) ? qe - qc : 10;
      float xv[37];
#pragma unroll
      for (int j = 0; j < 37; ++j) xv[j] = xot[3 * qc + j];
#pragma unroll
      for (int j0 = 0; j0 < 10; ++j0) {
        if (j0 < cnt) {
          float a0 = bias, a1 = bias, a2 = bias;
#pragma unroll
          for (int tt = 0; tt < 8; ++tt) {
            a0 = fmaf(wv[tt], xv[3 * j0 + tt], a0);
            a1 = fmaf(wv[tt], xv[3 * j0 + 1 + tt], a1);
            a2 = fmaf(wv[tt], xv[3 * j0 + 2 + tt], a2);
          }
          float m = fmaxf(fmaxf(a0, a1), fmaxf(a2, 0.f));
          const int pos = qc + j0;
          T1T[pos * 32 + (c ^ ((pos & 3) << 3))] = (short)f2bf(m);
        }
      }
    }
  }
  __syncthreads();

  {
    bf16x8 am[8];
#pragma unroll
    for (int kk = 0; kk < 8; ++kk)
      am[kk] = *(const bf16x8*)(W2k + (w * 16 + col) * 256 + kk * 32 + kg * 8);
#pragma unroll 1
    for (int qt = 0; qt < 5; ++qt) {
      const int rbase = qt * 48 + col * 3;
      bf16x8 rv[10];
#pragma unroll
      for (int s = 0; s < 10; ++s) {
        const int row = rbase + s;
        rv[s] = *(const bf16x8*)(T1T + row * 32 + ((kg ^ (row & 3)) << 3));
      }
      f32x4 a0 = {0.f, 0.f, 0.f, 0.f}, a1 = a0, a2 = a0;
#pragma unroll
      for (int kk = 0; kk < 8; ++kk) {
        a0 = __builtin_amdgcn_mfma_f32_16x16x32_bf16(am[kk], rv[kk], a0, 0, 0, 0);
        a1 = __builtin_amdgcn_mfma_f32_16x16x32_bf16(am[kk], rv[kk + 1], a1, 0, 0, 0);
        a2 = __builtin_amdgcn_mfma_f32_16x16x32_bf16(am[kk], rv[kk + 2], a2, 0, 0, 0);
      }
      const int q = qt * 16 + col;
      if (q < 78) {
        union { u16t u[4]; uint2 v; } pk;
#pragma unroll
        for (int r = 0; r < 4; ++r) {
          const float bb = b2s[w * 16 + kg * 4 + r];
          float m = fmaxf(fmaxf(a0[r], a1[r]), a2[r]);
          pk.u[r] = f2bf(fmaxf(m + bb, 0.f));
        }
        const int boff = (q * 128 + (w * 16 + kg * 4) * 2) ^ ((q & 7) << 4);
        *(uint2*)(T2B + boff) = pk.v;
      }
    }
  }
  __syncthreads();

  {
#pragma unroll 1
    for (int mi = 0; mi < 2; ++mi) {
      const int m3 = w * 2 + mi;
      f32x4 acc[2][3];
#pragma unroll
      for (int qt = 0; qt < 2; ++qt)
#pragma unroll
        for (int r = 0; r < 3; ++r) acc[qt][r] = (f32x4){0.f, 0.f, 0.f, 0.f};
#pragma unroll 1
      for (int kh = 0; kh < 2; ++kh) {
        bf16x8 amh[8];
#pragma unroll
        for (int tt = 0; tt < 8; ++tt)
          amh[tt] = *(const bf16x8*)(W3k + (m3 * 16 + col) * 512 + (tt * 2 + kh) * 32 + kg * 8);
#pragma unroll
        for (int qt = 0; qt < 2; ++qt) {
          const int rbase = qt * 48 + col * 3;
          bf16x8 rv[10];
#pragma unroll
          for (int s = 0; s < 10; ++s) {
            int row = rbase + s;
            row = (row < 78) ? row : 77;
            const int boff = (row * 128 + kh * 64 + kg * 16) ^ ((row & 7) << 4);
            rv[s] = *(const bf16x8*)(T2B + boff);
          }
#pragma unroll
          for (int tt = 0; tt < 8; ++tt) {
            acc[qt][0] = __builtin_amdgcn_mfma_f32_16x16x32_bf16(amh[tt], rv[tt], acc[qt][0], 0, 0, 0);
            acc[qt][1] = __builtin_amdgcn_mfma_f32_16x16x32_bf16(amh[tt], rv[tt + 1], acc[qt][1], 0, 0, 0);
            acc[qt][2] = __builtin_amdgcn_mfma_f32_16x16x32_bf16(amh[tt], rv[tt + 2], acc[qt][2], 0, 0, 0);
          }
        }
      }
#pragma unroll
      for (int qt = 0; qt < 2; ++qt) {
        const int q = qt * 16 + col;
        if (q < 23) {
#pragma unroll
          for (int r = 0; r < 4; ++r) {
            const int c = m3 * 16 + kg * 4 + r;
            float m = fmaxf(fmaxf(acc[qt][0][r], acc[qt][1][r]), acc[qt][2][r]);
            stg[c * 23 + q] = f2bf(fmaxf(m + b3s[c], 0.f));
          }
        }
      }
    }
  }
  __syncthreads();

  {
    const uint4* s4 = (const uint4*)stg;
    uint4* d4 = (uint4*)(t3 + (size_t)g * 2944);
    for (int id = t; id < 368; id += 256) d4[id] = s4[id];
  }
}

// ---------------- bf16 MFMA GEMM ----------------
__global__ __launch_bounds__(256) void k_mgemm(
    const u16t* __restrict__ A, int lda,
    const u16t* __restrict__ WT, const float* __restrict__ bias,
    void* __restrict__ Cv, int ldc, int c_off, int M, int Kd,
    int relu_f, int out32)
{
  __shared__ __align__(16) u16t As[128 * 4 * 8];
  __shared__ __align__(16) u16t Ws2[64 * 4 * 8];
  const int t = threadIdx.x;
  const int w = t >> 6, l = t & 63, col = l & 15, kg = l >> 4;
  const int wm = w & 1, wn = w >> 1;
  const int m0 = blockIdx.x * 128, n0 = blockIdx.y * 64;
  f32x4 acc[4][2];
#pragma unroll
  for (int i = 0; i < 4; ++i)
#pragma unroll
    for (int j = 0; j < 2; ++j) acc[i][j] = (f32x4){0.f, 0.f, 0.f, 0.f};
  const int ar = t >> 1, ac = (t & 1) * 2;
  const int wr = t >> 2, wc = t & 3;
  const bool aok = (m0 + ar) < M;
  const u16t* Ap = A + (size_t)(m0 + ar) * lda;
  const u16t* Wp = WT + (size_t)(n0 + wr) * Kd;
  for (int k0 = 0; k0 < Kd; k0 += 32) {
    bf16x8 av0 = {0, 0, 0, 0, 0, 0, 0, 0}, av1 = {0, 0, 0, 0, 0, 0, 0, 0};
    if (aok) {
      av0 = *(const bf16x8*)(Ap + k0 + ac * 8);
      av1 = *(const bf16x8*)(Ap + k0 + (ac + 1) * 8);
    }
    const bf16x8 wv = *(const bf16x8*)(Wp + k0 + wc * 8);
    __syncthreads();
    *(bf16x8*)(As + (ar * 4 + (ac ^ (ar & 3))) * 8) = av0;
    *(bf16x8*)(As + (ar * 4 + ((ac + 1) ^ (ar & 3))) * 8) = av1;
    *(bf16x8*)(Ws2 + (wr * 4 + (wc ^ (wr & 3))) * 8) = wv;
    __syncthreads();
    bf16x8 af[4], bf[2];
#pragma unroll
    for (int i = 0; i < 4; ++i) {
      const int R = wm * 64 + i * 16 + col;
      af[i] = *(const bf16x8*)(As + (R * 4 + (kg ^ (R & 3))) * 8);
    }
#pragma unroll
    for (int j = 0; j < 2; ++j) {
      const int R = wn * 32 + j * 16 + col;
      bf[j] = *(const bf16x8*)(Ws2 + (R * 4 + (kg ^ (R & 3))) * 8);
    }
#pragma unroll
    for (int i = 0; i < 4; ++i)
#pragma unroll
      for (int j = 0; j < 2; ++j)
        acc[i][j] = __builtin_amdgcn_mfma_f32_16x16x32_bf16(af[i], bf[j], acc[i][j], 0, 0, 0);
  }
#pragma unroll
  for (int j = 0; j < 2; ++j) {
    const int gn = n0 + wn * 32 + j * 16 + col;
    const float bb = bias[gn];
#pragma unroll
    for (int i = 0; i < 4; ++i) {
      const int gmb = m0 + wm * 64 + i * 16 + kg * 4;
#pragma unroll
      for (int r = 0; r < 4; ++r) {
        const int gm = gmb + r;
        if (gm < M) {
          float v = acc[i][j][r] + bb;
          if (relu_f) v = fmaxf(v, 0.f);
          if (out32) ((float*)Cv)[(size_t)gm * ldc + c_off + gn] = v;
          else ((u16t*)Cv)[(size_t)gm * ldc + c_off + gn] = f2bf(v);
        }
      }
    }
  }
}

__global__ __launch_bounds__(256) void k_out(
    const float* __restrict__ h2, const float* __restrict__ Wo,
    const float* __restrict__ bo, float* __restrict__ out)
{
  __shared__ float Ws_[128];
  const int t = threadIdx.x;
  if (t < 128) Ws_[t] = Wo[t];
  __syncthreads();
  const int g = blockIdx.x * 32 + (t >> 3), l = t & 7;
  float acc = 0.f;
  if (g < NG) {
    const float* hr = h2 + (size_t)g * 128 + l * 16;
    const float* wr = Ws_ + l * 16;
#pragma unroll
    for (int j = 0; j < 16; ++j) acc = fmaf(hr[j], wr[j], acc);
  }
  acc += __shfl_down(acc, 4, 8);
  acc += __shfl_down(acc, 2, 8);
  acc += __shfl_down(acc, 1, 8);
  if (l == 0 && g < NG) out[g] = acc + bo[0];
}

extern "C" void kernel_launch(void* const* d_in, const int* in_sizes, int n_in,
                              void* d_out, int out_size, void* d_ws, size_t ws_size,
                              hipStream_t stream) {
  const float* x    = (const float*)d_in[0];
  const int*   ei   = (const int*)d_in[1];
  const int*   batch= (const int*)d_in[2];
  const float* xo   = (const float*)d_in[3];
  const float* g1W1 = (const float*)d_in[4];
  const float* g1b1 = (const float*)d_in[5];
  const float* g1W2 = (const float*)d_in[6];
  const float* g1b2 = (const float*)d_in[7];
  const float* gsW1 = (const float*)d_in[8];
  const float* gsb1 = (const float*)d_in[9];
  const float* gsW2 = (const float*)d_in[10];
  const float* gsb2 = (const float*)d_in[11];
  const float* bng  = (const float*)d_in[12];
  const float* bnb  = (const float*)d_in[13];
  const float* Wxd  = (const float*)d_in[14];
  const float* bxd  = (const float*)d_in[15];
  const float* c1W  = (const float*)d_in[16];
  const float* c1b  = (const float*)d_in[17];
  const float* c2W  = (const float*)d_in[18];
  const float* c2b  = (const float*)d_in[19];
  const float* c3W  = (const float*)d_in[20];
  const float* c3b  = (const float*)d_in[21];
  const float* Wxt  = (const float*)d_in[22];
  const float* bxt  = (const float*)d_in[23];
  const float* W1f  = (const float*)d_in[24];
  const float* b1f  = (const float*)d_in[25];
  const float* W2f  = (const float*)d_in[26];
  const float* b2f  = (const float*)d_in[27];
  const float* Wo   = (const float*)d_in[28];
  const float* bo   = (const float*)d_in[29];

  char* ws = (char*)d_ws;
  u16t*  U    = (u16t*)(ws + OFF_U);
  u16t*  YA   = (u16t*)(ws + OFF_YA);
  u16t*  YB   = (u16t*)(ws + OFF_U);
  uint2* NDE  = (uint2*)(ws + OFF_NDE);
  float* ST   = (float*)(ws + OFF_ST);
  u32t*  RS   = (u32t*)(ws + OFF_RS);
  u32t*  CUR  = (u32t*)(ws + OFF_CUR);
  u32t*  BS   = (u32t*)(ws + OFF_BSUM);
  u32t*  DH   = (u32t*)(ws + OFF_BSUM + 4096);
  u32t*  DC   = (u32t*)(ws + OFF_BSUM + 4352);
  u32t*  DC0  = (u32t*)(ws + OFF_BSUM + 4608);
  u32t*  EC   = (u32t*)(ws + OFF_BSUM + 4864);
  u32t*  C63  = (u32t*)(ws + OFF_BSUM + 5120);
  u32t*  PERM = (u32t*)(ws + OFF_CUR);
  int*   SSRC = (int*)(ws + OFF_SSRC);
  int*   SSRC2= (int*)(ws + OFF_SSRC2);
  u16t*  WK   = (u16t*)(ws + OFF_WK);
  u16t*  W2K  = WK;
  u16t*  W3K  = WK + 16384;
  u16t*  WXT  = WK + 16384 + 65536;
  u16t*  WF1  = WK + 16384 + 65536 + 376832;
  u16t*  WF2  = WK + 16384 + 65536 + 376832 + 262144;
  u16t*  XC   = (u16t*)(ws + OFF_XC);
  u16t*  T3   = (u16t*)(ws + OFF_T3);
  u16t*  H1   = (u16t*)(ws + OFF_H1);
  float* H2   = (float*)(ws + OFF_H2);
  float* OUT  = (float*)d_out;

  const int NBLK = (NN + 1023) / 1024;

  hipMemsetAsync(ST, 0, 5 * 64 * sizeof(float), stream);
  hipMemsetAsync(CUR, 0, NN * sizeof(u32t), stream);
  hipMemsetAsync(DH, 0, 64 * sizeof(u32t), stream);

  k_prep<<<(128 * 2944 + 255) / 256, 256, 0, stream>>>(c2W, c3W, Wxt, W1f, W2f,
                                                        W2K, W3K, WXT, WF1, WF2);

  k_hist<<<(NE + 255) / 256, 256, 0, stream>>>(ei, CUR);
  k_scan1<<<NBLK, 256, 0, stream>>>(CUR, BS);
  k_scan2<<<1, 256, 0, stream>>>(BS, RS, NBLK);
  k_scan3<<<NBLK, 256, 0, stream>>>(CUR, RS, BS);
  k_scatter<<<(NE + 255) / 256, 256, 0, stream>>>(ei, CUR, SSRC);

  k_dhist<<<NBLK, 256, 0, stream>>>(RS, DH);
  k_dscan<<<1, 64, 0, stream>>>(DH, DC, DC0, EC, C63);
  k_dscatter<<<NBLK, 256, 0, stream>>>(RS, DC, DC0, EC, C63, PERM, NDE);
  k_eperm<<<(NN + 255) / 256, 256, 0, stream>>>(NDE, PERM, RS, SSRC, SSRC2);

  k_mlp1_first<<<2048, 256, 0, stream>>>(x, g1W1, U);
  k_agg0<<<NN / 64, 256, 0, stream>>>(U, NDE, SSRC2, PERM, g1b1, g1W2, g1b2, YA, ST + 0);
  const u16t* yin = YA;
  u16t* yout = YB;
  for (int lyr = 1; lyr <= 4; ++lyr) {
    k_layer<<<NN / 64, 256, 0, stream>>>(yin, NDE, SSRC2, PERM, ST + (lyr - 1) * 64,
                                         bng + (lyr - 1) * 32, bnb + (lyr - 1) * 32,
                                         gsW1 + (lyr - 1) * 1024, gsb1 + (lyr - 1) * 32,
                                         gsW2 + (lyr - 1) * 1024, gsb2 + (lyr - 1) * 32,
                                         yout, ST + lyr * 64);
    const u16t* tmp = yin;
    yin = yout;
    yout = (u16t*)tmp;
  }
  k_pool_xd<<<NG, 64, 0, stream>>>(yin, batch, ST, bng, bnb, Wxd, bxd, XC);

  k_cnn<<<NG, 256, 0, stream>>>(xo, c1W, c1b, W2K, c2b, W3K, c3b, T3);

  {
    dim3 grid((NG + 127) / 128, 2);
    k_mgemm<<<grid, 256, 0, stream>>>(T3, 2944, WXT, bxt, XC, 256, 128, NG, 2944, 0, 0);
  }
  {
    dim3 grid((NG + 127) / 128, 16);
    k_mgemm<<<grid, 256, 0, stream>>>(XC, 256, WF1, b1f, H1, 1024, 0, NG, 256, 1, 0);
  }
  {
    dim3 grid((NG + 127) / 128, 2);
    k_mgemm<<<grid, 256, 0, stream>>>(H1, 1024, WF2, b2f, H2, 128, 0, NG, 1024, 1, 1);
  }
  k_out<<<(NG + 31) / 32, 256, 0, stream>>>(H2, Wo, bo, OUT);
}

// Round 13
// 2768.154 us; speedup vs baseline: 1.2456x; 1.0112x over previous
//
#include <hip/hip_runtime.h>

#define NN 1000000
#define NE 4000000
#define NG 25000
#define BN_EPS 1e-5f

typedef unsigned short u16t;
typedef unsigned int u32t;
typedef __attribute__((ext_vector_type(8))) short bf16x8;
typedef __attribute__((ext_vector_type(8))) _Float16 f16x8;
typedef __attribute__((ext_vector_type(4))) float f32x4;

__device__ inline u16t f2bf(float f) {
  u32t u = __float_as_uint(f);
  u32t r = (u + 0x7FFFu + ((u >> 16) & 1u)) >> 16;
  return (u16t)r;
}
__device__ inline float bf2f(u16t h) { return __uint_as_float((u32t)h << 16); }
__device__ inline u16t f2h(float f) {
  _Float16 h = (_Float16)f;
  return *(u16t*)&h;
}
__device__ inline float h2f(u16t v) {
  _Float16 h = *(_Float16*)&v;
  return (float)h;
}
__device__ inline void add8h(float* a, uint4 v) {
  union { uint4 u; _Float16 h[8]; } cv;
  cv.u = v;
#pragma unroll
  for (int j = 0; j < 8; ++j) a[j] += (float)cv.h[j];
}

// ---- workspace layout (bytes) ----
static const size_t OFF_U    = 0;           // fp16 64MB; also YB
static const size_t OFF_YA   = 130000000;
static const size_t OFF_ST   = 258000000;
static const size_t OFF_RS   = 259000000;
static const size_t OFF_CUR  = 263200000;
static const size_t OFF_BSUM = 267300000;
static const size_t OFF_SSRC = 268000000;   // 16MB
static const size_t OFF_WK   = 285000000;
static const size_t OFF_XC   = 287000000;
static const size_t OFF_T3   = 0;
static const size_t OFF_H1   = 150000000;
static const size_t OFF_H2   = 210000000;

// ---------------- CSR build ----------------
__global__ __launch_bounds__(256) void k_hist(const int* __restrict__ ei, u32t* __restrict__ cnt) {
  const int i = blockIdx.x * 256 + threadIdx.x;
  if (i < NE) atomicAdd(&cnt[ei[NE + i]], 1u);
}

__global__ __launch_bounds__(256) void k_scan1(const u32t* __restrict__ deg, u32t* __restrict__ bsum) {
  __shared__ u32t red[4];
  const int b = blockIdx.x, t = threadIdx.x;
  u32t s = 0;
#pragma unroll
  for (int j = 0; j < 4; ++j) {
    const int i = b * 1024 + j * 256 + t;
    if (i < NN) s += deg[i];
  }
#pragma unroll
  for (int off = 32; off > 0; off >>= 1) s += __shfl_down(s, off);
  if ((t & 63) == 0) red[t >> 6] = s;
  __syncthreads();
  if (t == 0) bsum[b] = red[0] + red[1] + red[2] + red[3];
}

__global__ __launch_bounds__(256) void k_scan2(u32t* __restrict__ bsum, u32t* __restrict__ rs, int nblk) {
  __shared__ u32t sh[256];
  const int t = threadIdx.x;
  u32t v[4];
#pragma unroll
  for (int j = 0; j < 4; ++j) {
    const int i = t * 4 + j;
    v[j] = (i < nblk) ? bsum[i] : 0u;
  }
  const u32t tot = v[0] + v[1] + v[2] + v[3];
  sh[t] = tot;
  __syncthreads();
  for (int off = 1; off < 256; off <<= 1) {
    u32t add = (t >= off) ? sh[t - off] : 0u;
    __syncthreads();
    sh[t] += add;
    __syncthreads();
  }
  const u32t tb = (t == 0) ? 0u : sh[t - 1];
  u32t run = tb;
#pragma unroll
  for (int j = 0; j < 4; ++j) {
    const int i = t * 4 + j;
    if (i < nblk) bsum[i] = run;
    run += v[j];
  }
  if (t == 0) rs[NN] = NE;
}

__global__ __launch_bounds__(256) void k_scan3(u32t* __restrict__ cur, u32t* __restrict__ rs,
                                               const u32t* __restrict__ bsum) {
  __shared__ u32t sh[256];
  const int b = blockIdx.x, t = threadIdx.x;
  const int i0 = b * 1024 + t * 4;
  u32t v[4];
#pragma unroll
  for (int j = 0; j < 4; ++j) v[j] = (i0 + j < NN) ? cur[i0 + j] : 0u;
  sh[t] = v[0] + v[1] + v[2] + v[3];
  __syncthreads();
  for (int off = 1; off < 256; off <<= 1) {
    u32t add = (t >= off) ? sh[t - off] : 0u;
    __syncthreads();
    sh[t] += add;
    __syncthreads();
  }
  u32t run = bsum[b] + ((t == 0) ? 0u : sh[t - 1]);
#pragma unroll
  for (int j = 0; j < 4; ++j) {
    const int i = i0 + j;
    if (i < NN) { rs[i] = run; cur[i] = run; }
    run += v[j];
  }
}

__global__ __launch_bounds__(256) void k_scatter(const int* __restrict__ ei,
                                                 u32t* __restrict__ cur, int* __restrict__ ssrc) {
  const int i = blockIdx.x * 256 + threadIdx.x;
  if (i < NE) {
    const int src = ei[i], dst = ei[NE + i];
    const u32t pos = atomicAdd(&cur[dst], 1u);
    ssrc[pos] = src;
  }
}

// ---------------- GNN kernels ----------------

__global__ __launch_bounds__(256) void k_mlp1_first(
    const float* __restrict__ x, const float* __restrict__ W1, u16t* __restrict__ u)
{
  __shared__ float Wt[78 * 33];
  __shared__ float xt_[8 * 79];
  const int t = threadIdx.x;
  for (int id = t; id < 78 * 32; id += 256) {
    int k = id >> 5, c = id & 31;
    Wt[k * 33 + c] = W1[id];
  }
  const int c = t & 31, nl = t >> 5;
  const int ntiles = NN / 8;
  for (int tile = blockIdx.x; tile < ntiles; tile += gridDim.x) {
    const int n0 = tile * 8;
    __syncthreads();
    for (int id = t; id < 8 * 78; id += 256) {
      int r = id / 78, k = id - r * 78;
      xt_[r * 79 + k] = x[(size_t)n0 * 78 + id];
    }
    __syncthreads();
    float acc = 0.f;
    const float* xr = xt_ + nl * 79;
#pragma unroll
    for (int k = 0; k < 78; ++k) acc = fmaf(xr[k], Wt[k * 33 + c], acc);
    u[(size_t)(n0 + nl) * 32 + c] = f2h(acc);
  }
}

// layer0 part B: gather (direct CSR) + fp16-MFMA MLP
__global__ __launch_bounds__(256) void k_agg0(
    const u16t* __restrict__ u, const u32t* __restrict__ rs, const int* __restrict__ ssrc,
    const float* __restrict__ b1, const float* __restrict__ W2, const float* __restrict__ b2,
    u16t* __restrict__ yout, float* __restrict__ stats_out)
{
  __shared__ __align__(16) u16t W2t[32 * 40];
  __shared__ __align__(16) u16t A1h[64 * 40];
  __shared__ __align__(16) u16t A2h[64 * 40];
  __shared__ float red[256];
  __shared__ u32t rss[65];
  const int t = threadIdx.x;
  const int n0b = blockIdx.x * 64;
  for (int id = t; id < 1024; id += 256) {
    int k = id >> 5, c = id & 31;
    W2t[c * 40 + k] = f2h(W2[id]);
  }
  if (t < 65) rss[t] = rs[n0b + t];
  __syncthreads();
  const int nl = t >> 2, c0 = (t & 3) * 8;
  {
    const int n = n0b + nl;
    float a[8] = {};
    add8h(a, *(const uint4*)(u + (size_t)n * 32 + c0));
    const u32t e0 = rss[nl], e1 = rss[nl + 1];
    u32t e = e0;
    for (; e + 4 <= e1; e += 4) {
      const int s0v = ssrc[e], s1v = ssrc[e + 1], s2v = ssrc[e + 2], s3v = ssrc[e + 3];
      const uint4 v0 = *(const uint4*)(u + (size_t)s0v * 32 + c0);
      const uint4 v1 = *(const uint4*)(u + (size_t)s1v * 32 + c0);
      const uint4 v2 = *(const uint4*)(u + (size_t)s2v * 32 + c0);
      const uint4 v3 = *(const uint4*)(u + (size_t)s3v * 32 + c0);
      add8h(a, v0); add8h(a, v1); add8h(a, v2); add8h(a, v3);
    }
    for (; e < e1; ++e)
      add8h(a, *(const uint4*)(u + (size_t)ssrc[e] * 32 + c0));
    union { u16t h[8]; uint4 v; } pk;
#pragma unroll
    for (int j = 0; j < 8; ++j) pk.h[j] = f2h(fmaxf(a[j] + b1[c0 + j], 0.f));
    *(uint4*)(A1h + nl * 40 + c0) = pk.v;
  }
  __syncthreads();
  // MFMA: C[64x32] = A1 @ W2
  {
    const int w = t >> 6, l = t & 63, col = l & 15, kg = l >> 4;
    const int m0 = w * 16;
    const f16x8 af = *(const f16x8*)(A1h + (m0 + col) * 40 + kg * 8);
    const f16x8 bf0 = *(const f16x8*)(W2t + col * 40 + kg * 8);
    const f16x8 bf1 = *(const f16x8*)(W2t + (16 + col) * 40 + kg * 8);
    f32x4 ac0 = {0.f, 0.f, 0.f, 0.f}, ac1 = {0.f, 0.f, 0.f, 0.f};
    ac0 = __builtin_amdgcn_mfma_f32_16x16x32_f16(af, bf0, ac0, 0, 0, 0);
    ac1 = __builtin_amdgcn_mfma_f32_16x16x32_f16(af, bf1, ac1, 0, 0, 0);
    const float bb0 = b2[col], bb1 = b2[16 + col];
#pragma unroll
    for (int r = 0; r < 4; ++r) {
      const int m = m0 + kg * 4 + r;
      A2h[m * 40 + col] = f2h(fmaxf(ac0[r] + bb0, 0.f));
      A2h[m * 40 + 16 + col] = f2h(fmaxf(ac1[r] + bb1, 0.f));
    }
  }
  __syncthreads();
  const int c = t & 31;
  float rsum = 0.f, rq = 0.f;
#pragma unroll
  for (int rep = 0; rep < 8; ++rep) {
    const int row = (t >> 5) + rep * 8;
    const float v = h2f(A2h[row * 40 + c]);
    rsum += v;
    rq += v * v;
  }
  {
    const int row = t >> 2;
    const uint4 v = *(const uint4*)(A2h + row * 40 + (t & 3) * 8);
    *(uint4*)(yout + (size_t)(n0b + row) * 32 + (t & 3) * 8) = v;
  }
  rsum += __shfl_down(rsum, 32);
  rq += __shfl_down(rq, 32);
  __syncthreads();
  const int wv_ = t >> 6, lane = t & 63;
  if (lane < 32) {
    red[wv_ * 32 + lane] = rsum;
    red[128 + wv_ * 32 + lane] = rq;
  }
  __syncthreads();
  if (t < 32) {
    float aa = red[t] + red[32 + t] + red[64 + t] + red[96 + t];
    float bb = red[128 + t] + red[160 + t] + red[192 + t] + red[224 + t];
    unsafeAtomicAdd(&stats_out[t], aa);
    unsafeAtomicAdd(&stats_out[32 + t], bb);
  }
}

// layers 1..4: gather (direct CSR) + BN-affine + two fp16-MFMA MLPs
__global__ __launch_bounds__(256) void k_layer(
    const u16t* __restrict__ yin, const u32t* __restrict__ rs, const int* __restrict__ ssrc,
    const float* __restrict__ stats, const float* __restrict__ gamma, const float* __restrict__ beta,
    const float* __restrict__ W1, const float* __restrict__ b1,
    const float* __restrict__ W2, const float* __restrict__ b2,
    u16t* __restrict__ yout, float* __restrict__ stats_out)
{
  __shared__ __align__(16) u16t W1t[32 * 40];
  __shared__ __align__(16) u16t W2t[32 * 40];
  __shared__ __align__(16) u16t A1h[64 * 40];
  __shared__ __align__(16) u16t A2h[64 * 40];
  __shared__ float red[256];
  __shared__ u32t rss[65];
  const int t = threadIdx.x;
  const int n0b = blockIdx.x * 64;
  for (int id = t; id < 1024; id += 256) {
    int k = id >> 5, c = id & 31;
    W1t[c * 40 + k] = f2h(W1[id]);
    W2t[c * 40 + k] = f2h(W2[id]);
  }
  if (t < 65) rss[t] = rs[n0b + t];
  __syncthreads();
  const int nl = t >> 2, c0 = (t & 3) * 8;
  {
    const int n = n0b + nl;
    float sc[8], sh[8];
#pragma unroll
    for (int j = 0; j < 8; ++j) {
      const int c = c0 + j;
      const float mu = stats[c] * (1.f / NN);
      float var = fmaxf(stats[32 + c] * (1.f / NN) - mu * mu, 0.f);
      sc[j] = gamma[c] * rsqrtf(var + BN_EPS);
      sh[j] = beta[c] - mu * sc[j];
    }
    float a[8] = {};
    add8h(a, *(const uint4*)(yin + (size_t)n * 32 + c0));
    const u32t e0 = rss[nl], e1 = rss[nl + 1];
    u32t e = e0;
    for (; e + 4 <= e1; e += 4) {
      const int s0v = ssrc[e], s1v = ssrc[e + 1], s2v = ssrc[e + 2], s3v = ssrc[e + 3];
      const uint4 v0 = *(const uint4*)(yin + (size_t)s0v * 32 + c0);
      const uint4 v1 = *(const uint4*)(yin + (size_t)s1v * 32 + c0);
      const uint4 v2 = *(const uint4*)(yin + (size_t)s2v * 32 + c0);
      const uint4 v3 = *(const uint4*)(yin + (size_t)s3v * 32 + c0);
      add8h(a, v0); add8h(a, v1); add8h(a, v2); add8h(a, v3);
    }
    for (; e < e1; ++e)
      add8h(a, *(const uint4*)(yin + (size_t)ssrc[e] * 32 + c0));
    const float cnt = (float)(e1 - e0 + 1u);
    union { u16t h[8]; uint4 v; } pk;
#pragma unroll
    for (int j = 0; j < 8; ++j) pk.h[j] = f2h(sc[j] * a[j] + cnt * sh[j]);
    *(uint4*)(A1h + nl * 40 + c0) = pk.v;
  }
  __syncthreads();
  const int w = t >> 6, l = t & 63, col = l & 15, kg = l >> 4;
  const int m0 = w * 16;
  // matmul1: A2 = relu(A1 @ W1 + b1)
  {
    const f16x8 af = *(const f16x8*)(A1h + (m0 + col) * 40 + kg * 8);
    const f16x8 bf0 = *(const f16x8*)(W1t + col * 40 + kg * 8);
    const f16x8 bf1 = *(const f16x8*)(W1t + (16 + col) * 40 + kg * 8);
    f32x4 ac0 = {0.f, 0.f, 0.f, 0.f}, ac1 = {0.f, 0.f, 0.f, 0.f};
    ac0 = __builtin_amdgcn_mfma_f32_16x16x32_f16(af, bf0, ac0, 0, 0, 0);
    ac1 = __builtin_amdgcn_mfma_f32_16x16x32_f16(af, bf1, ac1, 0, 0, 0);
    const float bb0 = b1[col], bb1 = b1[16 + col];
#pragma unroll
    for (int r = 0; r < 4; ++r) {
      const int m = m0 + kg * 4 + r;
      A2h[m * 40 + col] = f2h(fmaxf(ac0[r] + bb0, 0.f));
      A2h[m * 40 + 16 + col] = f2h(fmaxf(ac1[r] + bb1, 0.f));
    }
  }
  __syncthreads();
  // matmul2: y = relu(A2 @ W2 + b2) -> A1h (reuse)
  {
    const f16x8 af = *(const f16x8*)(A2h + (m0 + col) * 40 + kg * 8);
    const f16x8 bf0 = *(const f16x8*)(W2t + col * 40 + kg * 8);
    const f16x8 bf1 = *(const f16x8*)(W2t + (16 + col) * 40 + kg * 8);
    f32x4 ac0 = {0.f, 0.f, 0.f, 0.f}, ac1 = {0.f, 0.f, 0.f, 0.f};
    ac0 = __builtin_amdgcn_mfma_f32_16x16x32_f16(af, bf0, ac0, 0, 0, 0);
    ac1 = __builtin_amdgcn_mfma_f32_16x16x32_f16(af, bf1, ac1, 0, 0, 0);
    const float bb0 = b2[col], bb1 = b2[16 + col];
#pragma unroll
    for (int r = 0; r < 4; ++r) {
      const int m = m0 + kg * 4 + r;
      A1h[m * 40 + col] = f2h(fmaxf(ac0[r] + bb0, 0.f));
      A1h[m * 40 + 16 + col] = f2h(fmaxf(ac1[r] + bb1, 0.f));
    }
  }
  __syncthreads();
  const int c = t & 31;
  float rsum = 0.f, rq = 0.f;
#pragma unroll
  for (int rep = 0; rep < 8; ++rep) {
    const int row = (t >> 5) + rep * 8;
    const float v = h2f(A1h[row * 40 + c]);
    rsum += v;
    rq += v * v;
  }
  {
    const int row = t >> 2;
    const uint4 v = *(const uint4*)(A1h + row * 40 + (t & 3) * 8);
    *(uint4*)(yout + (size_t)(n0b + row) * 32 + (t & 3) * 8) = v;
  }
  rsum += __shfl_down(rsum, 32);
  rq += __shfl_down(rq, 32);
  __syncthreads();
  const int wv_ = t >> 6, lane = t & 63;
  if (lane < 32) {
    red[wv_ * 32 + lane] = rsum;
    red[128 + wv_ * 32 + lane] = rq;
  }
  __syncthreads();
  if (t < 32) {
    float aa = red[t] + red[32 + t] + red[64 + t] + red[96 + t];
    float bb = red[128 + t] + red[160 + t] + red[192 + t] + red[224 + t];
    unsafeAtomicAdd(&stats_out[t], aa);
    unsafeAtomicAdd(&stats_out[32 + t], bb);
  }
}

__global__ __launch_bounds__(64) void k_pool_xd(
    const u16t* __restrict__ y, const int* __restrict__ batch,
    const float* __restrict__ stats, const float* __restrict__ gamma,
    const float* __restrict__ beta, const float* __restrict__ Wxd,
    const float* __restrict__ bxd, u16t* __restrict__ xc)
{
  const int g = blockIdx.x, t = threadIdx.x;
  int lo = 0, n = NN;
  while (n > 0) {
    int h = n >> 1, m = lo + h;
    if (batch[m] < g) { lo = m + 1; n -= h + 1; } else n = h;
  }
  int hi = lo;
  n = NN - lo;
  while (n > 0) {
    int h = n >> 1, m = hi + h;
    if (batch[m] < g + 1) { hi = m + 1; n -= h + 1; } else n = h;
  }
  const int c = t & 31;
  const float mu = stats[4 * 64 + c] * (1.f / NN);
  float var = fmaxf(stats[4 * 64 + 32 + c] * (1.f / NN) - mu * mu, 0.f);
  const float sc = gamma[4 * 32 + c] * rsqrtf(var + BN_EPS);
  const float sh = beta[4 * 32 + c] - mu * sc;
  float acc = 0.f;
  for (int i = lo + (t >> 5); i < hi; i += 2) acc += h2f(y[(size_t)i * 32 + c]);
  acc += __shfl_down(acc, 32);
  __shared__ float pl[32];
  if (t < 32) pl[t] = acc * sc + (float)(hi - lo) * sh;
  __syncthreads();
#pragma unroll
  for (int rep = 0; rep < 2; ++rep) {
    const int o = t + rep * 64;
    float a = bxd[o];
#pragma unroll
    for (int cc = 0; cc < 32; ++cc) a = fmaf(pl[cc], Wxd[cc * 128 + o], a);
    xc[(size_t)g * 256 + o] = f2bf(fmaxf(a, 0.f));
  }
}

// ---------------- weight prep ----------------
__global__ __launch_bounds__(256) void k_prep(
    const float* __restrict__ w2, const float* __restrict__ w3,
    const float* __restrict__ wxt, const float* __restrict__ wf1, const float* __restrict__ wf2,
    u16t* __restrict__ W2k, u16t* __restrict__ W3k,
    u16t* __restrict__ WXT, u16t* __restrict__ WF1, u16t* __restrict__ WF2)
{
  const int i = blockIdx.x * 256 + threadIdx.x;
  if (i < 64 * 256) {
    int c2 = i >> 8, kk = i & 255, tt = kk >> 5, ci = kk & 31;
    W2k[i] = f2bf(w2[c2 * 256 + ci * 8 + tt]);
  }
  if (i < 128 * 512) {
    int c3 = i >> 9, kk = i & 511, tt = kk >> 6, ci = kk & 63;
    W3k[i] = f2bf(w3[c3 * 512 + ci * 8 + tt]);
  }
  if (i < 128 * 2944) {
    int nn = i / 2944, kk = i - nn * 2944;
    WXT[i] = f2bf(wxt[kk * 128 + nn]);
  }
  if (i < 1024 * 256) {
    int nn = i >> 8, kk = i & 255;
    WF1[i] = f2bf(wf1[kk * 1024 + nn]);
  }
  if (i < 128 * 1024) {
    int nn = i >> 10, kk = i & 1023;
    WF2[i] = f2bf(wf2[kk * 128 + nn]);
  }
}

// ---------------- fused per-graph CNN (unchanged) ----------------
__global__ __launch_bounds__(256, 4) void k_cnn(
    const float* __restrict__ xo,
    const float* __restrict__ w1, const float* __restrict__ b1,
    const u16t* __restrict__ W2k, const float* __restrict__ b2,
    const u16t* __restrict__ W3k, const float* __restrict__ b3,
    u16t* __restrict__ t3)
{
  __shared__ __align__(16) char smem[30720];
  float* xot = (float*)(smem);
  float* w1s = (float*)(smem + 3072);
  float* b2s = (float*)(smem + 4096);
  float* b3s = (float*)(smem + 4352);
  short* T1T = (short*)(smem + 4864);
  char*  T2B = smem + 20736;
  u16t*  stg = (u16t*)(smem + 4864);

  const int g = blockIdx.x, t = threadIdx.x;
  const int w = t >> 6, l = t & 63, col = l & 15, kg = l >> 4;

  for (int i = t; i < 768; i += 256) xot[i] = (i < 735) ? xo[(size_t)g * 735 + i] : 0.f;
  w1s[t] = w1[t];
  if (t < 64) b2s[t] = b2[t];
  if (t < 128) b3s[t] = b3[t];
  if (t < 192) {
    int r = 242 + (t >> 5), c = t & 31;
    T1T[r * 32 + c] = 0;
  }
  __syncthreads();

  {
    const int c = t >> 3, qg = t & 7;
    float wv[8];
#pragma unroll
    for (int j = 0; j < 8; ++j) wv[j] = w1s[c * 8 + j];
    const float bias = b1[c];
    const int q0 = qg * 31, qe = (q0 + 31 < 242) ? q0 + 31 : 242;
#pragma unroll 1
    for (int qc = q0; qc < qe; qc += 10) {
      const int cnt = (qe - qc < 10) ? qe - qc : 10;
      float xv[37];
#pragma unroll
      for (int j = 0; j < 37; ++j) xv[j] = xot[3 * qc + j];
#pragma unroll
      for (int j0 = 0; j0 < 10; ++j0) {
        if (j0 < cnt) {
          float a0 = bias, a1 = bias, a2 = bias;
#pragma unroll
          for (int tt = 0; tt < 8; ++tt) {
            a0 = fmaf(wv[tt], xv[3 * j0 + tt], a0);
            a1 = fmaf(wv[tt], xv[3 * j0 + 1 + tt], a1);
            a2 = fmaf(wv[tt], xv[3 * j0 + 2 + tt], a2);
          }
          float m = fmaxf(fmaxf(a0, a1), fmaxf(a2, 0.f));
          const int pos = qc + j0;
          T1T[pos * 32 + (c ^ ((pos & 3) << 3))] = (short)f2bf(m);
        }
      }
    }
  }
  __syncthreads();

  {
    bf16x8 am[8];
#pragma unroll
    for (int kk = 0; kk < 8; ++kk)
      am[kk] = *(const bf16x8*)(W2k + (w * 16 + col) * 256 + kk * 32 + kg * 8);
#pragma unroll 1
    for (int qt = 0; qt < 5; ++qt) {
      const int rbase = qt * 48 + col * 3;
      bf16x8 rv[10];
#pragma unroll
      for (int s = 0; s < 10; ++s) {
        const int row = rbase + s;
        rv[s] = *(const bf16x8*)(T1T + row * 32 + ((kg ^ (row & 3)) << 3));
      }
      f32x4 a0 = {0.f, 0.f, 0.f, 0.f}, a1 = a0, a2 = a0;
#pragma unroll
      for (int kk = 0; kk < 8; ++kk) {
        a0 = __builtin_amdgcn_mfma_f32_16x16x32_bf16(am[kk], rv[kk], a0, 0, 0, 0);
        a1 = __builtin_amdgcn_mfma_f32_16x16x32_bf16(am[kk], rv[kk + 1], a1, 0, 0, 0);
        a2 = __builtin_amdgcn_mfma_f32_16x16x32_bf16(am[kk], rv[kk + 2], a2, 0, 0, 0);
      }
      const int q = qt * 16 + col;
      if (q < 78) {
        union { u16t u[4]; uint2 v; } pk;
#pragma unroll
        for (int r = 0; r < 4; ++r) {
          const float bb = b2s[w * 16 + kg * 4 + r];
          float m = fmaxf(fmaxf(a0[r], a1[r]), a2[r]);
          pk.u[r] = f2bf(fmaxf(m + bb, 0.f));
        }
        const int boff = (q * 128 + (w * 16 + kg * 4) * 2) ^ ((q & 7) << 4);
        *(uint2*)(T2B + boff) = pk.v;
      }
    }
  }
  __syncthreads();

  {
#pragma unroll 1
    for (int mi = 0; mi < 2; ++mi) {
      const int m3 = w * 2 + mi;
      f32x4 acc[2][3];
#pragma unroll
      for (int qt = 0; qt < 2; ++qt)
#pragma unroll
        for (int r = 0; r < 3; ++r) acc[qt][r] = (f32x4){0.f, 0.f, 0.f, 0.f};
#pragma unroll 1
      for (int kh = 0; kh < 2; ++kh) {
        bf16x8 amh[8];
#pragma unroll
        for (int tt = 0; tt < 8; ++tt)
          amh[tt] = *(const bf16x8*)(W3k + (m3 * 16 + col) * 512 + (tt * 2 + kh) * 32 + kg * 8);
#pragma unroll
        for (int qt = 0; qt < 2; ++qt) {
          const int rbase = qt * 48 + col * 3;
          bf16x8 rv[10];
#pragma unroll
          for (int s = 0; s < 10; ++s) {
            int row = rbase + s;
            row = (row < 78) ? row : 77;
            const int boff = (row * 128 + kh * 64 + kg * 16) ^ ((row & 7) << 4);
            rv[s] = *(const bf16x8*)(T2B + boff);
          }
#pragma unroll
          for (int tt = 0; tt < 8; ++tt) {
            acc[qt][0] = __builtin_amdgcn_mfma_f32_16x16x32_bf16(amh[tt], rv[tt], acc[qt][0], 0, 0, 0);
            acc[qt][1] = __builtin_amdgcn_mfma_f32_16x16x32_bf16(amh[tt], rv[tt + 1], acc[qt][1], 0, 0, 0);
            acc[qt][2] = __builtin_amdgcn_mfma_f32_16x16x32_bf16(amh[tt], rv[tt + 2], acc[qt][2], 0, 0, 0);
          }
        }
      }
#pragma unroll
      for (int qt = 0; qt < 2; ++qt) {
        const int q = qt * 16 + col;
        if (q < 23) {
#pragma unroll
          for (int r = 0; r < 4; ++r) {
            const int c = m3 * 16 + kg * 4 + r;
            float m = fmaxf(fmaxf(acc[qt][0][r], acc[qt][1][r]), acc[qt][2][r]);
            stg[c * 23 + q] = f2bf(fmaxf(m + b3s[c], 0.f));
          }
        }
      }
    }
  }
  __syncthreads();

  {
    const uint4* s4 = (const uint4*)stg;
    uint4* d4 = (uint4*)(t3 + (size_t)g * 2944);
    for (int id = t; id < 368; id += 256) d4[id] = s4[id];
  }
}

// ---------------- bf16 MFMA GEMM ----------------
__global__ __launch_bounds__(256) void k_mgemm(
    const u16t* __restrict__ A, int lda,
    const u16t* __restrict__ WT, const float* __restrict__ bias,
    void* __restrict__ Cv, int ldc, int c_off, int M, int Kd,
    int relu_f, int out32)
{
  __shared__ __align__(16) u16t As[128 * 4 * 8];
  __shared__ __align__(16) u16t Ws2[64 * 4 * 8];
  const int t = threadIdx.x;
  const int w = t >> 6, l = t & 63, col = l & 15, kg = l >> 4;
  const int wm = w & 1, wn = w >> 1;
  const int m0 = blockIdx.x * 128, n0 = blockIdx.y * 64;
  f32x4 acc[4][2];
#pragma unroll
  for (int i = 0; i < 4; ++i)
#pragma unroll
    for (int j = 0; j < 2; ++j) acc[i][j] = (f32x4){0.f, 0.f, 0.f, 0.f};
  const int ar = t >> 1, ac = (t & 1) * 2;
  const int wr = t >> 2, wc = t & 3;
  const bool aok = (m0 + ar) < M;
  const u16t* Ap = A + (size_t)(m0 + ar) * lda;
  const u16t* Wp = WT + (size_t)(n0 + wr) * Kd;
  for (int k0 = 0; k0 < Kd; k0 += 32) {
    bf16x8 av0 = {0, 0, 0, 0, 0, 0, 0, 0}, av1 = {0, 0, 0, 0, 0, 0, 0, 0};
    if (aok) {
      av0 = *(const bf16x8*)(Ap + k0 + ac * 8);
      av1 = *(const bf16x8*)(Ap + k0 + (ac + 1) * 8);
    }
    const bf16x8 wv = *(const bf16x8*)(Wp + k0 + wc * 8);
    __syncthreads();
    *(bf16x8*)(As + (ar * 4 + (ac ^ (ar & 3))) * 8) = av0;
    *(bf16x8*)(As + (ar * 4 + ((ac + 1) ^ (ar & 3))) * 8) = av1;
    *(bf16x8*)(Ws2 + (wr * 4 + (wc ^ (wr & 3))) * 8) = wv;
    __syncthreads();
    bf16x8 af[4], bf[2];
#pragma unroll
    for (int i = 0; i < 4; ++i) {
      const int R = wm * 64 + i * 16 + col;
      af[i] = *(const bf16x8*)(As + (R * 4 + (kg ^ (R & 3))) * 8);
    }
#pragma unroll
    for (int j = 0; j < 2; ++j) {
      const int R = wn * 32 + j * 16 + col;
      bf[j] = *(const bf16x8*)(Ws2 + (R * 4 + (kg ^ (R & 3))) * 8);
    }
#pragma unroll
    for (int i = 0; i < 4; ++i)
#pragma unroll
      for (int j = 0; j < 2; ++j)
        acc[i][j] = __builtin_amdgcn_mfma_f32_16x16x32_bf16(af[i], bf[j], acc[i][j], 0, 0, 0);
  }
#pragma unroll
  for (int j = 0; j < 2; ++j) {
    const int gn = n0 + wn * 32 + j * 16 + col;
    const float bb = bias[gn];
#pragma unroll
    for (int i = 0; i < 4; ++i) {
      const int gmb = m0 + wm * 64 + i * 16 + kg * 4;
#pragma unroll
      for (int r = 0; r < 4; ++r) {
        const int gm = gmb + r;
        if (gm < M) {
          float v = acc[i][j][r] + bb;
          if (relu_f) v = fmaxf(v, 0.f);
          if (out32) ((float*)Cv)[(size_t)gm * ldc + c_off + gn] = v;
          else ((u16t*)Cv)[(size_t)gm * ldc + c_off + gn] = f2bf(v);
        }
      }
    }
  }
}

__global__ __launch_bounds__(256) void k_out(
    const float* __restrict__ h2, const float* __restrict__ Wo,
    const float* __restrict__ bo, float* __restrict__ out)
{
  __shared__ float Ws_[128];
  const int t = threadIdx.x;
  if (t < 128) Ws_[t] = Wo[t];
  __syncthreads();
  const int g = blockIdx.x * 32 + (t >> 3), l = t & 7;
  float acc = 0.f;
  if (g < NG) {
    const float* hr = h2 + (size_t)g * 128 + l * 16;
    const float* wr = Ws_ + l * 16;
#pragma unroll
    for (int j = 0; j < 16; ++j) acc = fmaf(hr[j], wr[j], acc);
  }
  acc += __shfl_down(acc, 4, 8);
  acc += __shfl_down(acc, 2, 8);
  acc += __shfl_down(acc, 1, 8);
  if (l == 0 && g < NG) out[g] = acc + bo[0];
}

extern "C" void kernel_launch(void* const* d_in, const int* in_sizes, int n_in,
                              void* d_out, int out_size, void* d_ws, size_t ws_size,
                              hipStream_t stream) {
  const float* x    = (const float*)d_in[0];
  const int*   ei   = (const int*)d_in[1];
  const int*   batch= (const int*)d_in[2];
  const float* xo   = (const float*)d_in[3];
  const float* g1W1 = (const float*)d_in[4];
  const float* g1b1 = (const float*)d_in[5];
  const float* g1W2 = (const float*)d_in[6];
  const float* g1b2 = (const float*)d_in[7];
  const float* gsW1 = (const float*)d_in[8];
  const float* gsb1 = (const float*)d_in[9];
  const float* gsW2 = (const float*)d_in[10];
  const float* gsb2 = (const float*)d_in[11];
  const float* bng  = (const float*)d_in[12];
  const float* bnb  = (const float*)d_in[13];
  const float* Wxd  = (const float*)d_in[14];
  const float* bxd  = (const float*)d_in[15];
  const float* c1W  = (const float*)d_in[16];
  const float* c1b  = (const float*)d_in[17];
  const float* c2W  = (const float*)d_in[18];
  const float* c2b  = (const float*)d_in[19];
  const float* c3W  = (const float*)d_in[20];
  const float* c3b  = (const float*)d_in[21];
  const float* Wxt  = (const float*)d_in[22];
  const float* bxt  = (const float*)d_in[23];
  const float* W1f  = (const float*)d_in[24];
  const float* b1f  = (const float*)d_in[25];
  const float* W2f  = (const float*)d_in[26];
  const float* b2f  = (const float*)d_in[27];
  const float* Wo   = (const float*)d_in[28];
  const float* bo   = (const float*)d_in[29];

  char* ws = (char*)d_ws;
  u16t*  U    = (u16t*)(ws + OFF_U);
  u16t*  YA   = (u16t*)(ws + OFF_YA);
  u16t*  YB   = (u16t*)(ws + OFF_U);
  float* ST   = (float*)(ws + OFF_ST);
  u32t*  RS   = (u32t*)(ws + OFF_RS);
  u32t*  CUR  = (u32t*)(ws + OFF_CUR);
  u32t*  BS   = (u32t*)(ws + OFF_BSUM);
  int*   SSRC = (int*)(ws + OFF_SSRC);
  u16t*  WK   = (u16t*)(ws + OFF_WK);
  u16t*  W2K  = WK;
  u16t*  W3K  = WK + 16384;
  u16t*  WXT  = WK + 16384 + 65536;
  u16t*  WF1  = WK + 16384 + 65536 + 376832;
  u16t*  WF2  = WK + 16384 + 65536 + 376832 + 262144;
  u16t*  XC   = (u16t*)(ws + OFF_XC);
  u16t*  T3   = (u16t*)(ws + OFF_T3);
  u16t*  H1   = (u16t*)(ws + OFF_H1);
  float* H2   = (float*)(ws + OFF_H2);
  float* OUT  = (float*)d_out;

  const int NBLK = (NN + 1023) / 1024;

  hipMemsetAsync(ST, 0, 5 * 64 * sizeof(float), stream);
  hipMemsetAsync(CUR, 0, NN * sizeof(u32t), stream);

  k_prep<<<(128 * 2944 + 255) / 256, 256, 0, stream>>>(c2W, c3W, Wxt, W1f, W2f,
                                                        W2K, W3K, WXT, WF1, WF2);

  k_hist<<<(NE + 255) / 256, 256, 0, stream>>>(ei, CUR);
  k_scan1<<<NBLK, 256, 0, stream>>>(CUR, BS);
  k_scan2<<<1, 256, 0, stream>>>(BS, RS, NBLK);
  k_scan3<<<NBLK, 256, 0, stream>>>(CUR, RS, BS);
  k_scatter<<<(NE + 255) / 256, 256, 0, stream>>>(ei, CUR, SSRC);

  k_mlp1_first<<<2048, 256, 0, stream>>>(x, g1W1, U);
  k_agg0<<<NN / 64, 256, 0, stream>>>(U, RS, SSRC, g1b1, g1W2, g1b2, YA, ST + 0);
  const u16t* yin = YA;
  u16t* yout = YB;
  for (int lyr = 1; lyr <= 4; ++lyr) {
    k_layer<<<NN / 64, 256, 0, stream>>>(yin, RS, SSRC, ST + (lyr - 1) * 64,
                                         bng + (lyr - 1) * 32, bnb + (lyr - 1) * 32,
                                         gsW1 + (lyr - 1) * 1024, gsb1 + (lyr - 1) * 32,
                                         gsW2 + (lyr - 1) * 1024, gsb2 + (lyr - 1) * 32,
                                         yout, ST + lyr * 64);
    const u16t* tmp = yin;
    yin = yout;
    yout = (u16t*)tmp;
  }
  k_pool_xd<<<NG, 64, 0, stream>>>(yin, batch, ST, bng, bnb, Wxd, bxd, XC);

  k_cnn<<<NG, 256, 0, stream>>>(xo, c1W, c1b, W2K, c2b, W3K, c3b, T3);

  {
    dim3 grid((NG + 127) / 128, 2);
    k_mgemm<<<grid, 256, 0, stream>>>(T3, 2944, WXT, bxt, XC, 256, 128, NG, 2944, 0, 0);
  }
  {
    dim3 grid((NG + 127) / 128, 16);
    k_mgemm<<<grid, 256, 0, stream>>>(XC, 256, WF1, b1f, H1, 1024, 0, NG, 256, 1, 0);
  }
  {
    dim3 grid((NG + 127) / 128, 2);
    k_mgemm<<<grid, 256, 0, stream>>>(H1, 1024, WF2, b2f, H2, 128, 0, NG, 1024, 1, 1);
  }
  k_out<<<(NG + 31) / 32, 256, 0, stream>>>(H2, Wo, bo, OUT);
}

// Round 14
// 2523.378 us; speedup vs baseline: 1.3665x; 1.0970x over previous
//
#include <hip/hip_runtime.h>

#define NN 1000000
#define NE 4000000
#define NG 25000
#define BN_EPS 1e-5f

typedef unsigned short u16t;
typedef unsigned int u32t;
typedef __attribute__((ext_vector_type(8))) short bf16x8;
typedef __attribute__((ext_vector_type(8))) _Float16 f16x8;
typedef __attribute__((ext_vector_type(4))) float f32x4;

__device__ inline u16t f2bf(float f) {
  u32t u = __float_as_uint(f);
  u32t r = (u + 0x7FFFu + ((u >> 16) & 1u)) >> 16;
  return (u16t)r;
}
__device__ inline float bf2f(u16t h) { return __uint_as_float((u32t)h << 16); }
__device__ inline u16t f2h(float f) {
  _Float16 h = (_Float16)f;
  return *(u16t*)&h;
}
__device__ inline float h2f(u16t v) {
  _Float16 h = *(_Float16*)&v;
  return (float)h;
}
__device__ inline void add8h(float* a, uint4 v) {
  union { uint4 u; _Float16 h[8]; } cv;
  cv.u = v;
#pragma unroll
  for (int j = 0; j < 8; ++j) a[j] += (float)cv.h[j];
}

// ---- workspace layout (bytes) ----
static const size_t OFF_U    = 0;           // fp16 64MB; also YB
static const size_t OFF_YA   = 130000000;
static const size_t OFF_ST   = 258000000;
static const size_t OFF_RS   = 259000000;
static const size_t OFF_CUR  = 263200000;
static const size_t OFF_BSUM = 267300000;
static const size_t OFF_SSRC = 268000000;   // 16MB
static const size_t OFF_WK   = 285000000;
static const size_t OFF_XC   = 287000000;
static const size_t OFF_T3   = 0;
static const size_t OFF_H1   = 150000000;
static const size_t OFF_H2   = 210000000;

// ---------------- CSR build ----------------
__global__ __launch_bounds__(256) void k_hist(const int* __restrict__ ei, u32t* __restrict__ cnt) {
  const int i = blockIdx.x * 256 + threadIdx.x;
  if (i < NE) atomicAdd(&cnt[ei[NE + i]], 1u);
}

__global__ __launch_bounds__(256) void k_scan1(const u32t* __restrict__ deg, u32t* __restrict__ bsum) {
  __shared__ u32t red[4];
  const int b = blockIdx.x, t = threadIdx.x;
  u32t s = 0;
#pragma unroll
  for (int j = 0; j < 4; ++j) {
    const int i = b * 1024 + j * 256 + t;
    if (i < NN) s += deg[i];
  }
#pragma unroll
  for (int off = 32; off > 0; off >>= 1) s += __shfl_down(s, off);
  if ((t & 63) == 0) red[t >> 6] = s;
  __syncthreads();
  if (t == 0) bsum[b] = red[0] + red[1] + red[2] + red[3];
}

__global__ __launch_bounds__(256) void k_scan2(u32t* __restrict__ bsum, u32t* __restrict__ rs, int nblk) {
  __shared__ u32t sh[256];
  const int t = threadIdx.x;
  u32t v[4];
#pragma unroll
  for (int j = 0; j < 4; ++j) {
    const int i = t * 4 + j;
    v[j] = (i < nblk) ? bsum[i] : 0u;
  }
  const u32t tot = v[0] + v[1] + v[2] + v[3];
  sh[t] = tot;
  __syncthreads();
  for (int off = 1; off < 256; off <<= 1) {
    u32t add = (t >= off) ? sh[t - off] : 0u;
    __syncthreads();
    sh[t] += add;
    __syncthreads();
  }
  const u32t tb = (t == 0) ? 0u : sh[t - 1];
  u32t run = tb;
#pragma unroll
  for (int j = 0; j < 4; ++j) {
    const int i = t * 4 + j;
    if (i < nblk) bsum[i] = run;
    run += v[j];
  }
  if (t == 0) rs[NN] = NE;
}

__global__ __launch_bounds__(256) void k_scan3(u32t* __restrict__ cur, u32t* __restrict__ rs,
                                               const u32t* __restrict__ bsum) {
  __shared__ u32t sh[256];
  const int b = blockIdx.x, t = threadIdx.x;
  const int i0 = b * 1024 + t * 4;
  u32t v[4];
#pragma unroll
  for (int j = 0; j < 4; ++j) v[j] = (i0 + j < NN) ? cur[i0 + j] : 0u;
  sh[t] = v[0] + v[1] + v[2] + v[3];
  __syncthreads();
  for (int off = 1; off < 256; off <<= 1) {
    u32t add = (t >= off) ? sh[t - off] : 0u;
    __syncthreads();
    sh[t] += add;
    __syncthreads();
  }
  u32t run = bsum[b] + ((t == 0) ? 0u : sh[t - 1]);
#pragma unroll
  for (int j = 0; j < 4; ++j) {
    const int i = i0 + j;
    if (i < NN) { rs[i] = run; cur[i] = run; }
    run += v[j];
  }
}

__global__ __launch_bounds__(256) void k_scatter(const int* __restrict__ ei,
                                                 u32t* __restrict__ cur, int* __restrict__ ssrc) {
  const int i = blockIdx.x * 256 + threadIdx.x;
  if (i < NE) {
    const int src = ei[i], dst = ei[NE + i];
    const u32t pos = atomicAdd(&cur[dst], 1u);
    ssrc[pos] = src;
  }
}

// ---------------- GNN kernels ----------------

// layer0 part A: u = x @ W1 (78->32) via fp16 MFMA. 64 nodes/block.
// LDS: Xh [64][104] fp16 (K padded 78->96 w/ zeros), Wt [32][104], Uh [64][40]
__global__ __launch_bounds__(256) void k_mlp1_first(
    const float* __restrict__ x, const float* __restrict__ W1, u16t* __restrict__ u)
{
  __shared__ __align__(16) u16t Xh[64 * 104];
  __shared__ __align__(16) u16t Wt[32 * 104];
  __shared__ __align__(16) u16t Uh[64 * 40];
  const int t = threadIdx.x;
  const int n0b = blockIdx.x * 64;
  // stage x (64 rows x 78 f32 -> fp16), zero-pad K 78..95
  for (int id = t; id < 64 * 78; id += 256) {
    const int row = id / 78, k = id - row * 78;
    Xh[row * 104 + k] = f2h(x[(size_t)n0b * 78 + id]);
  }
  for (int id = t; id < 64 * 18; id += 256) {
    const int row = id / 18, k = 78 + (id - row * 18);
    Xh[row * 104 + k] = 0;
  }
  // stage W1 transposed [c][k], zero-pad
  for (int id = t; id < 78 * 32; id += 256) {
    const int k = id >> 5, c = id & 31;
    Wt[c * 104 + k] = f2h(W1[id]);
  }
  for (int id = t; id < 32 * 18; id += 256) {
    const int c = id / 18, k = 78 + (id - c * 18);
    Wt[c * 104 + k] = 0;
  }
  __syncthreads();
  {
    const int w = t >> 6, l = t & 63, col = l & 15, kg = l >> 4;
    const int m0 = w * 16;
    f32x4 ac0 = {0.f, 0.f, 0.f, 0.f}, ac1 = {0.f, 0.f, 0.f, 0.f};
#pragma unroll
    for (int ks = 0; ks < 3; ++ks) {
      const f16x8 af = *(const f16x8*)(Xh + (m0 + col) * 104 + ks * 32 + kg * 8);
      const f16x8 bf0 = *(const f16x8*)(Wt + col * 104 + ks * 32 + kg * 8);
      const f16x8 bf1 = *(const f16x8*)(Wt + (16 + col) * 104 + ks * 32 + kg * 8);
      ac0 = __builtin_amdgcn_mfma_f32_16x16x32_f16(af, bf0, ac0, 0, 0, 0);
      ac1 = __builtin_amdgcn_mfma_f32_16x16x32_f16(af, bf1, ac1, 0, 0, 0);
    }
#pragma unroll
    for (int r = 0; r < 4; ++r) {
      const int m = m0 + kg * 4 + r;
      Uh[m * 40 + col] = f2h(ac0[r]);
      Uh[m * 40 + 16 + col] = f2h(ac1[r]);
    }
  }
  __syncthreads();
  {
    const int row = t >> 2;
    const uint4 v = *(const uint4*)(Uh + row * 40 + (t & 3) * 8);
    *(uint4*)(u + (size_t)(n0b + row) * 32 + (t & 3) * 8) = v;
  }
}

// layer0 part B: gather (direct CSR) + fp16-MFMA MLP
__global__ __launch_bounds__(256) void k_agg0(
    const u16t* __restrict__ u, const u32t* __restrict__ rs, const int* __restrict__ ssrc,
    const float* __restrict__ b1, const float* __restrict__ W2, const float* __restrict__ b2,
    u16t* __restrict__ yout, float* __restrict__ stats_out)
{
  __shared__ __align__(16) u16t W2t[32 * 40];
  __shared__ __align__(16) u16t A1h[64 * 40];
  __shared__ __align__(16) u16t A2h[64 * 40];
  __shared__ float red[256];
  __shared__ u32t rss[65];
  const int t = threadIdx.x;
  const int n0b = blockIdx.x * 64;
  for (int id = t; id < 1024; id += 256) {
    int k = id >> 5, c = id & 31;
    W2t[c * 40 + k] = f2h(W2[id]);
  }
  if (t < 65) rss[t] = rs[n0b + t];
  __syncthreads();
  const int nl = t >> 2, c0 = (t & 3) * 8;
  {
    const int n = n0b + nl;
    float a[8] = {};
    add8h(a, *(const uint4*)(u + (size_t)n * 32 + c0));
    const u32t e0 = rss[nl], e1 = rss[nl + 1];
    u32t e = e0;
    for (; e + 4 <= e1; e += 4) {
      const int s0v = ssrc[e], s1v = ssrc[e + 1], s2v = ssrc[e + 2], s3v = ssrc[e + 3];
      const uint4 v0 = *(const uint4*)(u + (size_t)s0v * 32 + c0);
      const uint4 v1 = *(const uint4*)(u + (size_t)s1v * 32 + c0);
      const uint4 v2 = *(const uint4*)(u + (size_t)s2v * 32 + c0);
      const uint4 v3 = *(const uint4*)(u + (size_t)s3v * 32 + c0);
      add8h(a, v0); add8h(a, v1); add8h(a, v2); add8h(a, v3);
    }
    for (; e < e1; ++e)
      add8h(a, *(const uint4*)(u + (size_t)ssrc[e] * 32 + c0));
    union { u16t h[8]; uint4 v; } pk;
#pragma unroll
    for (int j = 0; j < 8; ++j) pk.h[j] = f2h(fmaxf(a[j] + b1[c0 + j], 0.f));
    *(uint4*)(A1h + nl * 40 + c0) = pk.v;
  }
  __syncthreads();
  {
    const int w = t >> 6, l = t & 63, col = l & 15, kg = l >> 4;
    const int m0 = w * 16;
    const f16x8 af = *(const f16x8*)(A1h + (m0 + col) * 40 + kg * 8);
    const f16x8 bf0 = *(const f16x8*)(W2t + col * 40 + kg * 8);
    const f16x8 bf1 = *(const f16x8*)(W2t + (16 + col) * 40 + kg * 8);
    f32x4 ac0 = {0.f, 0.f, 0.f, 0.f}, ac1 = {0.f, 0.f, 0.f, 0.f};
    ac0 = __builtin_amdgcn_mfma_f32_16x16x32_f16(af, bf0, ac0, 0, 0, 0);
    ac1 = __builtin_amdgcn_mfma_f32_16x16x32_f16(af, bf1, ac1, 0, 0, 0);
    const float bb0 = b2[col], bb1 = b2[16 + col];
#pragma unroll
    for (int r = 0; r < 4; ++r) {
      const int m = m0 + kg * 4 + r;
      A2h[m * 40 + col] = f2h(fmaxf(ac0[r] + bb0, 0.f));
      A2h[m * 40 + 16 + col] = f2h(fmaxf(ac1[r] + bb1, 0.f));
    }
  }
  __syncthreads();
  const int c = t & 31;
  float rsum = 0.f, rq = 0.f;
#pragma unroll
  for (int rep = 0; rep < 8; ++rep) {
    const int row = (t >> 5) + rep * 8;
    const float v = h2f(A2h[row * 40 + c]);
    rsum += v;
    rq += v * v;
  }
  {
    const int row = t >> 2;
    const uint4 v = *(const uint4*)(A2h + row * 40 + (t & 3) * 8);
    *(uint4*)(yout + (size_t)(n0b + row) * 32 + (t & 3) * 8) = v;
  }
  rsum += __shfl_down(rsum, 32);
  rq += __shfl_down(rq, 32);
  __syncthreads();
  const int wv_ = t >> 6, lane = t & 63;
  if (lane < 32) {
    red[wv_ * 32 + lane] = rsum;
    red[128 + wv_ * 32 + lane] = rq;
  }
  __syncthreads();
  if (t < 32) {
    float aa = red[t] + red[32 + t] + red[64 + t] + red[96 + t];
    float bb = red[128 + t] + red[160 + t] + red[192 + t] + red[224 + t];
    unsafeAtomicAdd(&stats_out[t], aa);
    unsafeAtomicAdd(&stats_out[32 + t], bb);
  }
}

// layers 1..4: gather (direct CSR) + BN-affine + two fp16-MFMA MLPs
__global__ __launch_bounds__(256) void k_layer(
    const u16t* __restrict__ yin, const u32t* __restrict__ rs, const int* __restrict__ ssrc,
    const float* __restrict__ stats, const float* __restrict__ gamma, const float* __restrict__ beta,
    const float* __restrict__ W1, const float* __restrict__ b1,
    const float* __restrict__ W2, const float* __restrict__ b2,
    u16t* __restrict__ yout, float* __restrict__ stats_out)
{
  __shared__ __align__(16) u16t W1t[32 * 40];
  __shared__ __align__(16) u16t W2t[32 * 40];
  __shared__ __align__(16) u16t A1h[64 * 40];
  __shared__ __align__(16) u16t A2h[64 * 40];
  __shared__ float red[256];
  __shared__ u32t rss[65];
  const int t = threadIdx.x;
  const int n0b = blockIdx.x * 64;
  for (int id = t; id < 1024; id += 256) {
    int k = id >> 5, c = id & 31;
    W1t[c * 40 + k] = f2h(W1[id]);
    W2t[c * 40 + k] = f2h(W2[id]);
  }
  if (t < 65) rss[t] = rs[n0b + t];
  __syncthreads();
  const int nl = t >> 2, c0 = (t & 3) * 8;
  {
    const int n = n0b + nl;
    float sc[8], sh[8];
#pragma unroll
    for (int j = 0; j < 8; ++j) {
      const int c = c0 + j;
      const float mu = stats[c] * (1.f / NN);
      float var = fmaxf(stats[32 + c] * (1.f / NN) - mu * mu, 0.f);
      sc[j] = gamma[c] * rsqrtf(var + BN_EPS);
      sh[j] = beta[c] - mu * sc[j];
    }
    float a[8] = {};
    add8h(a, *(const uint4*)(yin + (size_t)n * 32 + c0));
    const u32t e0 = rss[nl], e1 = rss[nl + 1];
    u32t e = e0;
    for (; e + 4 <= e1; e += 4) {
      const int s0v = ssrc[e], s1v = ssrc[e + 1], s2v = ssrc[e + 2], s3v = ssrc[e + 3];
      const uint4 v0 = *(const uint4*)(yin + (size_t)s0v * 32 + c0);
      const uint4 v1 = *(const uint4*)(yin + (size_t)s1v * 32 + c0);
      const uint4 v2 = *(const uint4*)(yin + (size_t)s2v * 32 + c0);
      const uint4 v3 = *(const uint4*)(yin + (size_t)s3v * 32 + c0);
      add8h(a, v0); add8h(a, v1); add8h(a, v2); add8h(a, v3);
    }
    for (; e < e1; ++e)
      add8h(a, *(const uint4*)(yin + (size_t)ssrc[e] * 32 + c0));
    const float cnt = (float)(e1 - e0 + 1u);
    union { u16t h[8]; uint4 v; } pk;
#pragma unroll
    for (int j = 0; j < 8; ++j) pk.h[j] = f2h(sc[j] * a[j] + cnt * sh[j]);
    *(uint4*)(A1h + nl * 40 + c0) = pk.v;
  }
  __syncthreads();
  const int w = t >> 6, l = t & 63, col = l & 15, kg = l >> 4;
  const int m0 = w * 16;
  {
    const f16x8 af = *(const f16x8*)(A1h + (m0 + col) * 40 + kg * 8);
    const f16x8 bf0 = *(const f16x8*)(W1t + col * 40 + kg * 8);
    const f16x8 bf1 = *(const f16x8*)(W1t + (16 + col) * 40 + kg * 8);
    f32x4 ac0 = {0.f, 0.f, 0.f, 0.f}, ac1 = {0.f, 0.f, 0.f, 0.f};
    ac0 = __builtin_amdgcn_mfma_f32_16x16x32_f16(af, bf0, ac0, 0, 0, 0);
    ac1 = __builtin_amdgcn_mfma_f32_16x16x32_f16(af, bf1, ac1, 0, 0, 0);
    const float bb0 = b1[col], bb1 = b1[16 + col];
#pragma unroll
    for (int r = 0; r < 4; ++r) {
      const int m = m0 + kg * 4 + r;
      A2h[m * 40 + col] = f2h(fmaxf(ac0[r] + bb0, 0.f));
      A2h[m * 40 + 16 + col] = f2h(fmaxf(ac1[r] + bb1, 0.f));
    }
  }
  __syncthreads();
  {
    const f16x8 af = *(const f16x8*)(A2h + (m0 + col) * 40 + kg * 8);
    const f16x8 bf0 = *(const f16x8*)(W2t + col * 40 + kg * 8);
    const f16x8 bf1 = *(const f16x8*)(W2t + (16 + col) * 40 + kg * 8);
    f32x4 ac0 = {0.f, 0.f, 0.f, 0.f}, ac1 = {0.f, 0.f, 0.f, 0.f};
    ac0 = __builtin_amdgcn_mfma_f32_16x16x32_f16(af, bf0, ac0, 0, 0, 0);
    ac1 = __builtin_amdgcn_mfma_f32_16x16x32_f16(af, bf1, ac1, 0, 0, 0);
    const float bb0 = b2[col], bb1 = b2[16 + col];
#pragma unroll
    for (int r = 0; r < 4; ++r) {
      const int m = m0 + kg * 4 + r;
      A1h[m * 40 + col] = f2h(fmaxf(ac0[r] + bb0, 0.f));
      A1h[m * 40 + 16 + col] = f2h(fmaxf(ac1[r] + bb1, 0.f));
    }
  }
  __syncthreads();
  const int c = t & 31;
  float rsum = 0.f, rq = 0.f;
#pragma unroll
  for (int rep = 0; rep < 8; ++rep) {
    const int row = (t >> 5) + rep * 8;
    const float v = h2f(A1h[row * 40 + c]);
    rsum += v;
    rq += v * v;
  }
  {
    const int row = t >> 2;
    const uint4 v = *(const uint4*)(A1h + row * 40 + (t & 3) * 8);
    *(uint4*)(yout + (size_t)(n0b + row) * 32 + (t & 3) * 8) = v;
  }
  rsum += __shfl_down(rsum, 32);
  rq += __shfl_down(rq, 32);
  __syncthreads();
  const int wv_ = t >> 6, lane = t & 63;
  if (lane < 32) {
    red[wv_ * 32 + lane] = rsum;
    red[128 + wv_ * 32 + lane] = rq;
  }
  __syncthreads();
  if (t < 32) {
    float aa = red[t] + red[32 + t] + red[64 + t] + red[96 + t];
    float bb = red[128 + t] + red[160 + t] + red[192 + t] + red[224 + t];
    unsafeAtomicAdd(&stats_out[t], aa);
    unsafeAtomicAdd(&stats_out[32 + t], bb);
  }
}

__global__ __launch_bounds__(64) void k_pool_xd(
    const u16t* __restrict__ y, const int* __restrict__ batch,
    const float* __restrict__ stats, const float* __restrict__ gamma,
    const float* __restrict__ beta, const float* __restrict__ Wxd,
    const float* __restrict__ bxd, u16t* __restrict__ xc)
{
  const int g = blockIdx.x, t = threadIdx.x;
  int lo = 0, n = NN;
  while (n > 0) {
    int h = n >> 1, m = lo + h;
    if (batch[m] < g) { lo = m + 1; n -= h + 1; } else n = h;
  }
  int hi = lo;
  n = NN - lo;
  while (n > 0) {
    int h = n >> 1, m = hi + h;
    if (batch[m] < g + 1) { hi = m + 1; n -= h + 1; } else n = h;
  }
  const int c = t & 31;
  const float mu = stats[4 * 64 + c] * (1.f / NN);
  float var = fmaxf(stats[4 * 64 + 32 + c] * (1.f / NN) - mu * mu, 0.f);
  const float sc = gamma[4 * 32 + c] * rsqrtf(var + BN_EPS);
  const float sh = beta[4 * 32 + c] - mu * sc;
  float acc = 0.f;
  for (int i = lo + (t >> 5); i < hi; i += 2) acc += h2f(y[(size_t)i * 32 + c]);
  acc += __shfl_down(acc, 32);
  __shared__ float pl[32];
  if (t < 32) pl[t] = acc * sc + (float)(hi - lo) * sh;
  __syncthreads();
#pragma unroll
  for (int rep = 0; rep < 2; ++rep) {
    const int o = t + rep * 64;
    float a = bxd[o];
#pragma unroll
    for (int cc = 0; cc < 32; ++cc) a = fmaf(pl[cc], Wxd[cc * 128 + o], a);
    xc[(size_t)g * 256 + o] = f2bf(fmaxf(a, 0.f));
  }
}

// ---------------- weight prep ----------------
__global__ __launch_bounds__(256) void k_prep(
    const float* __restrict__ w2, const float* __restrict__ w3,
    const float* __restrict__ wxt, const float* __restrict__ wf1, const float* __restrict__ wf2,
    u16t* __restrict__ W2k, u16t* __restrict__ W3k,
    u16t* __restrict__ WXT, u16t* __restrict__ WF1, u16t* __restrict__ WF2)
{
  const int i = blockIdx.x * 256 + threadIdx.x;
  if (i < 64 * 256) {
    int c2 = i >> 8, kk = i & 255, tt = kk >> 5, ci = kk & 31;
    W2k[i] = f2bf(w2[c2 * 256 + ci * 8 + tt]);
  }
  if (i < 128 * 512) {
    int c3 = i >> 9, kk = i & 511, tt = kk >> 6, ci = kk & 63;
    W3k[i] = f2bf(w3[c3 * 512 + ci * 8 + tt]);
  }
  if (i < 128 * 2944) {
    int nn = i / 2944, kk = i - nn * 2944;
    WXT[i] = f2bf(wxt[kk * 128 + nn]);
  }
  if (i < 1024 * 256) {
    int nn = i >> 8, kk = i & 255;
    WF1[i] = f2bf(wf1[kk * 1024 + nn]);
  }
  if (i < 128 * 1024) {
    int nn = i >> 10, kk = i & 1023;
    WF2[i] = f2bf(wf2[kk * 128 + nn]);
  }
}

// ---------------- fused per-graph CNN (unchanged) ----------------
__global__ __launch_bounds__(256, 4) void k_cnn(
    const float* __restrict__ xo,
    const float* __restrict__ w1, const float* __restrict__ b1,
    const u16t* __restrict__ W2k, const float* __restrict__ b2,
    const u16t* __restrict__ W3k, const float* __restrict__ b3,
    u16t* __restrict__ t3)
{
  __shared__ __align__(16) char smem[30720];
  float* xot = (float*)(smem);
  float* w1s = (float*)(smem + 3072);
  float* b2s = (float*)(smem + 4096);
  float* b3s = (float*)(smem + 4352);
  short* T1T = (short*)(smem + 4864);
  char*  T2B = smem + 20736;
  u16t*  stg = (u16t*)(smem + 4864);

  const int g = blockIdx.x, t = threadIdx.x;
  const int w = t >> 6, l = t & 63, col = l & 15, kg = l >> 4;

  for (int i = t; i < 768; i += 256) xot[i] = (i < 735) ? xo[(size_t)g * 735 + i] : 0.f;
  w1s[t] = w1[t];
  if (t < 64) b2s[t] = b2[t];
  if (t < 128) b3s[t] = b3[t];
  if (t < 192) {
    int r = 242 + (t >> 5), c = t & 31;
    T1T[r * 32 + c] = 0;
  }
  __syncthreads();

  {
    const int c = t >> 3, qg = t & 7;
    float wv[8];
#pragma unroll
    for (int j = 0; j < 8; ++j) wv[j] = w1s[c * 8 + j];
    const float bias = b1[c];
    const int q0 = qg * 31, qe = (q0 + 31 < 242) ? q0 + 31 : 242;
#pragma unroll 1
    for (int qc = q0; qc < qe; qc += 10) {
      const int cnt = (qe - qc < 10) ? qe - qc : 10;
      float xv[37];
#pragma unroll
      for (int j = 0; j < 37; ++j) xv[j] = xot[3 * qc + j];
#pragma unroll
      for (int j0 = 0; j0 < 10; ++j0) {
        if (j0 < cnt) {
          float a0 = bias, a1 = bias, a2 = bias;
#pragma unroll
          for (int tt = 0; tt < 8; ++tt) {
            a0 = fmaf(wv[tt], xv[3 * j0 + tt], a0);
            a1 = fmaf(wv[tt], xv[3 * j0 + 1 + tt], a1);
            a2 = fmaf(wv[tt], xv[3 * j0 + 2 + tt], a2);
          }
          float m = fmaxf(fmaxf(a0, a1), fmaxf(a2, 0.f));
          const int pos = qc + j0;
          T1T[pos * 32 + (c ^ ((pos & 3) << 3))] = (short)f2bf(m);
        }
      }
    }
  }
  __syncthreads();

  {
    bf16x8 am[8];
#pragma unroll
    for (int kk = 0; kk < 8; ++kk)
      am[kk] = *(const bf16x8*)(W2k + (w * 16 + col) * 256 + kk * 32 + kg * 8);
#pragma unroll 1
    for (int qt = 0; qt < 5; ++qt) {
      const int rbase = qt * 48 + col * 3;
      bf16x8 rv[10];
#pragma unroll
      for (int s = 0; s < 10; ++s) {
        const int row = rbase + s;
        rv[s] = *(const bf16x8*)(T1T + row * 32 + ((kg ^ (row & 3)) << 3));
      }
      f32x4 a0 = {0.f, 0.f, 0.f, 0.f}, a1 = a0, a2 = a0;
#pragma unroll
      for (int kk = 0; kk < 8; ++kk) {
        a0 = __builtin_amdgcn_mfma_f32_16x16x32_bf16(am[kk], rv[kk], a0, 0, 0, 0);
        a1 = __builtin_amdgcn_mfma_f32_16x16x32_bf16(am[kk], rv[kk + 1], a1, 0, 0, 0);
        a2 = __builtin_amdgcn_mfma_f32_16x16x32_bf16(am[kk], rv[kk + 2], a2, 0, 0, 0);
      }
      const int q = qt * 16 + col;
      if (q < 78) {
        union { u16t u[4]; uint2 v; } pk;
#pragma unroll
        for (int r = 0; r < 4; ++r) {
          const float bb = b2s[w * 16 + kg * 4 + r];
          float m = fmaxf(fmaxf(a0[r], a1[r]), a2[r]);
          pk.u[r] = f2bf(fmaxf(m + bb, 0.f));
        }
        const int boff = (q * 128 + (w * 16 + kg * 4) * 2) ^ ((q & 7) << 4);
        *(uint2*)(T2B + boff) = pk.v;
      }
    }
  }
  __syncthreads();

  {
#pragma unroll 1
    for (int mi = 0; mi < 2; ++mi) {
      const int m3 = w * 2 + mi;
      f32x4 acc[2][3];
#pragma unroll
      for (int qt = 0; qt < 2; ++qt)
#pragma unroll
        for (int r = 0; r < 3; ++r) acc[qt][r] = (f32x4){0.f, 0.f, 0.f, 0.f};
#pragma unroll 1
      for (int kh = 0; kh < 2; ++kh) {
        bf16x8 amh[8];
#pragma unroll
        for (int tt = 0; tt < 8; ++tt)
          amh[tt] = *(const bf16x8*)(W3k + (m3 * 16 + col) * 512 + (tt * 2 + kh) * 32 + kg * 8);
#pragma unroll
        for (int qt = 0; qt < 2; ++qt) {
          const int rbase = qt * 48 + col * 3;
          bf16x8 rv[10];
#pragma unroll
          for (int s = 0; s < 10; ++s) {
            int row = rbase + s;
            row = (row < 78) ? row : 77;
            const int boff = (row * 128 + kh * 64 + kg * 16) ^ ((row & 7) << 4);
            rv[s] = *(const bf16x8*)(T2B + boff);
          }
#pragma unroll
          for (int tt = 0; tt < 8; ++tt) {
            acc[qt][0] = __builtin_amdgcn_mfma_f32_16x16x32_bf16(amh[tt], rv[tt], acc[qt][0], 0, 0, 0);
            acc[qt][1] = __builtin_amdgcn_mfma_f32_16x16x32_bf16(amh[tt], rv[tt + 1], acc[qt][1], 0, 0, 0);
            acc[qt][2] = __builtin_amdgcn_mfma_f32_16x16x32_bf16(amh[tt], rv[tt + 2], acc[qt][2], 0, 0, 0);
          }
        }
      }
#pragma unroll
      for (int qt = 0; qt < 2; ++qt) {
        const int q = qt * 16 + col;
        if (q < 23) {
#pragma unroll
          for (int r = 0; r < 4; ++r) {
            const int c = m3 * 16 + kg * 4 + r;
            float m = fmaxf(fmaxf(acc[qt][0][r], acc[qt][1][r]), acc[qt][2][r]);
            stg[c * 23 + q] = f2bf(fmaxf(m + b3s[c], 0.f));
          }
        }
      }
    }
  }
  __syncthreads();

  {
    const uint4* s4 = (const uint4*)stg;
    uint4* d4 = (uint4*)(t3 + (size_t)g * 2944);
    for (int id = t; id < 368; id += 256) d4[id] = s4[id];
  }
}

// ---------------- bf16 MFMA GEMM ----------------
__global__ __launch_bounds__(256) void k_mgemm(
    const u16t* __restrict__ A, int lda,
    const u16t* __restrict__ WT, const float* __restrict__ bias,
    void* __restrict__ Cv, int ldc, int c_off, int M, int Kd,
    int relu_f, int out32)
{
  __shared__ __align__(16) u16t As[128 * 4 * 8];
  __shared__ __align__(16) u16t Ws2[64 * 4 * 8];
  const int t = threadIdx.x;
  const int w = t >> 6, l = t & 63, col = l & 15, kg = l >> 4;
  const int wm = w & 1, wn = w >> 1;
  const int m0 = blockIdx.x * 128, n0 = blockIdx.y * 64;
  f32x4 acc[4][2];
#pragma unroll
  for (int i = 0; i < 4; ++i)
#pragma unroll
    for (int j = 0; j < 2; ++j) acc[i][j] = (f32x4){0.f, 0.f, 0.f, 0.f};
  const int ar = t >> 1, ac = (t & 1) * 2;
  const int wr = t >> 2, wc = t & 3;
  const bool aok = (m0 + ar) < M;
  const u16t* Ap = A + (size_t)(m0 + ar) * lda;
  const u16t* Wp = WT + (size_t)(n0 + wr) * Kd;
  for (int k0 = 0; k0 < Kd; k0 += 32) {
    bf16x8 av0 = {0, 0, 0, 0, 0, 0, 0, 0}, av1 = {0, 0, 0, 0, 0, 0, 0, 0};
    if (aok) {
      av0 = *(const bf16x8*)(Ap + k0 + ac * 8);
      av1 = *(const bf16x8*)(Ap + k0 + (ac + 1) * 8);
    }
    const bf16x8 wv = *(const bf16x8*)(Wp + k0 + wc * 8);
    __syncthreads();
    *(bf16x8*)(As + (ar * 4 + (ac ^ (ar & 3))) * 8) = av0;
    *(bf16x8*)(As + (ar * 4 + ((ac + 1) ^ (ar & 3))) * 8) = av1;
    *(bf16x8*)(Ws2 + (wr * 4 + (wc ^ (wr & 3))) * 8) = wv;
    __syncthreads();
    bf16x8 af[4], bf[2];
#pragma unroll
    for (int i = 0; i < 4; ++i) {
      const int R = wm * 64 + i * 16 + col;
      af[i] = *(const bf16x8*)(As + (R * 4 + (kg ^ (R & 3))) * 8);
    }
#pragma unroll
    for (int j = 0; j < 2; ++j) {
      const int R = wn * 32 + j * 16 + col;
      bf[j] = *(const bf16x8*)(Ws2 + (R * 4 + (kg ^ (R & 3))) * 8);
    }
#pragma unroll
    for (int i = 0; i < 4; ++i)
#pragma unroll
      for (int j = 0; j < 2; ++j)
        acc[i][j] = __builtin_amdgcn_mfma_f32_16x16x32_bf16(af[i], bf[j], acc[i][j], 0, 0, 0);
  }
#pragma unroll
  for (int j = 0; j < 2; ++j) {
    const int gn = n0 + wn * 32 + j * 16 + col;
    const float bb = bias[gn];
#pragma unroll
    for (int i = 0; i < 4; ++i) {
      const int gmb = m0 + wm * 64 + i * 16 + kg * 4;
#pragma unroll
      for (int r = 0; r < 4; ++r) {
        const int gm = gmb + r;
        if (gm < M) {
          float v = acc[i][j][r] + bb;
          if (relu_f) v = fmaxf(v, 0.f);
          if (out32) ((float*)Cv)[(size_t)gm * ldc + c_off + gn] = v;
          else ((u16t*)Cv)[(size_t)gm * ldc + c_off + gn] = f2bf(v);
        }
      }
    }
  }
}

__global__ __launch_bounds__(256) void k_out(
    const float* __restrict__ h2, const float* __restrict__ Wo,
    const float* __restrict__ bo, float* __restrict__ out)
{
  __shared__ float Ws_[128];
  const int t = threadIdx.x;
  if (t < 128) Ws_[t] = Wo[t];
  __syncthreads();
  const int g = blockIdx.x * 32 + (t >> 3), l = t & 7;
  float acc = 0.f;
  if (g < NG) {
    const float* hr = h2 + (size_t)g * 128 + l * 16;
    const float* wr = Ws_ + l * 16;
#pragma unroll
    for (int j = 0; j < 16; ++j) acc = fmaf(hr[j], wr[j], acc);
  }
  acc += __shfl_down(acc, 4, 8);
  acc += __shfl_down(acc, 2, 8);
  acc += __shfl_down(acc, 1, 8);
  if (l == 0 && g < NG) out[g] = acc + bo[0];
}

extern "C" void kernel_launch(void* const* d_in, const int* in_sizes, int n_in,
                              void* d_out, int out_size, void* d_ws, size_t ws_size,
                              hipStream_t stream) {
  const float* x    = (const float*)d_in[0];
  const int*   ei   = (const int*)d_in[1];
  const int*   batch= (const int*)d_in[2];
  const float* xo   = (const float*)d_in[3];
  const float* g1W1 = (const float*)d_in[4];
  const float* g1b1 = (const float*)d_in[5];
  const float* g1W2 = (const float*)d_in[6];
  const float* g1b2 = (const float*)d_in[7];
  const float* gsW1 = (const float*)d_in[8];
  const float* gsb1 = (const float*)d_in[9];
  const float* gsW2 = (const float*)d_in[10];
  const float* gsb2 = (const float*)d_in[11];
  const float* bng  = (const float*)d_in[12];
  const float* bnb  = (const float*)d_in[13];
  const float* Wxd  = (const float*)d_in[14];
  const float* bxd  = (const float*)d_in[15];
  const float* c1W  = (const float*)d_in[16];
  const float* c1b  = (const float*)d_in[17];
  const float* c2W  = (const float*)d_in[18];
  const float* c2b  = (const float*)d_in[19];
  const float* c3W  = (const float*)d_in[20];
  const float* c3b  = (const float*)d_in[21];
  const float* Wxt  = (const float*)d_in[22];
  const float* bxt  = (const float*)d_in[23];
  const float* W1f  = (const float*)d_in[24];
  const float* b1f  = (const float*)d_in[25];
  const float* W2f  = (const float*)d_in[26];
  const float* b2f  = (const float*)d_in[27];
  const float* Wo   = (const float*)d_in[28];
  const float* bo   = (const float*)d_in[29];

  char* ws = (char*)d_ws;
  u16t*  U    = (u16t*)(ws + OFF_U);
  u16t*  YA   = (u16t*)(ws + OFF_YA);
  u16t*  YB   = (u16t*)(ws + OFF_U);
  float* ST   = (float*)(ws + OFF_ST);
  u32t*  RS   = (u32t*)(ws + OFF_RS);
  u32t*  CUR  = (u32t*)(ws + OFF_CUR);
  u32t*  BS   = (u32t*)(ws + OFF_BSUM);
  int*   SSRC = (int*)(ws + OFF_SSRC);
  u16t*  WK   = (u16t*)(ws + OFF_WK);
  u16t*  W2K  = WK;
  u16t*  W3K  = WK + 16384;
  u16t*  WXT  = WK + 16384 + 65536;
  u16t*  WF1  = WK + 16384 + 65536 + 376832;
  u16t*  WF2  = WK + 16384 + 65536 + 376832 + 262144;
  u16t*  XC   = (u16t*)(ws + OFF_XC);
  u16t*  T3   = (u16t*)(ws + OFF_T3);
  u16t*  H1   = (u16t*)(ws + OFF_H1);
  float* H2   = (float*)(ws + OFF_H2);
  float* OUT  = (float*)d_out;

  const int NBLK = (NN + 1023) / 1024;

  hipMemsetAsync(ST, 0, 5 * 64 * sizeof(float), stream);
  hipMemsetAsync(CUR, 0, NN * sizeof(u32t), stream);

  k_prep<<<(128 * 2944 + 255) / 256, 256, 0, stream>>>(c2W, c3W, Wxt, W1f, W2f,
                                                        W2K, W3K, WXT, WF1, WF2);

  k_hist<<<(NE + 255) / 256, 256, 0, stream>>>(ei, CUR);
  k_scan1<<<NBLK, 256, 0, stream>>>(CUR, BS);
  k_scan2<<<1, 256, 0, stream>>>(BS, RS, NBLK);
  k_scan3<<<NBLK, 256, 0, stream>>>(CUR, RS, BS);
  k_scatter<<<(NE + 255) / 256, 256, 0, stream>>>(ei, CUR, SSRC);

  k_mlp1_first<<<NN / 64, 256, 0, stream>>>(x, g1W1, U);
  k_agg0<<<NN / 64, 256, 0, stream>>>(U, RS, SSRC, g1b1, g1W2, g1b2, YA, ST + 0);
  const u16t* yin = YA;
  u16t* yout = YB;
  for (int lyr = 1; lyr <= 4; ++lyr) {
    k_layer<<<NN / 64, 256, 0, stream>>>(yin, RS, SSRC, ST + (lyr - 1) * 64,
                                         bng + (lyr - 1) * 32, bnb + (lyr - 1) * 32,
                                         gsW1 + (lyr - 1) * 1024, gsb1 + (lyr - 1) * 32,
                                         gsW2 + (lyr - 1) * 1024, gsb2 + (lyr - 1) * 32,
                                         yout, ST + lyr * 64);
    const u16t* tmp = yin;
    yin = yout;
    yout = (u16t*)tmp;
  }
  k_pool_xd<<<NG, 64, 0, stream>>>(yin, batch, ST, bng, bnb, Wxd, bxd, XC);

  k_cnn<<<NG, 256, 0, stream>>>(xo, c1W, c1b, W2K, c2b, W3K, c3b, T3);

  {
    dim3 grid((NG + 127) / 128, 2);
    k_mgemm<<<grid, 256, 0, stream>>>(T3, 2944, WXT, bxt, XC, 256, 128, NG, 2944, 0, 0);
  }
  {
    dim3 grid((NG + 127) / 128, 16);
    k_mgemm<<<grid, 256, 0, stream>>>(XC, 256, WF1, b1f, H1, 1024, 0, NG, 256, 1, 0);
  }
  {
    dim3 grid((NG + 127) / 128, 2);
    k_mgemm<<<grid, 256, 0, stream>>>(H1, 1024, WF2, b2f, H2, 128, 0, NG, 1024, 1, 1);
  }
  k_out<<<(NG + 31) / 32, 256, 0, stream>>>(H2, Wo, bo, OUT);
}

// Round 15
// 2093.420 us; speedup vs baseline: 1.6471x; 1.2054x over previous
//
#include <hip/hip_runtime.h>

#define NN 1000000
#define NE 4000000
#define NG 25000
#define BN_EPS 1e-5f

typedef unsigned short u16t;
typedef unsigned int u32t;
typedef __attribute__((ext_vector_type(8))) short bf16x8;
typedef __attribute__((ext_vector_type(8))) _Float16 f16x8;
typedef __attribute__((ext_vector_type(4))) float f32x4;

__device__ inline u16t f2bf(float f) {
  u32t u = __float_as_uint(f);
  u32t r = (u + 0x7FFFu + ((u >> 16) & 1u)) >> 16;
  return (u16t)r;
}
__device__ inline float bf2f(u16t h) { return __uint_as_float((u32t)h << 16); }
__device__ inline u16t f2h(float f) {
  _Float16 h = (_Float16)f;
  return *(u16t*)&h;
}
__device__ inline float h2f(u16t v) {
  _Float16 h = *(_Float16*)&v;
  return (float)h;
}
__device__ inline void add8h(float* a, uint4 v) {
  union { uint4 u; _Float16 h[8]; } cv;
  cv.u = v;
#pragma unroll
  for (int j = 0; j < 8; ++j) a[j] += (float)cv.h[j];
}

// ---- workspace layout (bytes) ----
// U @0 (64MB, dead after agg0) | T3 bf16 @0 (147.2MB, written by cnn chunks during layers 1-4)
// YA @150e6, YB @214e6 (fp16 64MB ping-pong; never at 0 -> no clash with T3)
// ST @278e6 | RS @279e6 | CUR @283.2e6 | BSUM @287.3e6 | SSRC @288e6 (16MB)
// WK @304e6 (~1MB bf16 weights) | XC @306e6 (12.8MB)
// head: H1 @150e6 (overlays dead YA), H2 @214e6 (overlays dead YB)
static const size_t OFF_U    = 0;
static const size_t OFF_T3   = 0;
static const size_t OFF_YA   = 150000000;
static const size_t OFF_YB   = 214000000;
static const size_t OFF_ST   = 278000000;
static const size_t OFF_RS   = 279000000;
static const size_t OFF_CUR  = 283200000;
static const size_t OFF_BSUM = 287300000;
static const size_t OFF_SSRC = 288000000;
static const size_t OFF_WK   = 304000000;
static const size_t OFF_XC   = 306000000;
static const size_t OFF_H1   = 150000000;
static const size_t OFF_H2   = 214000000;

// ---------------- CSR build ----------------
__global__ __launch_bounds__(256) void k_hist(const int* __restrict__ ei, u32t* __restrict__ cnt) {
  const int i = blockIdx.x * 256 + threadIdx.x;
  if (i < NE) atomicAdd(&cnt[ei[NE + i]], 1u);
}

__global__ __launch_bounds__(256) void k_scan1(const u32t* __restrict__ deg, u32t* __restrict__ bsum) {
  __shared__ u32t red[4];
  const int b = blockIdx.x, t = threadIdx.x;
  u32t s = 0;
#pragma unroll
  for (int j = 0; j < 4; ++j) {
    const int i = b * 1024 + j * 256 + t;
    if (i < NN) s += deg[i];
  }
#pragma unroll
  for (int off = 32; off > 0; off >>= 1) s += __shfl_down(s, off);
  if ((t & 63) == 0) red[t >> 6] = s;
  __syncthreads();
  if (t == 0) bsum[b] = red[0] + red[1] + red[2] + red[3];
}

__global__ __launch_bounds__(256) void k_scan2(u32t* __restrict__ bsum, u32t* __restrict__ rs, int nblk) {
  __shared__ u32t sh[256];
  const int t = threadIdx.x;
  u32t v[4];
#pragma unroll
  for (int j = 0; j < 4; ++j) {
    const int i = t * 4 + j;
    v[j] = (i < nblk) ? bsum[i] : 0u;
  }
  const u32t tot = v[0] + v[1] + v[2] + v[3];
  sh[t] = tot;
  __syncthreads();
  for (int off = 1; off < 256; off <<= 1) {
    u32t add = (t >= off) ? sh[t - off] : 0u;
    __syncthreads();
    sh[t] += add;
    __syncthreads();
  }
  const u32t tb = (t == 0) ? 0u : sh[t - 1];
  u32t run = tb;
#pragma unroll
  for (int j = 0; j < 4; ++j) {
    const int i = t * 4 + j;
    if (i < nblk) bsum[i] = run;
    run += v[j];
  }
  if (t == 0) rs[NN] = NE;
}

__global__ __launch_bounds__(256) void k_scan3(u32t* __restrict__ cur, u32t* __restrict__ rs,
                                               const u32t* __restrict__ bsum) {
  __shared__ u32t sh[256];
  const int b = blockIdx.x, t = threadIdx.x;
  const int i0 = b * 1024 + t * 4;
  u32t v[4];
#pragma unroll
  for (int j = 0; j < 4; ++j) v[j] = (i0 + j < NN) ? cur[i0 + j] : 0u;
  sh[t] = v[0] + v[1] + v[2] + v[3];
  __syncthreads();
  for (int off = 1; off < 256; off <<= 1) {
    u32t add = (t >= off) ? sh[t - off] : 0u;
    __syncthreads();
    sh[t] += add;
    __syncthreads();
  }
  u32t run = bsum[b] + ((t == 0) ? 0u : sh[t - 1]);
#pragma unroll
  for (int j = 0; j < 4; ++j) {
    const int i = i0 + j;
    if (i < NN) { rs[i] = run; cur[i] = run; }
    run += v[j];
  }
}

__global__ __launch_bounds__(256) void k_scatter(const int* __restrict__ ei,
                                                 u32t* __restrict__ cur, int* __restrict__ ssrc) {
  const int i = blockIdx.x * 256 + threadIdx.x;
  if (i < NE) {
    const int src = ei[i], dst = ei[NE + i];
    const u32t pos = atomicAdd(&cur[dst], 1u);
    ssrc[pos] = src;
  }
}

// ---------------- GNN kernels ----------------

// layer0 part A: u = x @ W1 (78->32) via fp16 MFMA. 64 nodes/block.
__global__ __launch_bounds__(256) void k_mlp1_first(
    const float* __restrict__ x, const float* __restrict__ W1, u16t* __restrict__ u)
{
  __shared__ __align__(16) u16t Xh[64 * 104];
  __shared__ __align__(16) u16t Wt[32 * 104];
  __shared__ __align__(16) u16t Uh[64 * 40];
  const int t = threadIdx.x;
  const int n0b = blockIdx.x * 64;
  for (int id = t; id < 64 * 78; id += 256) {
    const int row = id / 78, k = id - row * 78;
    Xh[row * 104 + k] = f2h(x[(size_t)n0b * 78 + id]);
  }
  for (int id = t; id < 64 * 18; id += 256) {
    const int row = id / 18, k = 78 + (id - row * 18);
    Xh[row * 104 + k] = 0;
  }
  for (int id = t; id < 78 * 32; id += 256) {
    const int k = id >> 5, c = id & 31;
    Wt[c * 104 + k] = f2h(W1[id]);
  }
  for (int id = t; id < 32 * 18; id += 256) {
    const int c = id / 18, k = 78 + (id - c * 18);
    Wt[c * 104 + k] = 0;
  }
  __syncthreads();
  {
    const int w = t >> 6, l = t & 63, col = l & 15, kg = l >> 4;
    const int m0 = w * 16;
    f32x4 ac0 = {0.f, 0.f, 0.f, 0.f}, ac1 = {0.f, 0.f, 0.f, 0.f};
#pragma unroll
    for (int ks = 0; ks < 3; ++ks) {
      const f16x8 af = *(const f16x8*)(Xh + (m0 + col) * 104 + ks * 32 + kg * 8);
      const f16x8 bf0 = *(const f16x8*)(Wt + col * 104 + ks * 32 + kg * 8);
      const f16x8 bf1 = *(const f16x8*)(Wt + (16 + col) * 104 + ks * 32 + kg * 8);
      ac0 = __builtin_amdgcn_mfma_f32_16x16x32_f16(af, bf0, ac0, 0, 0, 0);
      ac1 = __builtin_amdgcn_mfma_f32_16x16x32_f16(af, bf1, ac1, 0, 0, 0);
    }
#pragma unroll
    for (int r = 0; r < 4; ++r) {
      const int m = m0 + kg * 4 + r;
      Uh[m * 40 + col] = f2h(ac0[r]);
      Uh[m * 40 + 16 + col] = f2h(ac1[r]);
    }
  }
  __syncthreads();
  {
    const int row = t >> 2;
    const uint4 v = *(const uint4*)(Uh + row * 40 + (t & 3) * 8);
    *(uint4*)(u + (size_t)(n0b + row) * 32 + (t & 3) * 8) = v;
  }
}

// layer0 part B: gather (direct CSR) + fp16-MFMA MLP (standalone; can't overlap cnn: U@0)
__global__ __launch_bounds__(256) void k_agg0(
    const u16t* __restrict__ u, const u32t* __restrict__ rs, const int* __restrict__ ssrc,
    const float* __restrict__ b1, const float* __restrict__ W2, const float* __restrict__ b2,
    u16t* __restrict__ yout, float* __restrict__ stats_out)
{
  __shared__ __align__(16) u16t W2t[32 * 40];
  __shared__ __align__(16) u16t A1h[64 * 40];
  __shared__ __align__(16) u16t A2h[64 * 40];
  __shared__ float red[256];
  __shared__ u32t rss[65];
  const int t = threadIdx.x;
  const int n0b = blockIdx.x * 64;
  for (int id = t; id < 1024; id += 256) {
    int k = id >> 5, c = id & 31;
    W2t[c * 40 + k] = f2h(W2[id]);
  }
  if (t < 65) rss[t] = rs[n0b + t];
  __syncthreads();
  const int nl = t >> 2, c0 = (t & 3) * 8;
  {
    const int n = n0b + nl;
    float a[8] = {};
    add8h(a, *(const uint4*)(u + (size_t)n * 32 + c0));
    const u32t e0 = rss[nl], e1 = rss[nl + 1];
    u32t e = e0;
    for (; e + 4 <= e1; e += 4) {
      const int s0v = ssrc[e], s1v = ssrc[e + 1], s2v = ssrc[e + 2], s3v = ssrc[e + 3];
      const uint4 v0 = *(const uint4*)(u + (size_t)s0v * 32 + c0);
      const uint4 v1 = *(const uint4*)(u + (size_t)s1v * 32 + c0);
      const uint4 v2 = *(const uint4*)(u + (size_t)s2v * 32 + c0);
      const uint4 v3 = *(const uint4*)(u + (size_t)s3v * 32 + c0);
      add8h(a, v0); add8h(a, v1); add8h(a, v2); add8h(a, v3);
    }
    for (; e < e1; ++e)
      add8h(a, *(const uint4*)(u + (size_t)ssrc[e] * 32 + c0));
    union { u16t h[8]; uint4 v; } pk;
#pragma unroll
    for (int j = 0; j < 8; ++j) pk.h[j] = f2h(fmaxf(a[j] + b1[c0 + j], 0.f));
    *(uint4*)(A1h + nl * 40 + c0) = pk.v;
  }
  __syncthreads();
  {
    const int w = t >> 6, l = t & 63, col = l & 15, kg = l >> 4;
    const int m0 = w * 16;
    const f16x8 af = *(const f16x8*)(A1h + (m0 + col) * 40 + kg * 8);
    const f16x8 bf0 = *(const f16x8*)(W2t + col * 40 + kg * 8);
    const f16x8 bf1 = *(const f16x8*)(W2t + (16 + col) * 40 + kg * 8);
    f32x4 ac0 = {0.f, 0.f, 0.f, 0.f}, ac1 = {0.f, 0.f, 0.f, 0.f};
    ac0 = __builtin_amdgcn_mfma_f32_16x16x32_f16(af, bf0, ac0, 0, 0, 0);
    ac1 = __builtin_amdgcn_mfma_f32_16x16x32_f16(af, bf1, ac1, 0, 0, 0);
    const float bb0 = b2[col], bb1 = b2[16 + col];
#pragma unroll
    for (int r = 0; r < 4; ++r) {
      const int m = m0 + kg * 4 + r;
      A2h[m * 40 + col] = f2h(fmaxf(ac0[r] + bb0, 0.f));
      A2h[m * 40 + 16 + col] = f2h(fmaxf(ac1[r] + bb1, 0.f));
    }
  }
  __syncthreads();
  const int c = t & 31;
  float rsum = 0.f, rq = 0.f;
#pragma unroll
  for (int rep = 0; rep < 8; ++rep) {
    const int row = (t >> 5) + rep * 8;
    const float v = h2f(A2h[row * 40 + c]);
    rsum += v;
    rq += v * v;
  }
  {
    const int row = t >> 2;
    const uint4 v = *(const uint4*)(A2h + row * 40 + (t & 3) * 8);
    *(uint4*)(yout + (size_t)(n0b + row) * 32 + (t & 3) * 8) = v;
  }
  rsum += __shfl_down(rsum, 32);
  rq += __shfl_down(rq, 32);
  __syncthreads();
  const int wv_ = t >> 6, lane = t & 63;
  if (lane < 32) {
    red[wv_ * 32 + lane] = rsum;
    red[128 + wv_ * 32 + lane] = rq;
  }
  __syncthreads();
  if (t < 32) {
    float aa = red[t] + red[32 + t] + red[64 + t] + red[96 + t];
    float bb = red[128 + t] + red[160 + t] + red[192 + t] + red[224 + t];
    unsafeAtomicAdd(&stats_out[t], aa);
    unsafeAtomicAdd(&stats_out[32 + t], bb);
  }
}

// ---- layer body (layers 1..4), operating out of a shared LDS arena ----
__device__ __forceinline__ void layer_body(
    int bid, char* smem,
    const u16t* __restrict__ yin, const u32t* __restrict__ rs, const int* __restrict__ ssrc,
    const float* __restrict__ stats, const float* __restrict__ gamma, const float* __restrict__ beta,
    const float* __restrict__ W1, const float* __restrict__ b1,
    const float* __restrict__ W2, const float* __restrict__ b2,
    u16t* __restrict__ yout, float* __restrict__ stats_out)
{
  u16t* W1t = (u16t*)smem;              // 2560 B
  u16t* W2t = (u16t*)(smem + 2560);     // 2560 B
  u16t* A1h = (u16t*)(smem + 5120);     // 5120 B
  u16t* A2h = (u16t*)(smem + 10240);    // 5120 B
  float* red = (float*)(smem + 15360);  // 1024 B
  u32t* rss = (u32t*)(smem + 16384);    // 260 B
  const int t = threadIdx.x;
  const int n0b = bid * 64;
  for (int id = t; id < 1024; id += 256) {
    int k = id >> 5, c = id & 31;
    W1t[c * 40 + k] = f2h(W1[id]);
    W2t[c * 40 + k] = f2h(W2[id]);
  }
  if (t < 65) rss[t] = rs[n0b + t];
  __syncthreads();
  const int nl = t >> 2, c0 = (t & 3) * 8;
  {
    const int n = n0b + nl;
    float sc[8], sh[8];
#pragma unroll
    for (int j = 0; j < 8; ++j) {
      const int c = c0 + j;
      const float mu = stats[c] * (1.f / NN);
      float var = fmaxf(stats[32 + c] * (1.f / NN) - mu * mu, 0.f);
      sc[j] = gamma[c] * rsqrtf(var + BN_EPS);
      sh[j] = beta[c] - mu * sc[j];
    }
    float a[8] = {};
    add8h(a, *(const uint4*)(yin + (size_t)n * 32 + c0));
    const u32t e0 = rss[nl], e1 = rss[nl + 1];
    u32t e = e0;
    for (; e + 4 <= e1; e += 4) {
      const int s0v = ssrc[e], s1v = ssrc[e + 1], s2v = ssrc[e + 2], s3v = ssrc[e + 3];
      const uint4 v0 = *(const uint4*)(yin + (size_t)s0v * 32 + c0);
      const uint4 v1 = *(const uint4*)(yin + (size_t)s1v * 32 + c0);
      const uint4 v2 = *(const uint4*)(yin + (size_t)s2v * 32 + c0);
      const uint4 v3 = *(const uint4*)(yin + (size_t)s3v * 32 + c0);
      add8h(a, v0); add8h(a, v1); add8h(a, v2); add8h(a, v3);
    }
    for (; e < e1; ++e)
      add8h(a, *(const uint4*)(yin + (size_t)ssrc[e] * 32 + c0));
    const float cnt = (float)(e1 - e0 + 1u);
    union { u16t h[8]; uint4 v; } pk;
#pragma unroll
    for (int j = 0; j < 8; ++j) pk.h[j] = f2h(sc[j] * a[j] + cnt * sh[j]);
    *(uint4*)(A1h + nl * 40 + c0) = pk.v;
  }
  __syncthreads();
  const int w = t >> 6, l = t & 63, col = l & 15, kg = l >> 4;
  const int m0 = w * 16;
  {
    const f16x8 af = *(const f16x8*)(A1h + (m0 + col) * 40 + kg * 8);
    const f16x8 bf0 = *(const f16x8*)(W1t + col * 40 + kg * 8);
    const f16x8 bf1 = *(const f16x8*)(W1t + (16 + col) * 40 + kg * 8);
    f32x4 ac0 = {0.f, 0.f, 0.f, 0.f}, ac1 = {0.f, 0.f, 0.f, 0.f};
    ac0 = __builtin_amdgcn_mfma_f32_16x16x32_f16(af, bf0, ac0, 0, 0, 0);
    ac1 = __builtin_amdgcn_mfma_f32_16x16x32_f16(af, bf1, ac1, 0, 0, 0);
    const float bb0 = b1[col], bb1 = b1[16 + col];
#pragma unroll
    for (int r = 0; r < 4; ++r) {
      const int m = m0 + kg * 4 + r;
      A2h[m * 40 + col] = f2h(fmaxf(ac0[r] + bb0, 0.f));
      A2h[m * 40 + 16 + col] = f2h(fmaxf(ac1[r] + bb1, 0.f));
    }
  }
  __syncthreads();
  {
    const f16x8 af = *(const f16x8*)(A2h + (m0 + col) * 40 + kg * 8);
    const f16x8 bf0 = *(const f16x8*)(W2t + col * 40 + kg * 8);
    const f16x8 bf1 = *(const f16x8*)(W2t + (16 + col) * 40 + kg * 8);
    f32x4 ac0 = {0.f, 0.f, 0.f, 0.f}, ac1 = {0.f, 0.f, 0.f, 0.f};
    ac0 = __builtin_amdgcn_mfma_f32_16x16x32_f16(af, bf0, ac0, 0, 0, 0);
    ac1 = __builtin_amdgcn_mfma_f32_16x16x32_f16(af, bf1, ac1, 0, 0, 0);
    const float bb0 = b2[col], bb1 = b2[16 + col];
#pragma unroll
    for (int r = 0; r < 4; ++r) {
      const int m = m0 + kg * 4 + r;
      A1h[m * 40 + col] = f2h(fmaxf(ac0[r] + bb0, 0.f));
      A1h[m * 40 + 16 + col] = f2h(fmaxf(ac1[r] + bb1, 0.f));
    }
  }
  __syncthreads();
  const int c = t & 31;
  float rsum = 0.f, rq = 0.f;
#pragma unroll
  for (int rep = 0; rep < 8; ++rep) {
    const int row = (t >> 5) + rep * 8;
    const float v = h2f(A1h[row * 40 + c]);
    rsum += v;
    rq += v * v;
  }
  {
    const int row = t >> 2;
    const uint4 v = *(const uint4*)(A1h + row * 40 + (t & 3) * 8);
    *(uint4*)(yout + (size_t)(n0b + row) * 32 + (t & 3) * 8) = v;
  }
  rsum += __shfl_down(rsum, 32);
  rq += __shfl_down(rq, 32);
  __syncthreads();
  const int wv_ = t >> 6, lane = t & 63;
  if (lane < 32) {
    red[wv_ * 32 + lane] = rsum;
    red[128 + wv_ * 32 + lane] = rq;
  }
  __syncthreads();
  if (t < 32) {
    float aa = red[t] + red[32 + t] + red[64 + t] + red[96 + t];
    float bb = red[128 + t] + red[160 + t] + red[192 + t] + red[224 + t];
    unsafeAtomicAdd(&stats_out[t], aa);
    unsafeAtomicAdd(&stats_out[32 + t], bb);
  }
}

// ---- fused per-graph CNN body (round-9 structure), parameterized by graph g ----
__device__ __forceinline__ void cnn_body(
    int g, char* smem,
    const float* __restrict__ xo,
    const float* __restrict__ w1, const float* __restrict__ b1,
    const u16t* __restrict__ W2k, const float* __restrict__ b2,
    const u16t* __restrict__ W3k, const float* __restrict__ b3,
    u16t* __restrict__ t3)
{
  float* xot = (float*)(smem);
  float* w1s = (float*)(smem + 3072);
  float* b2s = (float*)(smem + 4096);
  float* b3s = (float*)(smem + 4352);
  short* T1T = (short*)(smem + 4864);
  char*  T2B = smem + 20736;
  u16t*  stg = (u16t*)(smem + 4864);

  const int t = threadIdx.x;
  const int w = t >> 6, l = t & 63, col = l & 15, kg = l >> 4;

  for (int i = t; i < 768; i += 256) xot[i] = (i < 735) ? xo[(size_t)g * 735 + i] : 0.f;
  w1s[t] = w1[t];
  if (t < 64) b2s[t] = b2[t];
  if (t < 128) b3s[t] = b3[t];
  if (t < 192) {
    int r = 242 + (t >> 5), c = t & 31;
    T1T[r * 32 + c] = 0;
  }
  __syncthreads();

  {
    const int c = t >> 3, qg = t & 7;
    float wv[8];
#pragma unroll
    for (int j = 0; j < 8; ++j) wv[j] = w1s[c * 8 + j];
    const float bias = b1[c];
    const int q0 = qg * 31, qe = (q0 + 31 < 242) ? q0 + 31 : 242;
#pragma unroll 1
    for (int qc = q0; qc < qe; qc += 10) {
      const int cnt = (qe - qc < 10) ? qe - qc : 10;
      float xv[37];
#pragma unroll
      for (int j = 0; j < 37; ++j) xv[j] = xot[3 * qc + j];
#pragma unroll
      for (int j0 = 0; j0 < 10; ++j0) {
        if (j0 < cnt) {
          float a0 = bias, a1 = bias, a2 = bias;
#pragma unroll
          for (int tt = 0; tt < 8; ++tt) {
            a0 = fmaf(wv[tt], xv[3 * j0 + tt], a0);
            a1 = fmaf(wv[tt], xv[3 * j0 + 1 + tt], a1);
            a2 = fmaf(wv[tt], xv[3 * j0 + 2 + tt], a2);
          }
          float m = fmaxf(fmaxf(a0, a1), fmaxf(a2, 0.f));
          const int pos = qc + j0;
          T1T[pos * 32 + (c ^ ((pos & 3) << 3))] = (short)f2bf(m);
        }
      }
    }
  }
  __syncthreads();

  {
    bf16x8 am[8];
#pragma unroll
    for (int kk = 0; kk < 8; ++kk)
      am[kk] = *(const bf16x8*)(W2k + (w * 16 + col) * 256 + kk * 32 + kg * 8);
#pragma unroll 1
    for (int qt = 0; qt < 5; ++qt) {
      const int rbase = qt * 48 + col * 3;
      bf16x8 rv[10];
#pragma unroll
      for (int s = 0; s < 10; ++s) {
        const int row = rbase + s;
        rv[s] = *(const bf16x8*)(T1T + row * 32 + ((kg ^ (row & 3)) << 3));
      }
      f32x4 a0 = {0.f, 0.f, 0.f, 0.f}, a1 = a0, a2 = a0;
#pragma unroll
      for (int kk = 0; kk < 8; ++kk) {
        a0 = __builtin_amdgcn_mfma_f32_16x16x32_bf16(am[kk], rv[kk], a0, 0, 0, 0);
        a1 = __builtin_amdgcn_mfma_f32_16x16x32_bf16(am[kk], rv[kk + 1], a1, 0, 0, 0);
        a2 = __builtin_amdgcn_mfma_f32_16x16x32_bf16(am[kk], rv[kk + 2], a2, 0, 0, 0);
      }
      const int q = qt * 16 + col;
      if (q < 78) {
        union { u16t u[4]; uint2 v; } pk;
#pragma unroll
        for (int r = 0; r < 4; ++r) {
          const float bb = b2s[w * 16 + kg * 4 + r];
          float m = fmaxf(fmaxf(a0[r], a1[r]), a2[r]);
          pk.u[r] = f2bf(fmaxf(m + bb, 0.f));
        }
        const int boff = (q * 128 + (w * 16 + kg * 4) * 2) ^ ((q & 7) << 4);
        *(uint2*)(T2B + boff) = pk.v;
      }
    }
  }
  __syncthreads();

  {
#pragma unroll 1
    for (int mi = 0; mi < 2; ++mi) {
      const int m3 = w * 2 + mi;
      f32x4 acc[2][3];
#pragma unroll
      for (int qt = 0; qt < 2; ++qt)
#pragma unroll
        for (int r = 0; r < 3; ++r) acc[qt][r] = (f32x4){0.f, 0.f, 0.f, 0.f};
#pragma unroll 1
      for (int kh = 0; kh < 2; ++kh) {
        bf16x8 amh[8];
#pragma unroll
        for (int tt = 0; tt < 8; ++tt)
          amh[tt] = *(const bf16x8*)(W3k + (m3 * 16 + col) * 512 + (tt * 2 + kh) * 32 + kg * 8);
#pragma unroll
        for (int qt = 0; qt < 2; ++qt) {
          const int rbase = qt * 48 + col * 3;
          bf16x8 rv[10];
#pragma unroll
          for (int s = 0; s < 10; ++s) {
            int row = rbase + s;
            row = (row < 78) ? row : 77;
            const int boff = (row * 128 + kh * 64 + kg * 16) ^ ((row & 7) << 4);
            rv[s] = *(const bf16x8*)(T2B + boff);
          }
#pragma unroll
          for (int tt = 0; tt < 8; ++tt) {
            acc[qt][0] = __builtin_amdgcn_mfma_f32_16x16x32_bf16(amh[tt], rv[tt], acc[qt][0], 0, 0, 0);
            acc[qt][1] = __builtin_amdgcn_mfma_f32_16x16x32_bf16(amh[tt], rv[tt + 1], acc[qt][1], 0, 0, 0);
            acc[qt][2] = __builtin_amdgcn_mfma_f32_16x16x32_bf16(amh[tt], rv[tt + 2], acc[qt][2], 0, 0, 0);
          }
        }
      }
#pragma unroll
      for (int qt = 0; qt < 2; ++qt) {
        const int q = qt * 16 + col;
        if (q < 23) {
#pragma unroll
          for (int r = 0; r < 4; ++r) {
            const int c = m3 * 16 + kg * 4 + r;
            float m = fmaxf(fmaxf(acc[qt][0][r], acc[qt][1][r]), acc[qt][2][r]);
            stg[c * 23 + q] = f2bf(fmaxf(m + b3s[c], 0.f));
          }
        }
      }
    }
  }
  __syncthreads();

  {
    const uint4* s4 = (const uint4*)stg;
    uint4* d4 = (uint4*)(t3 + (size_t)g * 2944);
    for (int id = t; id < 368; id += 256) d4[id] = s4[id];
  }
}

// ---- fused launch: 5 layer blocks + 2 cnn blocks per group of 7 ----
// grid = 3125*7 = 21875 (layers: 15625 = NN/64; cnn chunk: 6250 graphs)
__global__ __launch_bounds__(256, 4) void k_fused(
    const u16t* __restrict__ yin, const u32t* __restrict__ rs, const int* __restrict__ ssrc,
    const float* __restrict__ stats, const float* __restrict__ gamma, const float* __restrict__ beta,
    const float* __restrict__ W1, const float* __restrict__ b1,
    const float* __restrict__ W2, const float* __restrict__ b2,
    u16t* __restrict__ yout, float* __restrict__ stats_out,
    const float* __restrict__ xo, const float* __restrict__ c1W, const float* __restrict__ c1b,
    const u16t* __restrict__ W2k, const float* __restrict__ c2b,
    const u16t* __restrict__ W3k, const float* __restrict__ c3b,
    u16t* __restrict__ t3, int cnn_g0)
{
  __shared__ __align__(16) char smem[30720];
  const int grp = blockIdx.x / 7, rem = blockIdx.x % 7;
  if (rem < 5)
    layer_body(grp * 5 + rem, smem, yin, rs, ssrc, stats, gamma, beta,
               W1, b1, W2, b2, yout, stats_out);
  else
    cnn_body(cnn_g0 + grp * 2 + (rem - 5), smem, xo, c1W, c1b, W2k, c2b, W3k, c3b, t3);
}

__global__ __launch_bounds__(64) void k_pool_xd(
    const u16t* __restrict__ y, const int* __restrict__ batch,
    const float* __restrict__ stats, const float* __restrict__ gamma,
    const float* __restrict__ beta, const float* __restrict__ Wxd,
    const float* __restrict__ bxd, u16t* __restrict__ xc)
{
  const int g = blockIdx.x, t = threadIdx.x;
  int lo = 0, n = NN;
  while (n > 0) {
    int h = n >> 1, m = lo + h;
    if (batch[m] < g) { lo = m + 1; n -= h + 1; } else n = h;
  }
  int hi = lo;
  n = NN - lo;
  while (n > 0) {
    int h = n >> 1, m = hi + h;
    if (batch[m] < g + 1) { hi = m + 1; n -= h + 1; } else n = h;
  }
  const int c = t & 31;
  const float mu = stats[4 * 64 + c] * (1.f / NN);
  float var = fmaxf(stats[4 * 64 + 32 + c] * (1.f / NN) - mu * mu, 0.f);
  const float sc = gamma[4 * 32 + c] * rsqrtf(var + BN_EPS);
  const float sh = beta[4 * 32 + c] - mu * sc;
  float acc = 0.f;
  for (int i = lo + (t >> 5); i < hi; i += 2) acc += h2f(y[(size_t)i * 32 + c]);
  acc += __shfl_down(acc, 32);
  __shared__ float pl[32];
  if (t < 32) pl[t] = acc * sc + (float)(hi - lo) * sh;
  __syncthreads();
#pragma unroll
  for (int rep = 0; rep < 2; ++rep) {
    const int o = t + rep * 64;
    float a = bxd[o];
#pragma unroll
    for (int cc = 0; cc < 32; ++cc) a = fmaf(pl[cc], Wxd[cc * 128 + o], a);
    xc[(size_t)g * 256 + o] = f2bf(fmaxf(a, 0.f));
  }
}

// ---------------- weight prep ----------------
__global__ __launch_bounds__(256) void k_prep(
    const float* __restrict__ w2, const float* __restrict__ w3,
    const float* __restrict__ wxt, const float* __restrict__ wf1, const float* __restrict__ wf2,
    u16t* __restrict__ W2k, u16t* __restrict__ W3k,
    u16t* __restrict__ WXT, u16t* __restrict__ WF1, u16t* __restrict__ WF2)
{
  const int i = blockIdx.x * 256 + threadIdx.x;
  if (i < 64 * 256) {
    int c2 = i >> 8, kk = i & 255, tt = kk >> 5, ci = kk & 31;
    W2k[i] = f2bf(w2[c2 * 256 + ci * 8 + tt]);
  }
  if (i < 128 * 512) {
    int c3 = i >> 9, kk = i & 511, tt = kk >> 6, ci = kk & 63;
    W3k[i] = f2bf(w3[c3 * 512 + ci * 8 + tt]);
  }
  if (i < 128 * 2944) {
    int nn = i / 2944, kk = i - nn * 2944;
    WXT[i] = f2bf(wxt[kk * 128 + nn]);
  }
  if (i < 1024 * 256) {
    int nn = i >> 8, kk = i & 255;
    WF1[i] = f2bf(wf1[kk * 1024 + nn]);
  }
  if (i < 128 * 1024) {
    int nn = i >> 10, kk = i & 1023;
    WF2[i] = f2bf(wf2[kk * 128 + nn]);
  }
}

// ---------------- bf16 MFMA GEMM ----------------
__global__ __launch_bounds__(256) void k_mgemm(
    const u16t* __restrict__ A, int lda,
    const u16t* __restrict__ WT, const float* __restrict__ bias,
    void* __restrict__ Cv, int ldc, int c_off, int M, int Kd,
    int relu_f, int out32)
{
  __shared__ __align__(16) u16t As[128 * 4 * 8];
  __shared__ __align__(16) u16t Ws2[64 * 4 * 8];
  const int t = threadIdx.x;
  const int w = t >> 6, l = t & 63, col = l & 15, kg = l >> 4;
  const int wm = w & 1, wn = w >> 1;
  const int m0 = blockIdx.x * 128, n0 = blockIdx.y * 64;
  f32x4 acc[4][2];
#pragma unroll
  for (int i = 0; i < 4; ++i)
#pragma unroll
    for (int j = 0; j < 2; ++j) acc[i][j] = (f32x4){0.f, 0.f, 0.f, 0.f};
  const int ar = t >> 1, ac = (t & 1) * 2;
  const int wr = t >> 2, wc = t & 3;
  const bool aok = (m0 + ar) < M;
  const u16t* Ap = A + (size_t)(m0 + ar) * lda;
  const u16t* Wp = WT + (size_t)(n0 + wr) * Kd;
  for (int k0 = 0; k0 < Kd; k0 += 32) {
    bf16x8 av0 = {0, 0, 0, 0, 0, 0, 0, 0}, av1 = {0, 0, 0, 0, 0, 0, 0, 0};
    if (aok) {
      av0 = *(const bf16x8*)(Ap + k0 + ac * 8);
      av1 = *(const bf16x8*)(Ap + k0 + (ac + 1) * 8);
    }
    const bf16x8 wv = *(const bf16x8*)(Wp + k0 + wc * 8);
    __syncthreads();
    *(bf16x8*)(As + (ar * 4 + (ac ^ (ar & 3))) * 8) = av0;
    *(bf16x8*)(As + (ar * 4 + ((ac + 1) ^ (ar & 3))) * 8) = av1;
    *(bf16x8*)(Ws2 + (wr * 4 + (wc ^ (wr & 3))) * 8) = wv;
    __syncthreads();
    bf16x8 af[4], bf[2];
#pragma unroll
    for (int i = 0; i < 4; ++i) {
      const int R = wm * 64 + i * 16 + col;
      af[i] = *(const bf16x8*)(As + (R * 4 + (kg ^ (R & 3))) * 8);
    }
#pragma unroll
    for (int j = 0; j < 2; ++j) {
      const int R = wn * 32 + j * 16 + col;
      bf[j] = *(const bf16x8*)(Ws2 + (R * 4 + (kg ^ (R & 3))) * 8);
    }
#pragma unroll
    for (int i = 0; i < 4; ++i)
#pragma unroll
      for (int j = 0; j < 2; ++j)
        acc[i][j] = __builtin_amdgcn_mfma_f32_16x16x32_bf16(af[i], bf[j], acc[i][j], 0, 0, 0);
  }
#pragma unroll
  for (int j = 0; j < 2; ++j) {
    const int gn = n0 + wn * 32 + j * 16 + col;
    const float bb = bias[gn];
#pragma unroll
    for (int i = 0; i < 4; ++i) {
      const int gmb = m0 + wm * 64 + i * 16 + kg * 4;
#pragma unroll
      for (int r = 0; r < 4; ++r) {
        const int gm = gmb + r;
        if (gm < M) {
          float v = acc[i][j][r] + bb;
          if (relu_f) v = fmaxf(v, 0.f);
          if (out32) ((float*)Cv)[(size_t)gm * ldc + c_off + gn] = v;
          else ((u16t*)Cv)[(size_t)gm * ldc + c_off + gn] = f2bf(v);
        }
      }
    }
  }
}

__global__ __launch_bounds__(256) void k_out(
    const float* __restrict__ h2, const float* __restrict__ Wo,
    const float* __restrict__ bo, float* __restrict__ out)
{
  __shared__ float Ws_[128];
  const int t = threadIdx.x;
  if (t < 128) Ws_[t] = Wo[t];
  __syncthreads();
  const int g = blockIdx.x * 32 + (t >> 3), l = t & 7;
  float acc = 0.f;
  if (g < NG) {
    const float* hr = h2 + (size_t)g * 128 + l * 16;
    const float* wr = Ws_ + l * 16;
#pragma unroll
    for (int j = 0; j < 16; ++j) acc = fmaf(hr[j], wr[j], acc);
  }
  acc += __shfl_down(acc, 4, 8);
  acc += __shfl_down(acc, 2, 8);
  acc += __shfl_down(acc, 1, 8);
  if (l == 0 && g < NG) out[g] = acc + bo[0];
}

extern "C" void kernel_launch(void* const* d_in, const int* in_sizes, int n_in,
                              void* d_out, int out_size, void* d_ws, size_t ws_size,
                              hipStream_t stream) {
  const float* x    = (const float*)d_in[0];
  const int*   ei   = (const int*)d_in[1];
  const int*   batch= (const int*)d_in[2];
  const float* xo   = (const float*)d_in[3];
  const float* g1W1 = (const float*)d_in[4];
  const float* g1b1 = (const float*)d_in[5];
  const float* g1W2 = (const float*)d_in[6];
  const float* g1b2 = (const float*)d_in[7];
  const float* gsW1 = (const float*)d_in[8];
  const float* gsb1 = (const float*)d_in[9];
  const float* gsW2 = (const float*)d_in[10];
  const float* gsb2 = (const float*)d_in[11];
  const float* bng  = (const float*)d_in[12];
  const float* bnb  = (const float*)d_in[13];
  const float* Wxd  = (const float*)d_in[14];
  const float* bxd  = (const float*)d_in[15];
  const float* c1W  = (const float*)d_in[16];
  const float* c1b  = (const float*)d_in[17];
  const float* c2W  = (const float*)d_in[18];
  const float* c2b  = (const float*)d_in[19];
  const float* c3W  = (const float*)d_in[20];
  const float* c3b  = (const float*)d_in[21];
  const float* Wxt  = (const float*)d_in[22];
  const float* bxt  = (const float*)d_in[23];
  const float* W1f  = (const float*)d_in[24];
  const float* b1f  = (const float*)d_in[25];
  const float* W2f  = (const float*)d_in[26];
  const float* b2f  = (const float*)d_in[27];
  const float* Wo   = (const float*)d_in[28];
  const float* bo   = (const float*)d_in[29];

  char* ws = (char*)d_ws;
  u16t*  U    = (u16t*)(ws + OFF_U);
  u16t*  YA   = (u16t*)(ws + OFF_YA);
  u16t*  YB   = (u16t*)(ws + OFF_YB);
  float* ST   = (float*)(ws + OFF_ST);
  u32t*  RS   = (u32t*)(ws + OFF_RS);
  u32t*  CUR  = (u32t*)(ws + OFF_CUR);
  u32t*  BS   = (u32t*)(ws + OFF_BSUM);
  int*   SSRC = (int*)(ws + OFF_SSRC);
  u16t*  WK   = (u16t*)(ws + OFF_WK);
  u16t*  W2K  = WK;
  u16t*  W3K  = WK + 16384;
  u16t*  WXT  = WK + 16384 + 65536;
  u16t*  WF1  = WK + 16384 + 65536 + 376832;
  u16t*  WF2  = WK + 16384 + 65536 + 376832 + 262144;
  u16t*  XC   = (u16t*)(ws + OFF_XC);
  u16t*  T3   = (u16t*)(ws + OFF_T3);
  u16t*  H1   = (u16t*)(ws + OFF_H1);
  float* H2   = (float*)(ws + OFF_H2);
  float* OUT  = (float*)d_out;

  const int NBLK = (NN + 1023) / 1024;

  hipMemsetAsync(ST, 0, 5 * 64 * sizeof(float), stream);
  hipMemsetAsync(CUR, 0, NN * sizeof(u32t), stream);

  k_prep<<<(128 * 2944 + 255) / 256, 256, 0, stream>>>(c2W, c3W, Wxt, W1f, W2f,
                                                        W2K, W3K, WXT, WF1, WF2);

  k_hist<<<(NE + 255) / 256, 256, 0, stream>>>(ei, CUR);
  k_scan1<<<NBLK, 256, 0, stream>>>(CUR, BS);
  k_scan2<<<1, 256, 0, stream>>>(BS, RS, NBLK);
  k_scan3<<<NBLK, 256, 0, stream>>>(CUR, RS, BS);
  k_scatter<<<(NE + 255) / 256, 256, 0, stream>>>(ei, CUR, SSRC);

  k_mlp1_first<<<NN / 64, 256, 0, stream>>>(x, g1W1, U);
  k_agg0<<<NN / 64, 256, 0, stream>>>(U, RS, SSRC, g1b1, g1W2, g1b2, YA, ST + 0);

  // layers 1..4 fused with CNN chunks (6250 graphs each; CNN independent of GNN)
  const u16t* yin = YA;
  u16t* yout = YB;
  for (int lyr = 1; lyr <= 4; ++lyr) {
    k_fused<<<21875, 256, 0, stream>>>(yin, RS, SSRC, ST + (lyr - 1) * 64,
                                       bng + (lyr - 1) * 32, bnb + (lyr - 1) * 32,
                                       gsW1 + (lyr - 1) * 1024, gsb1 + (lyr - 1) * 32,
                                       gsW2 + (lyr - 1) * 1024, gsb2 + (lyr - 1) * 32,
                                       yout, ST + lyr * 64,
                                       xo, c1W, c1b, W2K, c2b, W3K, c3b, T3,
                                       (lyr - 1) * 6250);
    const u16t* tmp = yin;
    yin = yout;
    yout = (u16t*)tmp;
  }
  // yin == YA after 4 layers
  k_pool_xd<<<NG, 64, 0, stream>>>(yin, batch, ST, bng, bnb, Wxd, bxd, XC);

  {
    dim3 grid((NG + 127) / 128, 2);
    k_mgemm<<<grid, 256, 0, stream>>>(T3, 2944, WXT, bxt, XC, 256, 128, NG, 2944, 0, 0);
  }
  {
    dim3 grid((NG + 127) / 128, 16);
    k_mgemm<<<grid, 256, 0, stream>>>(XC, 256, WF1, b1f, H1, 1024, 0, NG, 256, 1, 0);
  }
  {
    dim3 grid((NG + 127) / 128, 2);
    k_mgemm<<<grid, 256, 0, stream>>>(H1, 1024, WF2, b2f, H2, 128, 0, NG, 1024, 1, 1);
  }
  k_out<<<(NG + 31) / 32, 256, 0, stream>>>(H2, Wo, bo, OUT);
}

// Round 16
// 1998.785 us; speedup vs baseline: 1.7251x; 1.0473x over previous
//
#include <hip/hip_runtime.h>

#define NN 1000000
#define NE 4000000
#define NG 25000
#define BN_EPS 1e-5f

typedef unsigned short u16t;
typedef unsigned int u32t;
typedef __attribute__((ext_vector_type(8))) short bf16x8;
typedef __attribute__((ext_vector_type(8))) _Float16 f16x8;
typedef __attribute__((ext_vector_type(4))) float f32x4;

__device__ inline u16t f2bf(float f) {
  u32t u = __float_as_uint(f);
  u32t r = (u + 0x7FFFu + ((u >> 16) & 1u)) >> 16;
  return (u16t)r;
}
__device__ inline float bf2f(u16t h) { return __uint_as_float((u32t)h << 16); }
__device__ inline u16t f2h(float f) {
  _Float16 h = (_Float16)f;
  return *(u16t*)&h;
}
__device__ inline float h2f(u16t v) {
  _Float16 h = *(_Float16*)&v;
  return (float)h;
}
__device__ inline void add8h(float* a, uint4 v) {
  union { uint4 u; _Float16 h[8]; } cv;
  cv.u = v;
#pragma unroll
  for (int j = 0; j < 8; ++j) a[j] += (float)cv.h[j];
}

// ---- workspace layout (bytes) ----
static const size_t OFF_U    = 0;
static const size_t OFF_T3   = 0;
static const size_t OFF_YA   = 150000000;
static const size_t OFF_YB   = 214000000;
static const size_t OFF_ST   = 278000000;
static const size_t OFF_RS   = 279000000;
static const size_t OFF_CUR  = 283200000;
static const size_t OFF_BSUM = 287300000;
static const size_t OFF_SSRC = 288000000;
static const size_t OFF_WK   = 304000000;
static const size_t OFF_XC   = 306000000;
static const size_t OFF_H1   = 150000000;
static const size_t OFF_H2   = 214000000;

// ---------------- CSR build ----------------
__global__ __launch_bounds__(256) void k_hist(const int* __restrict__ ei, u32t* __restrict__ cnt) {
  const int i = blockIdx.x * 256 + threadIdx.x;
  if (i < NE) atomicAdd(&cnt[ei[NE + i]], 1u);
}

__global__ __launch_bounds__(256) void k_scan1(const u32t* __restrict__ deg, u32t* __restrict__ bsum) {
  __shared__ u32t red[4];
  const int b = blockIdx.x, t = threadIdx.x;
  u32t s = 0;
#pragma unroll
  for (int j = 0; j < 4; ++j) {
    const int i = b * 1024 + j * 256 + t;
    if (i < NN) s += deg[i];
  }
#pragma unroll
  for (int off = 32; off > 0; off >>= 1) s += __shfl_down(s, off);
  if ((t & 63) == 0) red[t >> 6] = s;
  __syncthreads();
  if (t == 0) bsum[b] = red[0] + red[1] + red[2] + red[3];
}

__global__ __launch_bounds__(256) void k_scan2(u32t* __restrict__ bsum, u32t* __restrict__ rs, int nblk) {
  __shared__ u32t sh[256];
  const int t = threadIdx.x;
  u32t v[4];
#pragma unroll
  for (int j = 0; j < 4; ++j) {
    const int i = t * 4 + j;
    v[j] = (i < nblk) ? bsum[i] : 0u;
  }
  const u32t tot = v[0] + v[1] + v[2] + v[3];
  sh[t] = tot;
  __syncthreads();
  for (int off = 1; off < 256; off <<= 1) {
    u32t add = (t >= off) ? sh[t - off] : 0u;
    __syncthreads();
    sh[t] += add;
    __syncthreads();
  }
  const u32t tb = (t == 0) ? 0u : sh[t - 1];
  u32t run = tb;
#pragma unroll
  for (int j = 0; j < 4; ++j) {
    const int i = t * 4 + j;
    if (i < nblk) bsum[i] = run;
    run += v[j];
  }
  if (t == 0) rs[NN] = NE;
}

__global__ __launch_bounds__(256) void k_scan3(u32t* __restrict__ cur, u32t* __restrict__ rs,
                                               const u32t* __restrict__ bsum) {
  __shared__ u32t sh[256];
  const int b = blockIdx.x, t = threadIdx.x;
  const int i0 = b * 1024 + t * 4;
  u32t v[4];
#pragma unroll
  for (int j = 0; j < 4; ++j) v[j] = (i0 + j < NN) ? cur[i0 + j] : 0u;
  sh[t] = v[0] + v[1] + v[2] + v[3];
  __syncthreads();
  for (int off = 1; off < 256; off <<= 1) {
    u32t add = (t >= off) ? sh[t - off] : 0u;
    __syncthreads();
    sh[t] += add;
    __syncthreads();
  }
  u32t run = bsum[b] + ((t == 0) ? 0u : sh[t - 1]);
#pragma unroll
  for (int j = 0; j < 4; ++j) {
    const int i = i0 + j;
    if (i < NN) { rs[i] = run; cur[i] = run; }
    run += v[j];
  }
}

// dst-range-partitioned scatter: pass p handles dst>>17 == p (8 passes).
// Each pass's ssrc writes land in a ~2MB contiguous window -> L2 merges sectors
// (single-pass version: 4B scattered writes -> 16x HBM write amplification, 370us)
__global__ __launch_bounds__(256) void k_scatter(const int* __restrict__ ei,
                                                 u32t* __restrict__ cur, int* __restrict__ ssrc,
                                                 int pass) {
  const int i = blockIdx.x * 256 + threadIdx.x;
  if (i < NE) {
    const int dst = ei[NE + i];
    if ((dst >> 17) == pass) {
      const int src = ei[i];
      const u32t pos = atomicAdd(&cur[dst], 1u);
      ssrc[pos] = src;
    }
  }
}

// ---------------- GNN kernels ----------------

__global__ __launch_bounds__(256) void k_mlp1_first(
    const float* __restrict__ x, const float* __restrict__ W1, u16t* __restrict__ u)
{
  __shared__ __align__(16) u16t Xh[64 * 104];
  __shared__ __align__(16) u16t Wt[32 * 104];
  __shared__ __align__(16) u16t Uh[64 * 40];
  const int t = threadIdx.x;
  const int n0b = blockIdx.x * 64;
  for (int id = t; id < 64 * 78; id += 256) {
    const int row = id / 78, k = id - row * 78;
    Xh[row * 104 + k] = f2h(x[(size_t)n0b * 78 + id]);
  }
  for (int id = t; id < 64 * 18; id += 256) {
    const int row = id / 18, k = 78 + (id - row * 18);
    Xh[row * 104 + k] = 0;
  }
  for (int id = t; id < 78 * 32; id += 256) {
    const int k = id >> 5, c = id & 31;
    Wt[c * 104 + k] = f2h(W1[id]);
  }
  for (int id = t; id < 32 * 18; id += 256) {
    const int c = id / 18, k = 78 + (id - c * 18);
    Wt[c * 104 + k] = 0;
  }
  __syncthreads();
  {
    const int w = t >> 6, l = t & 63, col = l & 15, kg = l >> 4;
    const int m0 = w * 16;
    f32x4 ac0 = {0.f, 0.f, 0.f, 0.f}, ac1 = {0.f, 0.f, 0.f, 0.f};
#pragma unroll
    for (int ks = 0; ks < 3; ++ks) {
      const f16x8 af = *(const f16x8*)(Xh + (m0 + col) * 104 + ks * 32 + kg * 8);
      const f16x8 bf0 = *(const f16x8*)(Wt + col * 104 + ks * 32 + kg * 8);
      const f16x8 bf1 = *(const f16x8*)(Wt + (16 + col) * 104 + ks * 32 + kg * 8);
      ac0 = __builtin_amdgcn_mfma_f32_16x16x32_f16(af, bf0, ac0, 0, 0, 0);
      ac1 = __builtin_amdgcn_mfma_f32_16x16x32_f16(af, bf1, ac1, 0, 0, 0);
    }
#pragma unroll
    for (int r = 0; r < 4; ++r) {
      const int m = m0 + kg * 4 + r;
      Uh[m * 40 + col] = f2h(ac0[r]);
      Uh[m * 40 + 16 + col] = f2h(ac1[r]);
    }
  }
  __syncthreads();
  {
    const int row = t >> 2;
    const uint4 v = *(const uint4*)(Uh + row * 40 + (t & 3) * 8);
    *(uint4*)(u + (size_t)(n0b + row) * 32 + (t & 3) * 8) = v;
  }
}

__global__ __launch_bounds__(256) void k_agg0(
    const u16t* __restrict__ u, const u32t* __restrict__ rs, const int* __restrict__ ssrc,
    const float* __restrict__ b1, const float* __restrict__ W2, const float* __restrict__ b2,
    u16t* __restrict__ yout, float* __restrict__ stats_out)
{
  __shared__ __align__(16) u16t W2t[32 * 40];
  __shared__ __align__(16) u16t A1h[64 * 40];
  __shared__ __align__(16) u16t A2h[64 * 40];
  __shared__ float red[256];
  __shared__ u32t rss[65];
  const int t = threadIdx.x;
  const int n0b = blockIdx.x * 64;
  for (int id = t; id < 1024; id += 256) {
    int k = id >> 5, c = id & 31;
    W2t[c * 40 + k] = f2h(W2[id]);
  }
  if (t < 65) rss[t] = rs[n0b + t];
  __syncthreads();
  const int nl = t >> 2, c0 = (t & 3) * 8;
  {
    const int n = n0b + nl;
    float a[8] = {};
    add8h(a, *(const uint4*)(u + (size_t)n * 32 + c0));
    const u32t e0 = rss[nl], e1 = rss[nl + 1];
    u32t e = e0;
    for (; e + 4 <= e1; e += 4) {
      const int s0v = ssrc[e], s1v = ssrc[e + 1], s2v = ssrc[e + 2], s3v = ssrc[e + 3];
      const uint4 v0 = *(const uint4*)(u + (size_t)s0v * 32 + c0);
      const uint4 v1 = *(const uint4*)(u + (size_t)s1v * 32 + c0);
      const uint4 v2 = *(const uint4*)(u + (size_t)s2v * 32 + c0);
      const uint4 v3 = *(const uint4*)(u + (size_t)s3v * 32 + c0);
      add8h(a, v0); add8h(a, v1); add8h(a, v2); add8h(a, v3);
    }
    for (; e < e1; ++e)
      add8h(a, *(const uint4*)(u + (size_t)ssrc[e] * 32 + c0));
    union { u16t h[8]; uint4 v; } pk;
#pragma unroll
    for (int j = 0; j < 8; ++j) pk.h[j] = f2h(fmaxf(a[j] + b1[c0 + j], 0.f));
    *(uint4*)(A1h + nl * 40 + c0) = pk.v;
  }
  __syncthreads();
  {
    const int w = t >> 6, l = t & 63, col = l & 15, kg = l >> 4;
    const int m0 = w * 16;
    const f16x8 af = *(const f16x8*)(A1h + (m0 + col) * 40 + kg * 8);
    const f16x8 bf0 = *(const f16x8*)(W2t + col * 40 + kg * 8);
    const f16x8 bf1 = *(const f16x8*)(W2t + (16 + col) * 40 + kg * 8);
    f32x4 ac0 = {0.f, 0.f, 0.f, 0.f}, ac1 = {0.f, 0.f, 0.f, 0.f};
    ac0 = __builtin_amdgcn_mfma_f32_16x16x32_f16(af, bf0, ac0, 0, 0, 0);
    ac1 = __builtin_amdgcn_mfma_f32_16x16x32_f16(af, bf1, ac1, 0, 0, 0);
    const float bb0 = b2[col], bb1 = b2[16 + col];
#pragma unroll
    for (int r = 0; r < 4; ++r) {
      const int m = m0 + kg * 4 + r;
      A2h[m * 40 + col] = f2h(fmaxf(ac0[r] + bb0, 0.f));
      A2h[m * 40 + 16 + col] = f2h(fmaxf(ac1[r] + bb1, 0.f));
    }
  }
  __syncthreads();
  const int c = t & 31;
  float rsum = 0.f, rq = 0.f;
#pragma unroll
  for (int rep = 0; rep < 8; ++rep) {
    const int row = (t >> 5) + rep * 8;
    const float v = h2f(A2h[row * 40 + c]);
    rsum += v;
    rq += v * v;
  }
  {
    const int row = t >> 2;
    const uint4 v = *(const uint4*)(A2h + row * 40 + (t & 3) * 8);
    *(uint4*)(yout + (size_t)(n0b + row) * 32 + (t & 3) * 8) = v;
  }
  rsum += __shfl_down(rsum, 32);
  rq += __shfl_down(rq, 32);
  __syncthreads();
  const int wv_ = t >> 6, lane = t & 63;
  if (lane < 32) {
    red[wv_ * 32 + lane] = rsum;
    red[128 + wv_ * 32 + lane] = rq;
  }
  __syncthreads();
  if (t < 32) {
    float aa = red[t] + red[32 + t] + red[64 + t] + red[96 + t];
    float bb = red[128 + t] + red[160 + t] + red[192 + t] + red[224 + t];
    unsafeAtomicAdd(&stats_out[t], aa);
    unsafeAtomicAdd(&stats_out[32 + t], bb);
  }
}

// ---- layer body (layers 1..4) ----
__device__ __forceinline__ void layer_body(
    int bid, char* smem,
    const u16t* __restrict__ yin, const u32t* __restrict__ rs, const int* __restrict__ ssrc,
    const float* __restrict__ stats, const float* __restrict__ gamma, const float* __restrict__ beta,
    const float* __restrict__ W1, const float* __restrict__ b1,
    const float* __restrict__ W2, const float* __restrict__ b2,
    u16t* __restrict__ yout, float* __restrict__ stats_out)
{
  u16t* W1t = (u16t*)smem;
  u16t* W2t = (u16t*)(smem + 2560);
  u16t* A1h = (u16t*)(smem + 5120);
  u16t* A2h = (u16t*)(smem + 10240);
  float* red = (float*)(smem + 15360);
  u32t* rss = (u32t*)(smem + 16384);
  const int t = threadIdx.x;
  const int n0b = bid * 64;
  for (int id = t; id < 1024; id += 256) {
    int k = id >> 5, c = id & 31;
    W1t[c * 40 + k] = f2h(W1[id]);
    W2t[c * 40 + k] = f2h(W2[id]);
  }
  if (t < 65) rss[t] = rs[n0b + t];
  __syncthreads();
  const int nl = t >> 2, c0 = (t & 3) * 8;
  {
    const int n = n0b + nl;
    float sc[8], sh[8];
#pragma unroll
    for (int j = 0; j < 8; ++j) {
      const int c = c0 + j;
      const float mu = stats[c] * (1.f / NN);
      float var = fmaxf(stats[32 + c] * (1.f / NN) - mu * mu, 0.f);
      sc[j] = gamma[c] * rsqrtf(var + BN_EPS);
      sh[j] = beta[c] - mu * sc[j];
    }
    float a[8] = {};
    add8h(a, *(const uint4*)(yin + (size_t)n * 32 + c0));
    const u32t e0 = rss[nl], e1 = rss[nl + 1];
    u32t e = e0;
    for (; e + 4 <= e1; e += 4) {
      const int s0v = ssrc[e], s1v = ssrc[e + 1], s2v = ssrc[e + 2], s3v = ssrc[e + 3];
      const uint4 v0 = *(const uint4*)(yin + (size_t)s0v * 32 + c0);
      const uint4 v1 = *(const uint4*)(yin + (size_t)s1v * 32 + c0);
      const uint4 v2 = *(const uint4*)(yin + (size_t)s2v * 32 + c0);
      const uint4 v3 = *(const uint4*)(yin + (size_t)s3v * 32 + c0);
      add8h(a, v0); add8h(a, v1); add8h(a, v2); add8h(a, v3);
    }
    for (; e < e1; ++e)
      add8h(a, *(const uint4*)(yin + (size_t)ssrc[e] * 32 + c0));
    const float cnt = (float)(e1 - e0 + 1u);
    union { u16t h[8]; uint4 v; } pk;
#pragma unroll
    for (int j = 0; j < 8; ++j) pk.h[j] = f2h(sc[j] * a[j] + cnt * sh[j]);
    *(uint4*)(A1h + nl * 40 + c0) = pk.v;
  }
  __syncthreads();
  const int w = t >> 6, l = t & 63, col = l & 15, kg = l >> 4;
  const int m0 = w * 16;
  {
    const f16x8 af = *(const f16x8*)(A1h + (m0 + col) * 40 + kg * 8);
    const f16x8 bf0 = *(const f16x8*)(W1t + col * 40 + kg * 8);
    const f16x8 bf1 = *(const f16x8*)(W1t + (16 + col) * 40 + kg * 8);
    f32x4 ac0 = {0.f, 0.f, 0.f, 0.f}, ac1 = {0.f, 0.f, 0.f, 0.f};
    ac0 = __builtin_amdgcn_mfma_f32_16x16x32_f16(af, bf0, ac0, 0, 0, 0);
    ac1 = __builtin_amdgcn_mfma_f32_16x16x32_f16(af, bf1, ac1, 0, 0, 0);
    const float bb0 = b1[col], bb1 = b1[16 + col];
#pragma unroll
    for (int r = 0; r < 4; ++r) {
      const int m = m0 + kg * 4 + r;
      A2h[m * 40 + col] = f2h(fmaxf(ac0[r] + bb0, 0.f));
      A2h[m * 40 + 16 + col] = f2h(fmaxf(ac1[r] + bb1, 0.f));
    }
  }
  __syncthreads();
  {
    const f16x8 af = *(const f16x8*)(A2h + (m0 + col) * 40 + kg * 8);
    const f16x8 bf0 = *(const f16x8*)(W2t + col * 40 + kg * 8);
    const f16x8 bf1 = *(const f16x8*)(W2t + (16 + col) * 40 + kg * 8);
    f32x4 ac0 = {0.f, 0.f, 0.f, 0.f}, ac1 = {0.f, 0.f, 0.f, 0.f};
    ac0 = __builtin_amdgcn_mfma_f32_16x16x32_f16(af, bf0, ac0, 0, 0, 0);
    ac1 = __builtin_amdgcn_mfma_f32_16x16x32_f16(af, bf1, ac1, 0, 0, 0);
    const float bb0 = b2[col], bb1 = b2[16 + col];
#pragma unroll
    for (int r = 0; r < 4; ++r) {
      const int m = m0 + kg * 4 + r;
      A1h[m * 40 + col] = f2h(fmaxf(ac0[r] + bb0, 0.f));
      A1h[m * 40 + 16 + col] = f2h(fmaxf(ac1[r] + bb1, 0.f));
    }
  }
  __syncthreads();
  const int c = t & 31;
  float rsum = 0.f, rq = 0.f;
#pragma unroll
  for (int rep = 0; rep < 8; ++rep) {
    const int row = (t >> 5) + rep * 8;
    const float v = h2f(A1h[row * 40 + c]);
    rsum += v;
    rq += v * v;
  }
  {
    const int row = t >> 2;
    const uint4 v = *(const uint4*)(A1h + row * 40 + (t & 3) * 8);
    *(uint4*)(yout + (size_t)(n0b + row) * 32 + (t & 3) * 8) = v;
  }
  rsum += __shfl_down(rsum, 32);
  rq += __shfl_down(rq, 32);
  __syncthreads();
  const int wv_ = t >> 6, lane = t & 63;
  if (lane < 32) {
    red[wv_ * 32 + lane] = rsum;
    red[128 + wv_ * 32 + lane] = rq;
  }
  __syncthreads();
  if (t < 32) {
    float aa = red[t] + red[32 + t] + red[64 + t] + red[96 + t];
    float bb = red[128 + t] + red[160 + t] + red[192 + t] + red[224 + t];
    unsafeAtomicAdd(&stats_out[t], aa);
    unsafeAtomicAdd(&stats_out[32 + t], bb);
  }
}

// ---- CNN body ----
__device__ __forceinline__ void cnn_body(
    int g, char* smem,
    const float* __restrict__ xo,
    const float* __restrict__ w1, const float* __restrict__ b1,
    const u16t* __restrict__ W2k, const float* __restrict__ b2,
    const u16t* __restrict__ W3k, const float* __restrict__ b3,
    u16t* __restrict__ t3)
{
  float* xot = (float*)(smem);
  float* w1s = (float*)(smem + 3072);
  float* b2s = (float*)(smem + 4096);
  float* b3s = (float*)(smem + 4352);
  short* T1T = (short*)(smem + 4864);
  char*  T2B = smem + 20736;
  u16t*  stg = (u16t*)(smem + 4864);

  const int t = threadIdx.x;
  const int w = t >> 6, l = t & 63, col = l & 15, kg = l >> 4;

  for (int i = t; i < 768; i += 256) xot[i] = (i < 735) ? xo[(size_t)g * 735 + i] : 0.f;
  w1s[t] = w1[t];
  if (t < 64) b2s[t] = b2[t];
  if (t < 128) b3s[t] = b3[t];
  if (t < 192) {
    int r = 242 + (t >> 5), c = t & 31;
    T1T[r * 32 + c] = 0;
  }
  __syncthreads();

  {
    const int c = t >> 3, qg = t & 7;
    float wv[8];
#pragma unroll
    for (int j = 0; j < 8; ++j) wv[j] = w1s[c * 8 + j];
    const float bias = b1[c];
    const int q0 = qg * 31, qe = (q0 + 31 < 242) ? q0 + 31 : 242;
#pragma unroll 1
    for (int qc = q0; qc < qe; qc += 10) {
      const int cnt = (qe - qc < 10) ? qe - qc : 10;
      float xv[37];
#pragma unroll
      for (int j = 0; j < 37; ++j) xv[j] = xot[3 * qc + j];
#pragma unroll
      for (int j0 = 0; j0 < 10; ++j0) {
        if (j0 < cnt) {
          float a0 = bias, a1 = bias, a2 = bias;
#pragma unroll
          for (int tt = 0; tt < 8; ++tt) {
            a0 = fmaf(wv[tt], xv[3 * j0 + tt], a0);
            a1 = fmaf(wv[tt], xv[3 * j0 + 1 + tt], a1);
            a2 = fmaf(wv[tt], xv[3 * j0 + 2 + tt], a2);
          }
          float m = fmaxf(fmaxf(a0, a1), fmaxf(a2, 0.f));
          const int pos = qc + j0;
          T1T[pos * 32 + (c ^ ((pos & 3) << 3))] = (short)f2bf(m);
        }
      }
    }
  }
  __syncthreads();

  {
    bf16x8 am[8];
#pragma unroll
    for (int kk = 0; kk < 8; ++kk)
      am[kk] = *(const bf16x8*)(W2k + (w * 16 + col) * 256 + kk * 32 + kg * 8);
#pragma unroll 1
    for (int qt = 0; qt < 5; ++qt) {
      const int rbase = qt * 48 + col * 3;
      bf16x8 rv[10];
#pragma unroll
      for (int s = 0; s < 10; ++s) {
        const int row = rbase + s;
        rv[s] = *(const bf16x8*)(T1T + row * 32 + ((kg ^ (row & 3)) << 3));
      }
      f32x4 a0 = {0.f, 0.f, 0.f, 0.f}, a1 = a0, a2 = a0;
#pragma unroll
      for (int kk = 0; kk < 8; ++kk) {
        a0 = __builtin_amdgcn_mfma_f32_16x16x32_bf16(am[kk], rv[kk], a0, 0, 0, 0);
        a1 = __builtin_amdgcn_mfma_f32_16x16x32_bf16(am[kk], rv[kk + 1], a1, 0, 0, 0);
        a2 = __builtin_amdgcn_mfma_f32_16x16x32_bf16(am[kk], rv[kk + 2], a2, 0, 0, 0);
      }
      const int q = qt * 16 + col;
      if (q < 78) {
        union { u16t u[4]; uint2 v; } pk;
#pragma unroll
        for (int r = 0; r < 4; ++r) {
          const float bb = b2s[w * 16 + kg * 4 + r];
          float m = fmaxf(fmaxf(a0[r], a1[r]), a2[r]);
          pk.u[r] = f2bf(fmaxf(m + bb, 0.f));
        }
        const int boff = (q * 128 + (w * 16 + kg * 4) * 2) ^ ((q & 7) << 4);
        *(uint2*)(T2B + boff) = pk.v;
      }
    }
  }
  __syncthreads();

  {
#pragma unroll 1
    for (int mi = 0; mi < 2; ++mi) {
      const int m3 = w * 2 + mi;
      f32x4 acc[2][3];
#pragma unroll
      for (int qt = 0; qt < 2; ++qt)
#pragma unroll
        for (int r = 0; r < 3; ++r) acc[qt][r] = (f32x4){0.f, 0.f, 0.f, 0.f};
#pragma unroll 1
      for (int kh = 0; kh < 2; ++kh) {
        bf16x8 amh[8];
#pragma unroll
        for (int tt = 0; tt < 8; ++tt)
          amh[tt] = *(const bf16x8*)(W3k + (m3 * 16 + col) * 512 + (tt * 2 + kh) * 32 + kg * 8);
#pragma unroll
        for (int qt = 0; qt < 2; ++qt) {
          const int rbase = qt * 48 + col * 3;
          bf16x8 rv[10];
#pragma unroll
          for (int s = 0; s < 10; ++s) {
            int row = rbase + s;
            row = (row < 78) ? row : 77;
            const int boff = (row * 128 + kh * 64 + kg * 16) ^ ((row & 7) << 4);
            rv[s] = *(const bf16x8*)(T2B + boff);
          }
#pragma unroll
          for (int tt = 0; tt < 8; ++tt) {
            acc[qt][0] = __builtin_amdgcn_mfma_f32_16x16x32_bf16(amh[tt], rv[tt], acc[qt][0], 0, 0, 0);
            acc[qt][1] = __builtin_amdgcn_mfma_f32_16x16x32_bf16(amh[tt], rv[tt + 1], acc[qt][1], 0, 0, 0);
            acc[qt][2] = __builtin_amdgcn_mfma_f32_16x16x32_bf16(amh[tt], rv[tt + 2], acc[qt][2], 0, 0, 0);
          }
        }
      }
#pragma unroll
      for (int qt = 0; qt < 2; ++qt) {
        const int q = qt * 16 + col;
        if (q < 23) {
#pragma unroll
          for (int r = 0; r < 4; ++r) {
            const int c = m3 * 16 + kg * 4 + r;
            float m = fmaxf(fmaxf(acc[qt][0][r], acc[qt][1][r]), acc[qt][2][r]);
            stg[c * 23 + q] = f2bf(fmaxf(m + b3s[c], 0.f));
          }
        }
      }
    }
  }
  __syncthreads();

  {
    const uint4* s4 = (const uint4*)stg;
    uint4* d4 = (uint4*)(t3 + (size_t)g * 2944);
    for (int id = t; id < 368; id += 256) d4[id] = s4[id];
  }
}

// ---- fused launch: 5 layer blocks + 2 cnn blocks per group of 7 ----
__global__ __launch_bounds__(256, 4) void k_fused(
    const u16t* __restrict__ yin, const u32t* __restrict__ rs, const int* __restrict__ ssrc,
    const float* __restrict__ stats, const float* __restrict__ gamma, const float* __restrict__ beta,
    const float* __restrict__ W1, const float* __restrict__ b1,
    const float* __restrict__ W2, const float* __restrict__ b2,
    u16t* __restrict__ yout, float* __restrict__ stats_out,
    const float* __restrict__ xo, const float* __restrict__ c1W, const float* __restrict__ c1b,
    const u16t* __restrict__ W2k, const float* __restrict__ c2b,
    const u16t* __restrict__ W3k, const float* __restrict__ c3b,
    u16t* __restrict__ t3, int cnn_g0)
{
  __shared__ __align__(16) char smem[30720];
  const int grp = blockIdx.x / 7, rem = blockIdx.x % 7;
  if (rem < 5)
    layer_body(grp * 5 + rem, smem, yin, rs, ssrc, stats, gamma, beta,
               W1, b1, W2, b2, yout, stats_out);
  else
    cnn_body(cnn_g0 + grp * 2 + (rem - 5), smem, xo, c1W, c1b, W2k, c2b, W3k, c3b, t3);
}

__global__ __launch_bounds__(64) void k_pool_xd(
    const u16t* __restrict__ y, const int* __restrict__ batch,
    const float* __restrict__ stats, const float* __restrict__ gamma,
    const float* __restrict__ beta, const float* __restrict__ Wxd,
    const float* __restrict__ bxd, u16t* __restrict__ xc)
{
  const int g = blockIdx.x, t = threadIdx.x;
  int lo = 0, n = NN;
  while (n > 0) {
    int h = n >> 1, m = lo + h;
    if (batch[m] < g) { lo = m + 1; n -= h + 1; } else n = h;
  }
  int hi = lo;
  n = NN - lo;
  while (n > 0) {
    int h = n >> 1, m = hi + h;
    if (batch[m] < g + 1) { hi = m + 1; n -= h + 1; } else n = h;
  }
  const int c = t & 31;
  const float mu = stats[4 * 64 + c] * (1.f / NN);
  float var = fmaxf(stats[4 * 64 + 32 + c] * (1.f / NN) - mu * mu, 0.f);
  const float sc = gamma[4 * 32 + c] * rsqrtf(var + BN_EPS);
  const float sh = beta[4 * 32 + c] - mu * sc;
  float acc = 0.f;
  for (int i = lo + (t >> 5); i < hi; i += 2) acc += h2f(y[(size_t)i * 32 + c]);
  acc += __shfl_down(acc, 32);
  __shared__ float pl[32];
  if (t < 32) pl[t] = acc * sc + (float)(hi - lo) * sh;
  __syncthreads();
#pragma unroll
  for (int rep = 0; rep < 2; ++rep) {
    const int o = t + rep * 64;
    float a = bxd[o];
#pragma unroll
    for (int cc = 0; cc < 32; ++cc) a = fmaf(pl[cc], Wxd[cc * 128 + o], a);
    xc[(size_t)g * 256 + o] = f2bf(fmaxf(a, 0.f));
  }
}

// ---------------- weight prep ----------------
__global__ __launch_bounds__(256) void k_prep(
    const float* __restrict__ w2, const float* __restrict__ w3,
    const float* __restrict__ wxt, const float* __restrict__ wf1, const float* __restrict__ wf2,
    u16t* __restrict__ W2k, u16t* __restrict__ W3k,
    u16t* __restrict__ WXT, u16t* __restrict__ WF1, u16t* __restrict__ WF2)
{
  const int i = blockIdx.x * 256 + threadIdx.x;
  if (i < 64 * 256) {
    int c2 = i >> 8, kk = i & 255, tt = kk >> 5, ci = kk & 31;
    W2k[i] = f2bf(w2[c2 * 256 + ci * 8 + tt]);
  }
  if (i < 128 * 512) {
    int c3 = i >> 9, kk = i & 511, tt = kk >> 6, ci = kk & 63;
    W3k[i] = f2bf(w3[c3 * 512 + ci * 8 + tt]);
  }
  if (i < 128 * 2944) {
    int nn = i / 2944, kk = i - nn * 2944;
    WXT[i] = f2bf(wxt[kk * 128 + nn]);
  }
  if (i < 1024 * 256) {
    int nn = i >> 8, kk = i & 255;
    WF1[i] = f2bf(wf1[kk * 1024 + nn]);
  }
  if (i < 128 * 1024) {
    int nn = i >> 10, kk = i & 1023;
    WF2[i] = f2bf(wf2[kk * 128 + nn]);
  }
}

// ---------------- bf16 MFMA GEMM ----------------
__global__ __launch_bounds__(256) void k_mgemm(
    const u16t* __restrict__ A, int lda,
    const u16t* __restrict__ WT, const float* __restrict__ bias,
    void* __restrict__ Cv, int ldc, int c_off, int M, int Kd,
    int relu_f, int out32)
{
  __shared__ __align__(16) u16t As[128 * 4 * 8];
  __shared__ __align__(16) u16t Ws2[64 * 4 * 8];
  const int t = threadIdx.x;
  const int w = t >> 6, l = t & 63, col = l & 15, kg = l >> 4;
  const int wm = w & 1, wn = w >> 1;
  const int m0 = blockIdx.x * 128, n0 = blockIdx.y * 64;
  f32x4 acc[4][2];
#pragma unroll
  for (int i = 0; i < 4; ++i)
#pragma unroll
    for (int j = 0; j < 2; ++j) acc[i][j] = (f32x4){0.f, 0.f, 0.f, 0.f};
  const int ar = t >> 1, ac = (t & 1) * 2;
  const int wr = t >> 2, wc = t & 3;
  const bool aok = (m0 + ar) < M;
  const u16t* Ap = A + (size_t)(m0 + ar) * lda;
  const u16t* Wp = WT + (size_t)(n0 + wr) * Kd;
  for (int k0 = 0; k0 < Kd; k0 += 32) {
    bf16x8 av0 = {0, 0, 0, 0, 0, 0, 0, 0}, av1 = {0, 0, 0, 0, 0, 0, 0, 0};
    if (aok) {
      av0 = *(const bf16x8*)(Ap + k0 + ac * 8);
      av1 = *(const bf16x8*)(Ap + k0 + (ac + 1) * 8);
    }
    const bf16x8 wv = *(const bf16x8*)(Wp + k0 + wc * 8);
    __syncthreads();
    *(bf16x8*)(As + (ar * 4 + (ac ^ (ar & 3))) * 8) = av0;
    *(bf16x8*)(As + (ar * 4 + ((ac + 1) ^ (ar & 3))) * 8) = av1;
    *(bf16x8*)(Ws2 + (wr * 4 + (wc ^ (wr & 3))) * 8) = wv;
    __syncthreads();
    bf16x8 af[4], bf[2];
#pragma unroll
    for (int i = 0; i < 4; ++i) {
      const int R = wm * 64 + i * 16 + col;
      af[i] = *(const bf16x8*)(As + (R * 4 + (kg ^ (R & 3))) * 8);
    }
#pragma unroll
    for (int j = 0; j < 2; ++j) {
      const int R = wn * 32 + j * 16 + col;
      bf[j] = *(const bf16x8*)(Ws2 + (R * 4 + (kg ^ (R & 3))) * 8);
    }
#pragma unroll
    for (int i = 0; i < 4; ++i)
#pragma unroll
      for (int j = 0; j < 2; ++j)
        acc[i][j] = __builtin_amdgcn_mfma_f32_16x16x32_bf16(af[i], bf[j], acc[i][j], 0, 0, 0);
  }
#pragma unroll
  for (int j = 0; j < 2; ++j) {
    const int gn = n0 + wn * 32 + j * 16 + col;
    const float bb = bias[gn];
#pragma unroll
    for (int i = 0; i < 4; ++i) {
      const int gmb = m0 + wm * 64 + i * 16 + kg * 4;
#pragma unroll
      for (int r = 0; r < 4; ++r) {
        const int gm = gmb + r;
        if (gm < M) {
          float v = acc[i][j][r] + bb;
          if (relu_f) v = fmaxf(v, 0.f);
          if (out32) ((float*)Cv)[(size_t)gm * ldc + c_off + gn] = v;
          else ((u16t*)Cv)[(size_t)gm * ldc + c_off + gn] = f2bf(v);
        }
      }
    }
  }
}

__global__ __launch_bounds__(256) void k_out(
    const float* __restrict__ h2, const float* __restrict__ Wo,
    const float* __restrict__ bo, float* __restrict__ out)
{
  __shared__ float Ws_[128];
  const int t = threadIdx.x;
  if (t < 128) Ws_[t] = Wo[t];
  __syncthreads();
  const int g = blockIdx.x * 32 + (t >> 3), l = t & 7;
  float acc = 0.f;
  if (g < NG) {
    const float* hr = h2 + (size_t)g * 128 + l * 16;
    const float* wr = Ws_ + l * 16;
#pragma unroll
    for (int j = 0; j < 16; ++j) acc = fmaf(hr[j], wr[j], acc);
  }
  acc += __shfl_down(acc, 4, 8);
  acc += __shfl_down(acc, 2, 8);
  acc += __shfl_down(acc, 1, 8);
  if (l == 0 && g < NG) out[g] = acc + bo[0];
}

extern "C" void kernel_launch(void* const* d_in, const int* in_sizes, int n_in,
                              void* d_out, int out_size, void* d_ws, size_t ws_size,
                              hipStream_t stream) {
  const float* x    = (const float*)d_in[0];
  const int*   ei   = (const int*)d_in[1];
  const int*   batch= (const int*)d_in[2];
  const float* xo   = (const float*)d_in[3];
  const float* g1W1 = (const float*)d_in[4];
  const float* g1b1 = (const float*)d_in[5];
  const float* g1W2 = (const float*)d_in[6];
  const float* g1b2 = (const float*)d_in[7];
  const float* gsW1 = (const float*)d_in[8];
  const float* gsb1 = (const float*)d_in[9];
  const float* gsW2 = (const float*)d_in[10];
  const float* gsb2 = (const float*)d_in[11];
  const float* bng  = (const float*)d_in[12];
  const float* bnb  = (const float*)d_in[13];
  const float* Wxd  = (const float*)d_in[14];
  const float* bxd  = (const float*)d_in[15];
  const float* c1W  = (const float*)d_in[16];
  const float* c1b  = (const float*)d_in[17];
  const float* c2W  = (const float*)d_in[18];
  const float* c2b  = (const float*)d_in[19];
  const float* c3W  = (const float*)d_in[20];
  const float* c3b  = (const float*)d_in[21];
  const float* Wxt  = (const float*)d_in[22];
  const float* bxt  = (const float*)d_in[23];
  const float* W1f  = (const float*)d_in[24];
  const float* b1f  = (const float*)d_in[25];
  const float* W2f  = (const float*)d_in[26];
  const float* b2f  = (const float*)d_in[27];
  const float* Wo   = (const float*)d_in[28];
  const float* bo   = (const float*)d_in[29];

  char* ws = (char*)d_ws;
  u16t*  U    = (u16t*)(ws + OFF_U);
  u16t*  YA   = (u16t*)(ws + OFF_YA);
  u16t*  YB   = (u16t*)(ws + OFF_YB);
  float* ST   = (float*)(ws + OFF_ST);
  u32t*  RS   = (u32t*)(ws + OFF_RS);
  u32t*  CUR  = (u32t*)(ws + OFF_CUR);
  u32t*  BS   = (u32t*)(ws + OFF_BSUM);
  int*   SSRC = (int*)(ws + OFF_SSRC);
  u16t*  WK   = (u16t*)(ws + OFF_WK);
  u16t*  W2K  = WK;
  u16t*  W3K  = WK + 16384;
  u16t*  WXT  = WK + 16384 + 65536;
  u16t*  WF1  = WK + 16384 + 65536 + 376832;
  u16t*  WF2  = WK + 16384 + 65536 + 376832 + 262144;
  u16t*  XC   = (u16t*)(ws + OFF_XC);
  u16t*  T3   = (u16t*)(ws + OFF_T3);
  u16t*  H1   = (u16t*)(ws + OFF_H1);
  float* H2   = (float*)(ws + OFF_H2);
  float* OUT  = (float*)d_out;

  const int NBLK = (NN + 1023) / 1024;

  hipMemsetAsync(ST, 0, 5 * 64 * sizeof(float), stream);
  hipMemsetAsync(CUR, 0, NN * sizeof(u32t), stream);

  k_prep<<<(128 * 2944 + 255) / 256, 256, 0, stream>>>(c2W, c3W, Wxt, W1f, W2f,
                                                        W2K, W3K, WXT, WF1, WF2);

  k_hist<<<(NE + 255) / 256, 256, 0, stream>>>(ei, CUR);
  k_scan1<<<NBLK, 256, 0, stream>>>(CUR, BS);
  k_scan2<<<1, 256, 0, stream>>>(BS, RS, NBLK);
  k_scan3<<<NBLK, 256, 0, stream>>>(CUR, RS, BS);
  for (int p = 0; p < 8; ++p)
    k_scatter<<<(NE + 255) / 256, 256, 0, stream>>>(ei, CUR, SSRC, p);

  k_mlp1_first<<<NN / 64, 256, 0, stream>>>(x, g1W1, U);
  k_agg0<<<NN / 64, 256, 0, stream>>>(U, RS, SSRC, g1b1, g1W2, g1b2, YA, ST + 0);

  const u16t* yin = YA;
  u16t* yout = YB;
  for (int lyr = 1; lyr <= 4; ++lyr) {
    k_fused<<<21875, 256, 0, stream>>>(yin, RS, SSRC, ST + (lyr - 1) * 64,
                                       bng + (lyr - 1) * 32, bnb + (lyr - 1) * 32,
                                       gsW1 + (lyr - 1) * 1024, gsb1 + (lyr - 1) * 32,
                                       gsW2 + (lyr - 1) * 1024, gsb2 + (lyr - 1) * 32,
                                       yout, ST + lyr * 64,
                                       xo, c1W, c1b, W2K, c2b, W3K, c3b, T3,
                                       (lyr - 1) * 6250);
    const u16t* tmp = yin;
    yin = yout;
    yout = (u16t*)tmp;
  }
  k_pool_xd<<<NG, 64, 0, stream>>>(yin, batch, ST, bng, bnb, Wxd, bxd, XC);

  {
    dim3 grid((NG + 127) / 128, 2);
    k_mgemm<<<grid, 256, 0, stream>>>(T3, 2944, WXT, bxt, XC, 256, 128, NG, 2944, 0, 0);
  }
  {
    dim3 grid((NG + 127) / 128, 16);
    k_mgemm<<<grid, 256, 0, stream>>>(XC, 256, WF1, b1f, H1, 1024, 0, NG, 256, 1, 0);
  }
  {
    dim3 grid((NG + 127) / 128, 2);
    k_mgemm<<<grid, 256, 0, stream>>>(H1, 1024, WF2, b2f, H2, 128, 0, NG, 1024, 1, 1);
  }
  k_out<<<(NG + 31) / 32, 256, 0, stream>>>(H2, Wo, bo, OUT);
}